// Round 8
// baseline (592.448 us; speedup 1.0000x reference)
//
#include <hip/hip_runtime.h>

typedef unsigned short u16;
typedef short short8 __attribute__((ext_vector_type(8)));
typedef u16 u16x4 __attribute__((ext_vector_type(4)));
typedef u16 u16x8 __attribute__((ext_vector_type(8)));
typedef float float4v __attribute__((ext_vector_type(4)));

#define NEG_SLOPE 0.2f

static __device__ __forceinline__ float b2f(u16 u) {
    union { unsigned int i; float f; } x; x.i = ((unsigned int)u) << 16; return x.f;
}
static __device__ __forceinline__ u16 f2b(float f) {
    unsigned int u = __float_as_uint(f);
    unsigned int r = (u + 0x7fffu + ((u >> 16) & 1u)) >> 16;
    return (u16)r;
}

// ---------------------------------------------------------------------------
// diagnostics: code 32 = CSR inconsistent; 1000+ = ws too small
// ---------------------------------------------------------------------------
__global__ void k_diag(float* out, int n, float val)
{
    int i = blockIdx.x * 256 + threadIdx.x;
    if (i < n) out[i] = val;
}

__global__ void scan_csr(const int* off, const int* srcs, int N, int E,
                         int* flag, int bit)
{
    int i = blockIdx.x * 256 + threadIdx.x;
    if (i < N) {
        int a = off[i], b = off[i + 1];
        if (a < 0 || b < a || b > E) atomicOr(flag, bit);
    }
    if (i == 0 && off[N] != E) atomicOr(flag, bit);
    if (i < E) {
        if ((unsigned)srcs[i] >= (unsigned)N) atomicOr(flag, bit);
    }
}

__global__ void k_final_diag(const int* flag, float* out, int n)
{
    int f = *flag;
    if (f == 0) return;
    int b = __ffs(f) - 1;
    float val = 32.0f * (b + 1);
    int i = blockIdx.x * 256 + threadIdx.x;
    if (i < n) out[i] = val;
}

// ---------------------------------------------------------------------------
// edge_index dtype probe + canonical int32 extraction (+ degree count fused)
// ---------------------------------------------------------------------------
__global__ void k_detect(const int* ei, int E, int* flag64)
{
    __shared__ int zc;
    if (threadIdx.x == 0) zc = 0;
    __syncthreads();
    int idx = 1 + 2 * (int)threadIdx.x;
    int z = (idx < 2 * E && ei[idx] == 0) ? 1 : 0;
    atomicAdd(&zc, z);
    __syncthreads();
    if (threadIdx.x == 0) *flag64 = (zc >= 200) ? 1 : 0;
}

__global__ void k_extract(const int* ei, int E, const int* flag64,
                          int* src, int* dst, int* deg, int N)
{
    int e = blockIdx.x * 256 + threadIdx.x;
    if (e >= E) return;
    int s, d;
    if (*flag64) {
        s = ei[2 * e];
        d = ei[2 * E + 2 * e];
    } else {
        s = ei[e];
        d = ei[E + e];
    }
    src[e] = s; dst[e] = d;
    if ((unsigned)d < (unsigned)N) atomicAdd(&deg[d], 1);
}

// ---------------------------------------------------------------------------
// device-wide exclusive scan, 3-phase (1024 elems per block in phase A)
// ---------------------------------------------------------------------------
__global__ __launch_bounds__(256)
void k_scan_a(const int* __restrict__ deg, int* __restrict__ off,
              int* __restrict__ partial, int N)
{
    __shared__ int sd[256];
    int tid = threadIdx.x;
    int base = blockIdx.x * 1024;
    int i0 = base + tid * 4;
    int v0 = 0, v1 = 0, v2 = 0, v3 = 0;
    if (i0 < N)     v0 = deg[i0];
    if (i0 + 1 < N) v1 = deg[i0 + 1];
    if (i0 + 2 < N) v2 = deg[i0 + 2];
    if (i0 + 3 < N) v3 = deg[i0 + 3];
    int t = v0 + v1 + v2 + v3;
    sd[tid] = t;
    __syncthreads();
    #pragma unroll
    for (int s = 1; s < 256; s <<= 1) {
        int u = (tid >= s) ? sd[tid - s] : 0;
        __syncthreads();
        sd[tid] += u;
        __syncthreads();
    }
    int excl = sd[tid] - t;                 // exclusive within block
    if (i0 < N)     off[i0]     = excl;
    if (i0 + 1 < N) off[i0 + 1] = excl + v0;
    if (i0 + 2 < N) off[i0 + 2] = excl + v0 + v1;
    if (i0 + 3 < N) off[i0 + 3] = excl + v0 + v1 + v2;
    if (tid == 255) partial[blockIdx.x] = sd[255];
}

__global__ __launch_bounds__(1024)
void k_scan_b(int* partial, int nblk)
{
    __shared__ int sd[1024];
    __shared__ int running;
    int tid = threadIdx.x;
    if (tid == 0) running = 0;
    __syncthreads();
    for (int base = 0; base < nblk; base += 1024) {
        int i = base + tid;
        int v = (i < nblk) ? partial[i] : 0;
        sd[tid] = v;
        __syncthreads();
        for (int s = 1; s < 1024; s <<= 1) {
            int u = (tid >= s) ? sd[tid - s] : 0;
            __syncthreads();
            sd[tid] += u;
            __syncthreads();
        }
        if (i < nblk) partial[i] = sd[tid] - v + running;   // exclusive
        int total = sd[1023];
        __syncthreads();
        if (tid == 0) running += total;
        __syncthreads();
    }
}

__global__ __launch_bounds__(256)
void k_scan_c(int* __restrict__ off, int* __restrict__ cursor,
              const int* __restrict__ partial, int N, int E)
{
    int i = blockIdx.x * 256 + threadIdx.x;
    if (i < N) {
        int v = off[i] + partial[i >> 10];
        off[i] = v;
        cursor[i] = v;
    }
    if (i == 0) off[N] = E;
}

__global__ void k_scatter(const int* src, const int* dst, int* cursor,
                          int* srcs, int E, int N)
{
    int e = blockIdx.x * 256 + threadIdx.x;
    if (e < E) {
        int d = dst[e];
        if ((unsigned)d < (unsigned)N) {
            int p = atomicAdd(&cursor[d], 1);
            if ((unsigned)p < (unsigned)E) srcs[p] = src[e];
        }
    }
}

// ---------------------------------------------------------------------------
// fused fp32->bf16 cast + row dots vs (vs,vd): 8 rows/block, 32 lanes/row.
// ---------------------------------------------------------------------------
__global__ __launch_bounds__(256)
void k_castdot(const float* __restrict__ x, const float* __restrict__ vs,
               const float* __restrict__ vd, u16* __restrict__ xb,
               float* __restrict__ a_s, float* __restrict__ a_d, int N)
{
    int tid = threadIdx.x;
    int rowb = tid >> 5;                // 0..7
    int col8 = (tid & 31) * 8;
    int n = blockIdx.x * 8 + rowb;
    if (n >= N) return;
    const float* xr = x + (size_t)n * 256 + col8;
    float4 v0 = *(const float4*)xr;
    float4 v1 = *(const float4*)(xr + 4);
    int4 w;
    w.x = (int)f2b(v0.x) | ((int)f2b(v0.y) << 16);
    w.y = (int)f2b(v0.z) | ((int)f2b(v0.w) << 16);
    w.z = (int)f2b(v1.x) | ((int)f2b(v1.y) << 16);
    w.w = (int)f2b(v1.z) | ((int)f2b(v1.w) << 16);
    *(int4*)(xb + (size_t)n * 256 + col8) = w;

    float4 s0 = *(const float4*)(vs + col8);
    float4 s1 = *(const float4*)(vs + col8 + 4);
    float4 d0 = *(const float4*)(vd + col8);
    float4 d1 = *(const float4*)(vd + col8 + 4);
    float ss = v0.x*s0.x + v0.y*s0.y + v0.z*s0.z + v0.w*s0.w
             + v1.x*s1.x + v1.y*s1.y + v1.z*s1.z + v1.w*s1.w;
    float sd = v0.x*d0.x + v0.y*d0.y + v0.z*d0.z + v0.w*d0.w
             + v1.x*d1.x + v1.y*d1.y + v1.z*d1.z + v1.w*d1.w;
    #pragma unroll
    for (int m = 16; m; m >>= 1) {
        ss += __shfl_xor(ss, m, 64);
        sd += __shfl_xor(sd, m, 64);
    }
    if ((tid & 31) == 0) { a_s[n] = ss; a_d[n] = sd; }
}

// ---------------------------------------------------------------------------
// fragment-major weight pack, all weights in one launch (blockIdx.z selects)
// out[(kt*NC16 + cf)*512 + l*8 + j] = bf16( W[kt*32+(l>>4)*8+j][cf*16+(l&15)] )
// ---------------------------------------------------------------------------
__global__ __launch_bounds__(64)
void k_packAll(const float* A1w, const float* W1, const float* W2, const float* A2w,
               const float* Hw1, const float* Hw2, const float* Hw3,
               u16* WT1, u16* WT2, u16* WTH)
{
    int z = blockIdx.z;
    const float *in1, *in2; int ksplit, csplit, in_ld, NC16; u16* out;
    if (z == 0)      { in1 = A1w; in2 = W1;  ksplit = 256; csplit = 0;   in_ld = 512; out = WT1; NC16 = 32; }
    else if (z == 1) { in1 = W2;  in2 = A2w; ksplit = 0;   csplit = 256; in_ld = 256; out = WT2; NC16 = 32; }
    else {
        if (blockIdx.x >= 16 || blockIdx.y >= 8) return;
        in1 = (z == 2) ? Hw1 : (z == 3) ? Hw2 : Hw3;
        in2 = nullptr; ksplit = 0; csplit = 0; in_ld = 256; NC16 = 16;
        out = WTH + (size_t)(z - 2) * 65536;
    }
    int l = threadIdx.x;
    int cf = blockIdx.x, kt = blockIdx.y;
    int col = cf * 16 + (l & 15);
    int kbase = kt * 32 + (l >> 4) * 8;
    const float* src = in1;
    int cc = col, koff = 0;
    if (ksplit > 0 && kbase >= ksplit) { src = in2; koff = ksplit; }
    if (csplit > 0 && col >= csplit)   { src = in2; cc = col - csplit; }
    u16* o = out + ((size_t)(kt * NC16 + cf) * 512) + l * 8;
    #pragma unroll
    for (int j = 0; j < 8; ++j)
        o[j] = f2b(src[(size_t)(kbase - koff + j) * in_ld + cc]);
}

// ---------------------------------------------------------------------------
// fp32 row-dot against two fp32 vectors — one wave per row, float4 lanes
// ---------------------------------------------------------------------------
__global__ __launch_bounds__(256)
void k_rowdot2f(const float* __restrict__ A, int ld, int H,
                const float* __restrict__ vs, const float* __restrict__ vd,
                float* a_s, float* a_d, int N)
{
    int wave = threadIdx.x >> 6, lane = threadIdx.x & 63;
    int n = blockIdx.x * 4 + wave;
    if (n >= N) return;
    const float* ar = A + (size_t)n * ld;
    float ss = 0.f, sd = 0.f;
    for (int i = lane * 4; i < H; i += 256) {
        float4 v  = *(const float4*)(ar + i);
        float4 s4 = *(const float4*)(vs + i);
        float4 d4 = *(const float4*)(vd + i);
        ss += v.x * s4.x + v.y * s4.y + v.z * s4.z + v.w * s4.w;
        sd += v.x * d4.x + v.y * d4.y + v.z * d4.z + v.w * d4.w;
    }
    #pragma unroll
    for (int m = 32; m; m >>= 1) {
        ss += __shfl_xor(ss, m, 64);
        sd += __shfl_xor(sd, m, 64);
    }
    if (lane == 0) { a_s[n] = ss; a_d[n] = sd; }
}

// ---------------------------------------------------------------------------
// per-dst softmax: exact online max/sum (1 pass) + alpha write (1 pass)
// ---------------------------------------------------------------------------
__global__ __launch_bounds__(256)
void k_alpha(const int* __restrict__ off, const int* __restrict__ srcs,
             const float* __restrict__ a_s, const float* __restrict__ a_d,
             float* __restrict__ alpha, int N)
{
    int wave = threadIdx.x >> 6, lane = threadIdx.x & 63;
    int n = blockIdx.x * 4 + wave;
    if (n >= N) return;
    int base = off[n], end = off[n + 1];
    float adn = a_d[n];
    float m = -1e30f, s = 0.f;
    for (int p = base + lane; p < end; p += 64) {
        int sx = srcs[p];
        sx = ((unsigned)sx < (unsigned)N) ? sx : 0;
        float z = a_s[sx] + adn;
        z = fmaxf(z, NEG_SLOPE * z);          // leaky_relu (slope<1)
        float mn = fmaxf(m, z);
        s = s * __expf(m - mn) + __expf(z - mn);
        m = mn;
    }
    #pragma unroll
    for (int msk = 32; msk; msk >>= 1) {
        float mo = __shfl_xor(m, msk, 64);
        float so = __shfl_xor(s, msk, 64);
        float mn = fmaxf(m, mo);
        s = s * __expf(m - mn) + so * __expf(mo - mn);
        m = mn;
    }
    float inv = 1.f / (s + 1e-16f);
    for (int p = base + lane; p < end; p += 64) {
        int sx = srcs[p];
        sx = ((unsigned)sx < (unsigned)N) ? sx : 0;
        float z = a_s[sx] + adn;
        z = fmaxf(z, NEG_SLOPE * z);
        alpha[p] = __expf(z - m) * inv;
    }
}

// ---------------------------------------------------------------------------
// weighted gather-aggregate, half-wave split: lanes 0-31 edge p, 32-63 edge
// p+1; 16B row loads; 4 edges in flight; one shfl(32) reduce per node.
// ---------------------------------------------------------------------------
__global__ __launch_bounds__(256)
void k_aggw(const u16* __restrict__ rows, const int* __restrict__ off,
            const int* __restrict__ srcs, const float* __restrict__ alpha,
            const u16* __restrict__ add, u16* __restrict__ out, int N)
{
    int wave = threadIdx.x >> 6, lane = threadIdx.x & 63;
    int n = blockIdx.x * 4 + wave;
    if (n >= N) return;
    int base = off[n], end = off[n + 1];
    int half = lane >> 5;
    int c8 = (lane & 31) * 8;
    float acc[8] = {};
    int p = base;
    for (; p + 3 < end; p += 4) {
        int sA = srcs[p + half];
        int sB = srcs[p + 2 + half];
        sA = ((unsigned)sA < (unsigned)N) ? sA : 0;
        sB = ((unsigned)sB < (unsigned)N) ? sB : 0;
        float wA = alpha[p + half];
        float wB = alpha[p + 2 + half];
        u16x8 vA = *(const u16x8*)(rows + (size_t)sA * 256 + c8);
        u16x8 vB = *(const u16x8*)(rows + (size_t)sB * 256 + c8);
        #pragma unroll
        for (int j = 0; j < 8; ++j)
            acc[j] += wA * b2f(vA[j]) + wB * b2f(vB[j]);
    }
    for (; p + 1 < end; p += 2) {
        int sA = srcs[p + half];
        sA = ((unsigned)sA < (unsigned)N) ? sA : 0;
        float wA = alpha[p + half];
        u16x8 vA = *(const u16x8*)(rows + (size_t)sA * 256 + c8);
        #pragma unroll
        for (int j = 0; j < 8; ++j)
            acc[j] += wA * b2f(vA[j]);
    }
    if (p < end) {
        int sA = srcs[p];
        sA = ((unsigned)sA < (unsigned)N) ? sA : 0;
        float wA = half ? 0.f : alpha[p];
        u16x8 vA = *(const u16x8*)(rows + (size_t)sA * 256 + c8);
        #pragma unroll
        for (int j = 0; j < 8; ++j)
            acc[j] += wA * b2f(vA[j]);
    }
    #pragma unroll
    for (int j = 0; j < 8; ++j)
        acc[j] += __shfl_xor(acc[j], 32, 64);
    if (half == 0) {
        size_t ob = (size_t)n * 256 + c8;
        if (add) {
            u16x8 ad8 = *(const u16x8*)(add + ob);
            #pragma unroll
            for (int j = 0; j < 8; ++j) acc[j] += b2f(ad8[j]);
        }
        u16x8 o;
        #pragma unroll
        for (int j = 0; j < 8; ++j) o[j] = f2b(acc[j]);
        *(u16x8*)(out + ob) = o;
    }
}

// ---------------------------------------------------------------------------
// full-width fused MFMA GEMM: BM=64, K=512 (two bf16 A halves of 256 each),
// NC=512, fragment-major WTf. BARRIER-FREE: each wave loads its own A and B
// fragments directly from global. A-fragment loads are 64B-line coalesced
// (4 q-groups of a row are consecutive) and L1-shared across the block's
// 8 waves (same CU). No LDS at all -> waves free-run, compiler pipelines
// loads of kt+1 under MFMAs of kt.
// Optional fused row-dots on the C1 half (bf16-rounded acc · dotS/dotD,
// atomicAdd into oaS/oaD).
// ---------------------------------------------------------------------------
__global__ __launch_bounds__(512)
void bigfull(const u16* __restrict__ A1, int lda1,
             const u16* __restrict__ A2, int lda2,
             const u16* __restrict__ WTf,
             const float* b0a, const float* b0b,
             const float* b1a, const float* b1b,
             u16* C1, int ldc1, u16* C2, int ldc2,
             const float* __restrict__ dotS, const float* __restrict__ dotD,
             float* oaS, float* oaD,
             int M, int relu0, int relu1)
{
    const int tid = threadIdx.x;
    const int w = tid >> 6, lane = tid & 63;
    const int m16 = lane & 15, q = lane >> 4;
    const int q8 = q * 8;
    const int rowBase = blockIdx.x * 64;

    // per-lane clamped row indices for the 4 row-fragments
    int grow4[4];
    #pragma unroll
    for (int rf = 0; rf < 4; ++rf) {
        int g = rowBase + rf * 16 + m16;
        grow4[rf] = (g < M) ? g : (M - 1);
    }
    const u16* bbase = WTf + (size_t)(w * 4) * 512 + lane * 8;

    float4v acc[16] = {};

    #pragma unroll 4
    for (int kt = 0; kt < 16; ++kt) {
        const u16* Ab = (kt < 8) ? A1 : A2;
        const int  ld = (kt < 8) ? lda1 : lda2;
        const int  kb = ((kt < 8) ? kt * 32 : kt * 32 - 256) + q8;

        short8 a[4], b[4];
        #pragma unroll
        for (int c = 0; c < 4; ++c) {
            int4 bv = *(const int4*)(bbase + (size_t)kt * 16384 + (size_t)c * 512);
            b[c] = *(short8*)&bv;
        }
        #pragma unroll
        for (int rf = 0; rf < 4; ++rf)
            a[rf] = *(const short8*)(Ab + (size_t)grow4[rf] * ld + kb);
        #pragma unroll
        for (int r = 0; r < 4; ++r)
            #pragma unroll
            for (int c = 0; c < 4; ++c)
                acc[r * 4 + c] = __builtin_amdgcn_mfma_f32_16x16x32_bf16(
                    a[r], b[c], acc[r * 4 + c], 0, 0, 0);
    }

    const int colgrp = w >> 2;
    const float* ba = colgrp ? b1a : b0a;
    const float* bb = colgrp ? b1b : b0b;
    u16* C  = colgrp ? C2 : C1;
    const int ldc  = colgrp ? ldc2 : ldc1;
    const int relu = colgrp ? relu1 : relu0;
    #pragma unroll
    for (int c = 0; c < 4; ++c) {
        int lc = ((w & 3) * 4 + c) * 16 + m16;
        float bv = (ba ? ba[lc] : 0.f) + (bb ? bb[lc] : 0.f);
        #pragma unroll
        for (int r = 0; r < 4; ++r)
            #pragma unroll
            for (int i = 0; i < 4; ++i) {
                int grow = rowBase + r * 16 + q * 4 + i;
                if (grow < M) {
                    float v = acc[r * 4 + c][i] + bv;
                    if (relu) v = fmaxf(v, 0.f);
                    C[(size_t)grow * ldc + lc] = f2b(v);
                }
            }
    }

    // fused attention row-dots on the C1 half (no bias / no relu path)
    if (dotS && colgrp == 0) {
        #pragma unroll
        for (int r = 0; r < 4; ++r)
            #pragma unroll
            for (int i = 0; i < 4; ++i) {
                float ss = 0.f, sd = 0.f;
                #pragma unroll
                for (int c = 0; c < 4; ++c) {
                    int lc = ((w & 3) * 4 + c) * 16 + m16;
                    float v = b2f(f2b(acc[r * 4 + c][i]));  // match stored bf16
                    ss += v * dotS[lc];
                    sd += v * dotD[lc];
                }
                #pragma unroll
                for (int msk = 1; msk < 16; msk <<= 1) {
                    ss += __shfl_xor(ss, msk, 64);
                    sd += __shfl_xor(sd, msk, 64);
                }
                int grow = rowBase + r * 16 + q * 4 + i;
                if (m16 == 0 && grow < M) {
                    atomicAdd(&oaS[grow], ss);
                    atomicAdd(&oaD[grow], sd);
                }
            }
    }
}

// ---------------------------------------------------------------------------
// fused 3-layer MLP [256->256] relu + classifier + softmax. 512 threads =
// 8 waves sharing a 64-row frag-major LDS panel (32 KB); each wave owns
// 64 rows x 32 cols (8 acc frags -> low VGPR -> high occupancy). B read
// directly per-wave from L2. Final layer stays in the panel; fc 256->5 +
// softmax computed from it (waves 0-3), writing only `out`.
// ---------------------------------------------------------------------------
__global__ __launch_bounds__(512)
void k_mlp3fc(const u16* __restrict__ WTHf,
              const float* Hb1, const float* Hb2, const float* Hb3,
              const float* __restrict__ fcw, const float* __restrict__ fcb,
              const u16* __restrict__ Hin, float* __restrict__ out, int M)
{
    __shared__ u16 P[64 * 256];     // frag-major activation panel (32 KB)

    const int tid = threadIdx.x;
    const int w = tid >> 6, lane = tid & 63;
    const int m16 = lane & 15, q = lane >> 4;
    const int rowBase = blockIdx.x * 64;

    // load panel (global row-major -> fragment-major), 4 chunks/thread
    #pragma unroll
    for (int p = 0; p < 4; ++p) {
        int ch = p * 512 + tid;          // 0..2047 16B-chunks
        int f = ch >> 6, l = ch & 63;    // frag f = kt*4+rf, lane-slot l
        int kt = f >> 2, rf = f & 3;
        int grow = rowBase + rf * 16 + (l & 15);
        if (grow >= M) grow = M - 1;
        int col = kt * 32 + (l >> 4) * 8;
        *(int4*)&P[ch * 8] = *(const int4*)(Hin + (size_t)grow * 256 + col);
    }
    __syncthreads();

    const float* biases[3] = {Hb1, Hb2, Hb3};
    for (int L = 0; L < 3; ++L) {
        const u16* WTf = WTHf + (size_t)L * 65536;
        float4v acc[8] = {};
        #pragma unroll 2
        for (int kt = 0; kt < 8; ++kt) {
            short8 a[4], b[2];
            #pragma unroll
            for (int c = 0; c < 2; ++c) {
                int4 bv = *(const int4*)(WTf + (size_t)(kt * 16 + w * 2 + c) * 512
                                         + lane * 8);
                b[c] = *(short8*)&bv;
            }
            #pragma unroll
            for (int r = 0; r < 4; ++r)
                a[r] = *(const short8*)&P[(kt * 4 + r) * 512 + lane * 8];
            #pragma unroll
            for (int r = 0; r < 4; ++r)
                #pragma unroll
                for (int c = 0; c < 2; ++c)
                    acc[r * 2 + c] = __builtin_amdgcn_mfma_f32_16x16x32_bf16(
                        a[r], b[c], acc[r * 2 + c], 0, 0, 0);
        }
        const float* bias = biases[L];
        __syncthreads();    // all panel reads done before overwrite
        // writeback into fragment-major panel (out col -> next-layer k)
        #pragma unroll
        for (int c = 0; c < 2; ++c) {
            int col = w * 32 + c * 16 + m16;
            float bv = bias[col];
            int kt2 = col >> 5;               // == w
            int l2h = 16 * ((col & 31) >> 3);
            int j2 = col & 7;
            #pragma unroll
            for (int r = 0; r < 4; ++r)
                #pragma unroll
                for (int i = 0; i < 4; ++i) {
                    int l2 = (q * 4 + i) + l2h;
                    P[(size_t)(kt2 * 4 + r) * 512 + l2 * 8 + j2] =
                        f2b(fmaxf(acc[r * 2 + c][i] + bv, 0.f));
                }
        }
        __syncthreads();
    }

    // classifier + softmax from the panel (waves 0-3, rf = w).
    if (w < 4) {
        float p5[5] = {0.f, 0.f, 0.f, 0.f, 0.f};
        #pragma unroll
        for (int kt = 0; kt < 8; ++kt) {
            u16x8 v = *(const u16x8*)&P[(kt * 4 + w) * 512 + lane * 8];
            int colb = kt * 32 + q * 8;
            #pragma unroll
            for (int j = 0; j < 8; ++j) {
                float hv = b2f(v[j]);
                const float* wr = fcw + (size_t)(colb + j) * 5;
                #pragma unroll
                for (int c = 0; c < 5; ++c) p5[c] += hv * wr[c];
            }
        }
        #pragma unroll
        for (int c = 0; c < 5; ++c) {
            p5[c] += __shfl_xor(p5[c], 16, 64);
            p5[c] += __shfl_xor(p5[c], 32, 64);
        }
        int grow = rowBase + w * 16 + m16;
        if (q == 0 && grow < M) {
            float mx = -1e30f;
            #pragma unroll
            for (int c = 0; c < 5; ++c) { p5[c] += fcb[c]; mx = fmaxf(mx, p5[c]); }
            float s = 0.f, e[5];
            #pragma unroll
            for (int c = 0; c < 5; ++c) { e[c] = __expf(p5[c] - mx); s += e[c]; }
            float inv = 1.f / s;
            #pragma unroll
            for (int c = 0; c < 5; ++c) out[(size_t)grow * 5 + c] = e[c] * inv;
        }
    }
}

// ---------------------------------------------------------------------------
extern "C" void kernel_launch(void* const* d_in, const int* in_sizes, int n_in,
                              void* d_out, int out_size, void* d_ws, size_t ws_size,
                              hipStream_t stream)
{
    const float* x    = (const float*)d_in[0];
    const int*   ei   = (const int*)  d_in[1];
    const float* W1   = (const float*)d_in[2];
    const float* as1  = (const float*)d_in[3];
    const float* ad1  = (const float*)d_in[4];
    const float* bc1  = (const float*)d_in[5];
    const float* A1w  = (const float*)d_in[6];
    const float* b1   = (const float*)d_in[7];
    const float* W2   = (const float*)d_in[8];
    const float* as2  = (const float*)d_in[9];
    const float* ad2  = (const float*)d_in[10];
    const float* bc2  = (const float*)d_in[11];
    const float* A2w  = (const float*)d_in[12];
    const float* b2   = (const float*)d_in[13];
    const float* Hw1  = (const float*)d_in[14];
    const float* Hb1  = (const float*)d_in[15];
    const float* Hw2  = (const float*)d_in[16];
    const float* Hb2  = (const float*)d_in[17];
    const float* Hw3  = (const float*)d_in[18];
    const float* Hb3  = (const float*)d_in[19];
    const float* fcw  = (const float*)d_in[20];
    const float* fcb  = (const float*)d_in[21];
    float* out = (float*)d_out;

    const int D = 256;
    const int N = in_sizes[0] / D;
    const int E = in_sizes[1] / 2;

    char* w = (char*)d_ws;
    auto alloc = [&](size_t bytes) {
        char* p = w;
        w += (bytes + 255) & ~(size_t)255;
        return p;
    };
    int*   flag   = (int*)  alloc(256);
    int*   flag64 = (int*)  alloc(256);
    float* a_s    = (float*)alloc((size_t)N * 4);
    float* a_d    = (float*)alloc((size_t)N * 4);
    float* vs1    = (float*)alloc(1024);                 // W1 @ att_src1  [256]
    float* vd1    = (float*)alloc(1024);                 // W1 @ att_dst1  [256]
    int*   deg    = (int*)  alloc((size_t)N * 4);
    int*   cursor = (int*)  alloc((size_t)N * 4);
    int*   offA   = (int*)  alloc((size_t)(N + 1) * 4);
    int*   part   = (int*)  alloc((size_t)((N + 1023) / 1024 + 1) * 4);
    int*   srcs   = (int*)  alloc((size_t)E * 4);
    float* alpha  = (float*)alloc((size_t)E * 4);        // normalized edge weights
    u16*   WT1    = (u16*)  alloc(512 * 512 * 2);        // frag-major [A1w;W1]
    u16*   WT2    = (u16*)  alloc(512 * 512 * 2);        // frag-major [W2|A2w]
    u16*   WTH    = (u16*)  alloc(3 * 256 * 256 * 2);    // frag-major MLP weights
    u16*   BUF1   = (u16*)  alloc((size_t)N * 512 * 2);  // xb|aggx -> h2|res2
    u16*   BUF2   = (u16*)  alloc((size_t)N * 512 * 2);  // hl1 -> out2

    // src32/dst32 alias BUF1 (dead before xb is written)
    int* src32 = (int*)BUF1;
    int* dst32 = src32 + E;

    size_t need = (size_t)(w - (char*)d_ws);             // ~112 MB
    if (ws_size < need) {
        float code = 1000.0f + (float)(ws_size >> 20);
        k_diag<<<(out_size + 255) / 256, 256, 0, stream>>>(out, out_size, code);
        return;
    }

    const int EB  = (E + 255) / 256;
    const int NB4 = (N + 3) / 4;
    const int OB  = (out_size + 255) / 256;
    const int NE  = (N > E ? N : E);
    const int RB64 = (N + 63) / 64;
    const int NBLK = (N + 1023) / 1024;
    const size_t NH2 = (size_t)N * 256;
    u16* XB   = BUF1;            // bf16 cast of x      [N,256]
    u16* AGGX = BUF1 + NH2;      // alpha-aggregated x  [N,256]

    hipMemsetAsync(flag, 0, 4, stream);
    hipMemsetAsync(deg, 0, (size_t)N * 4, stream);

    // ---- edge extraction (+degree count) + CSR by destination ----
    k_detect <<<1, 256, 0, stream>>>(ei, E, flag64);
    k_extract<<<EB, 256, 0, stream>>>(ei, E, flag64, src32, dst32, deg, N);
    k_scan_a <<<NBLK, 256, 0, stream>>>(deg, offA, part, N);
    k_scan_b <<<1, 1024, 0, stream>>>(part, NBLK);
    k_scan_c <<<(N + 255) / 256, 256, 0, stream>>>(offA, cursor, part, N, E);
    k_scatter<<<EB, 256, 0, stream>>>(src32, dst32, cursor, srcs, E, N);
    scan_csr <<<(NE + 255) / 256, 256, 0, stream>>>(offA, srcs, N, E, flag, 1);

    // ---- weight pre-pack (fragment-major bf16, single launch) ----
    k_packAll<<<dim3(32, 16, 5), 64, 0, stream>>>(A1w, W1, W2, A2w,
                                                  Hw1, Hw2, Hw3, WT1, WT2, WTH);

    // ---- attention vectors, then fused cast+dot over x ----
    k_rowdot2f<<<64, 256, 0, stream>>>(W1, 512, 512, as1, ad1, vs1, vd1, 256);
    k_castdot<<<(N + 7) / 8, 256, 0, stream>>>(x, vs1, vd1, XB, a_s, a_d, N);
    k_alpha<<<NB4, 256, 0, stream>>>(offA, srcs, a_s, a_d, alpha, N);

    // a_s/a_d consumed by k_alpha above; zero them for bigfull-2's fused
    // atomic row-dot accumulation (stream order guarantees safety)
    hipMemsetAsync(a_s, 0, (size_t)N * 4, stream);
    hipMemsetAsync(a_d, 0, (size_t)N * 4, stream);

    // ---- aggx = sum_e alpha_e * xb[src_e]  (GAT linearity: agg before W1) ----
    k_aggw<<<NB4, 256, 0, stream>>>(XB, offA, srcs, alpha, nullptr, AGGX, N);

    // ---- layer 1 fused: hl1 = relu([XB|AGGX] @ [A1w;W1] + b1 + bc1) ----
    bigfull<<<RB64, 512, 0, stream>>>(XB, 256, AGGX, 256, WT1,
                                      b1, bc1, b1 + 256, bc1 + 256,
                                      BUF2, 512, BUF2 + 256, 512,
                                      nullptr, nullptr, nullptr, nullptr,
                                      N, 1, 1);

    // ---- layer 2 fused: [h2 | res2] = hl1 @ [W2 | A2w] (+b2+bc2 on res2),
    //      with a_s2/a_d2 = h2·att2 accumulated in the epilogue ----
    bigfull<<<RB64, 512, 0, stream>>>(BUF2, 512, BUF2 + 256, 512, WT2,
                                      nullptr, nullptr, b2, bc2,
                                      BUF1, 256, BUF1 + NH2, 256,
                                      as2, ad2, a_s, a_d,
                                      N, 0, 0);

    k_alpha<<<NB4, 256, 0, stream>>>(offA, srcs, a_s, a_d, alpha, N);
    k_aggw<<<NB4, 256, 0, stream>>>(BUF1, offA, srcs, alpha, BUF1 + NH2, BUF2, N);

    // ---- fused 3-layer MLP + classifier + softmax (reads BUF2, writes out) ----
    k_mlp3fc<<<RB64, 512, 0, stream>>>(WTH, Hb1, Hb2, Hb3, fcw, fcb,
                                       BUF2, out, N);

    k_final_diag<<<OB, 256, 0, stream>>>(flag, out, out_size);
}

// Round 9
// 543.263 us; speedup vs baseline: 1.0905x; 1.0905x over previous
//
#include <hip/hip_runtime.h>

typedef unsigned short u16;
typedef short short8 __attribute__((ext_vector_type(8)));
typedef u16 u16x4 __attribute__((ext_vector_type(4)));
typedef u16 u16x8 __attribute__((ext_vector_type(8)));
typedef float float4v __attribute__((ext_vector_type(4)));

#define NEG_SLOPE 0.2f

static __device__ __forceinline__ float b2f(u16 u) {
    union { unsigned int i; float f; } x; x.i = ((unsigned int)u) << 16; return x.f;
}
static __device__ __forceinline__ u16 f2b(float f) {
    unsigned int u = __float_as_uint(f);
    unsigned int r = (u + 0x7fffu + ((u >> 16) & 1u)) >> 16;
    return (u16)r;
}

// ---------------------------------------------------------------------------
// diagnostics: code 32 = CSR inconsistent; 1000+ = ws too small
// ---------------------------------------------------------------------------
__global__ void k_diag(float* out, int n, float val)
{
    int i = blockIdx.x * 256 + threadIdx.x;
    if (i < n) out[i] = val;
}

__global__ void scan_csr(const int* off, const int* srcs, int N, int E,
                         int* flag, int bit)
{
    int i = blockIdx.x * 256 + threadIdx.x;
    if (i < N) {
        int a = off[i], b = off[i + 1];
        if (a < 0 || b < a || b > E) atomicOr(flag, bit);
    }
    if (i == 0 && off[N] != E) atomicOr(flag, bit);
    if (i < E) {
        if ((unsigned)srcs[i] >= (unsigned)N) atomicOr(flag, bit);
    }
}

__global__ void k_final_diag(const int* flag, float* out, int n)
{
    int f = *flag;
    if (f == 0) return;
    int b = __ffs(f) - 1;
    float val = 32.0f * (b + 1);
    int i = blockIdx.x * 256 + threadIdx.x;
    if (i < n) out[i] = val;
}

// ---------------------------------------------------------------------------
// edge_index dtype probe + canonical int32 extraction (+ degree count fused)
// ---------------------------------------------------------------------------
__global__ void k_detect(const int* ei, int E, int* flag64)
{
    __shared__ int zc;
    if (threadIdx.x == 0) zc = 0;
    __syncthreads();
    int idx = 1 + 2 * (int)threadIdx.x;
    int z = (idx < 2 * E && ei[idx] == 0) ? 1 : 0;
    atomicAdd(&zc, z);
    __syncthreads();
    if (threadIdx.x == 0) *flag64 = (zc >= 200) ? 1 : 0;
}

__global__ void k_extract(const int* ei, int E, const int* flag64,
                          int* src, int* dst, int* deg, int N)
{
    int e = blockIdx.x * 256 + threadIdx.x;
    if (e >= E) return;
    int s, d;
    if (*flag64) {
        s = ei[2 * e];
        d = ei[2 * E + 2 * e];
    } else {
        s = ei[e];
        d = ei[E + e];
    }
    src[e] = s; dst[e] = d;
    if ((unsigned)d < (unsigned)N) atomicAdd(&deg[d], 1);
}

// ---------------------------------------------------------------------------
// device-wide exclusive scan, 3-phase (1024 elems per block in phase A)
// ---------------------------------------------------------------------------
__global__ __launch_bounds__(256)
void k_scan_a(const int* __restrict__ deg, int* __restrict__ off,
              int* __restrict__ partial, int N)
{
    __shared__ int sd[256];
    int tid = threadIdx.x;
    int base = blockIdx.x * 1024;
    int i0 = base + tid * 4;
    int v0 = 0, v1 = 0, v2 = 0, v3 = 0;
    if (i0 < N)     v0 = deg[i0];
    if (i0 + 1 < N) v1 = deg[i0 + 1];
    if (i0 + 2 < N) v2 = deg[i0 + 2];
    if (i0 + 3 < N) v3 = deg[i0 + 3];
    int t = v0 + v1 + v2 + v3;
    sd[tid] = t;
    __syncthreads();
    #pragma unroll
    for (int s = 1; s < 256; s <<= 1) {
        int u = (tid >= s) ? sd[tid - s] : 0;
        __syncthreads();
        sd[tid] += u;
        __syncthreads();
    }
    int excl = sd[tid] - t;                 // exclusive within block
    if (i0 < N)     off[i0]     = excl;
    if (i0 + 1 < N) off[i0 + 1] = excl + v0;
    if (i0 + 2 < N) off[i0 + 2] = excl + v0 + v1;
    if (i0 + 3 < N) off[i0 + 3] = excl + v0 + v1 + v2;
    if (tid == 255) partial[blockIdx.x] = sd[255];
}

__global__ __launch_bounds__(1024)
void k_scan_b(int* partial, int nblk)
{
    __shared__ int sd[1024];
    __shared__ int running;
    int tid = threadIdx.x;
    if (tid == 0) running = 0;
    __syncthreads();
    for (int base = 0; base < nblk; base += 1024) {
        int i = base + tid;
        int v = (i < nblk) ? partial[i] : 0;
        sd[tid] = v;
        __syncthreads();
        for (int s = 1; s < 1024; s <<= 1) {
            int u = (tid >= s) ? sd[tid - s] : 0;
            __syncthreads();
            sd[tid] += u;
            __syncthreads();
        }
        if (i < nblk) partial[i] = sd[tid] - v + running;   // exclusive
        int total = sd[1023];
        __syncthreads();
        if (tid == 0) running += total;
        __syncthreads();
    }
}

__global__ __launch_bounds__(256)
void k_scan_c(int* __restrict__ off, int* __restrict__ cursor,
              const int* __restrict__ partial, int N, int E)
{
    int i = blockIdx.x * 256 + threadIdx.x;
    if (i < N) {
        int v = off[i] + partial[i >> 10];
        off[i] = v;
        cursor[i] = v;
    }
    if (i == 0) off[N] = E;
}

__global__ void k_scatter(const int* src, const int* dst, int* cursor,
                          int* srcs, int E, int N)
{
    int e = blockIdx.x * 256 + threadIdx.x;
    if (e < E) {
        int d = dst[e];
        if ((unsigned)d < (unsigned)N) {
            int p = atomicAdd(&cursor[d], 1);
            if ((unsigned)p < (unsigned)E) srcs[p] = src[e];
        }
    }
}

// ---------------------------------------------------------------------------
// fused fp32->bf16 cast + row dots vs (vs,vd): 8 rows/block, 32 lanes/row.
// ---------------------------------------------------------------------------
__global__ __launch_bounds__(256)
void k_castdot(const float* __restrict__ x, const float* __restrict__ vs,
               const float* __restrict__ vd, u16* __restrict__ xb,
               float* __restrict__ a_s, float* __restrict__ a_d, int N)
{
    int tid = threadIdx.x;
    int rowb = tid >> 5;                // 0..7
    int col8 = (tid & 31) * 8;
    int n = blockIdx.x * 8 + rowb;
    if (n >= N) return;
    const float* xr = x + (size_t)n * 256 + col8;
    float4 v0 = *(const float4*)xr;
    float4 v1 = *(const float4*)(xr + 4);
    int4 w;
    w.x = (int)f2b(v0.x) | ((int)f2b(v0.y) << 16);
    w.y = (int)f2b(v0.z) | ((int)f2b(v0.w) << 16);
    w.z = (int)f2b(v1.x) | ((int)f2b(v1.y) << 16);
    w.w = (int)f2b(v1.z) | ((int)f2b(v1.w) << 16);
    *(int4*)(xb + (size_t)n * 256 + col8) = w;

    float4 s0 = *(const float4*)(vs + col8);
    float4 s1 = *(const float4*)(vs + col8 + 4);
    float4 d0 = *(const float4*)(vd + col8);
    float4 d1 = *(const float4*)(vd + col8 + 4);
    float ss = v0.x*s0.x + v0.y*s0.y + v0.z*s0.z + v0.w*s0.w
             + v1.x*s1.x + v1.y*s1.y + v1.z*s1.z + v1.w*s1.w;
    float sd = v0.x*d0.x + v0.y*d0.y + v0.z*d0.z + v0.w*d0.w
             + v1.x*d1.x + v1.y*d1.y + v1.z*d1.z + v1.w*d1.w;
    #pragma unroll
    for (int m = 16; m; m >>= 1) {
        ss += __shfl_xor(ss, m, 64);
        sd += __shfl_xor(sd, m, 64);
    }
    if ((tid & 31) == 0) { a_s[n] = ss; a_d[n] = sd; }
}

// ---------------------------------------------------------------------------
// fragment-major weight pack, all weights in one launch (blockIdx.z selects)
// out[(kt*NC16 + cf)*512 + l*8 + j] = bf16( W[kt*32+(l>>4)*8+j][cf*16+(l&15)] )
// ---------------------------------------------------------------------------
__global__ __launch_bounds__(64)
void k_packAll(const float* A1w, const float* W1, const float* W2, const float* A2w,
               const float* Hw1, const float* Hw2, const float* Hw3,
               u16* WT1, u16* WT2, u16* WTH)
{
    int z = blockIdx.z;
    const float *in1, *in2; int ksplit, csplit, in_ld, NC16; u16* out;
    if (z == 0)      { in1 = A1w; in2 = W1;  ksplit = 256; csplit = 0;   in_ld = 512; out = WT1; NC16 = 32; }
    else if (z == 1) { in1 = W2;  in2 = A2w; ksplit = 0;   csplit = 256; in_ld = 256; out = WT2; NC16 = 32; }
    else {
        if (blockIdx.x >= 16 || blockIdx.y >= 8) return;
        in1 = (z == 2) ? Hw1 : (z == 3) ? Hw2 : Hw3;
        in2 = nullptr; ksplit = 0; csplit = 0; in_ld = 256; NC16 = 16;
        out = WTH + (size_t)(z - 2) * 65536;
    }
    int l = threadIdx.x;
    int cf = blockIdx.x, kt = blockIdx.y;
    int col = cf * 16 + (l & 15);
    int kbase = kt * 32 + (l >> 4) * 8;
    const float* src = in1;
    int cc = col, koff = 0;
    if (ksplit > 0 && kbase >= ksplit) { src = in2; koff = ksplit; }
    if (csplit > 0 && col >= csplit)   { src = in2; cc = col - csplit; }
    u16* o = out + ((size_t)(kt * NC16 + cf) * 512) + l * 8;
    #pragma unroll
    for (int j = 0; j < 8; ++j)
        o[j] = f2b(src[(size_t)(kbase - koff + j) * in_ld + cc]);
}

// ---------------------------------------------------------------------------
// fp32 row-dot against two fp32 vectors — one wave per row, float4 lanes
// ---------------------------------------------------------------------------
__global__ __launch_bounds__(256)
void k_rowdot2f(const float* __restrict__ A, int ld, int H,
                const float* __restrict__ vs, const float* __restrict__ vd,
                float* a_s, float* a_d, int N)
{
    int wave = threadIdx.x >> 6, lane = threadIdx.x & 63;
    int n = blockIdx.x * 4 + wave;
    if (n >= N) return;
    const float* ar = A + (size_t)n * ld;
    float ss = 0.f, sd = 0.f;
    for (int i = lane * 4; i < H; i += 256) {
        float4 v  = *(const float4*)(ar + i);
        float4 s4 = *(const float4*)(vs + i);
        float4 d4 = *(const float4*)(vd + i);
        ss += v.x * s4.x + v.y * s4.y + v.z * s4.z + v.w * s4.w;
        sd += v.x * d4.x + v.y * d4.y + v.z * d4.z + v.w * d4.w;
    }
    #pragma unroll
    for (int m = 32; m; m >>= 1) {
        ss += __shfl_xor(ss, m, 64);
        sd += __shfl_xor(sd, m, 64);
    }
    if (lane == 0) { a_s[n] = ss; a_d[n] = sd; }
}

// ---------------------------------------------------------------------------
// bf16 row-dot (for layer-2 h2) — one wave per node
// ---------------------------------------------------------------------------
__global__ __launch_bounds__(256)
void k_rowdot2(const u16* h, int ld, int H, const float* vs, const float* vd,
               float* a_s, float* a_d, int N)
{
    int wave = threadIdx.x >> 6, lane = threadIdx.x & 63;
    int n = blockIdx.x * 4 + wave;
    if (n >= N) return;
    const u16* hr = h + (size_t)n * ld;
    float ss = 0.f, sd = 0.f;
    for (int i = lane; i < H; i += 64) {
        float v = b2f(hr[i]);
        ss += v * vs[i];
        sd += v * vd[i];
    }
    #pragma unroll
    for (int m = 32; m; m >>= 1) {
        ss += __shfl_xor(ss, m, 64);
        sd += __shfl_xor(sd, m, 64);
    }
    if (lane == 0) { a_s[n] = ss; a_d[n] = sd; }
}

// ---------------------------------------------------------------------------
// per-dst softmax: exact online max/sum (1 pass) + alpha write (1 pass)
// ---------------------------------------------------------------------------
__global__ __launch_bounds__(256)
void k_alpha(const int* __restrict__ off, const int* __restrict__ srcs,
             const float* __restrict__ a_s, const float* __restrict__ a_d,
             float* __restrict__ alpha, int N)
{
    int wave = threadIdx.x >> 6, lane = threadIdx.x & 63;
    int n = blockIdx.x * 4 + wave;
    if (n >= N) return;
    int base = off[n], end = off[n + 1];
    float adn = a_d[n];
    float m = -1e30f, s = 0.f;
    for (int p = base + lane; p < end; p += 64) {
        int sx = srcs[p];
        sx = ((unsigned)sx < (unsigned)N) ? sx : 0;
        float z = a_s[sx] + adn;
        z = fmaxf(z, NEG_SLOPE * z);          // leaky_relu (slope<1)
        float mn = fmaxf(m, z);
        s = s * __expf(m - mn) + __expf(z - mn);
        m = mn;
    }
    #pragma unroll
    for (int msk = 32; msk; msk >>= 1) {
        float mo = __shfl_xor(m, msk, 64);
        float so = __shfl_xor(s, msk, 64);
        float mn = fmaxf(m, mo);
        s = s * __expf(m - mn) + so * __expf(mo - mn);
        m = mn;
    }
    float inv = 1.f / (s + 1e-16f);
    for (int p = base + lane; p < end; p += 64) {
        int sx = srcs[p];
        sx = ((unsigned)sx < (unsigned)N) ? sx : 0;
        float z = a_s[sx] + adn;
        z = fmaxf(z, NEG_SLOPE * z);
        alpha[p] = __expf(z - m) * inv;
    }
}

// ---------------------------------------------------------------------------
// weighted gather-aggregate, half-wave split: lanes 0-31 edge p, 32-63 edge
// p+1; 16B row loads; 4 edges in flight; one shfl(32) reduce per node.
// ---------------------------------------------------------------------------
__global__ __launch_bounds__(256)
void k_aggw(const u16* __restrict__ rows, const int* __restrict__ off,
            const int* __restrict__ srcs, const float* __restrict__ alpha,
            const u16* __restrict__ add, u16* __restrict__ out, int N)
{
    int wave = threadIdx.x >> 6, lane = threadIdx.x & 63;
    int n = blockIdx.x * 4 + wave;
    if (n >= N) return;
    int base = off[n], end = off[n + 1];
    int half = lane >> 5;
    int c8 = (lane & 31) * 8;
    float acc[8] = {};
    int p = base;
    for (; p + 3 < end; p += 4) {
        int sA = srcs[p + half];
        int sB = srcs[p + 2 + half];
        sA = ((unsigned)sA < (unsigned)N) ? sA : 0;
        sB = ((unsigned)sB < (unsigned)N) ? sB : 0;
        float wA = alpha[p + half];
        float wB = alpha[p + 2 + half];
        u16x8 vA = *(const u16x8*)(rows + (size_t)sA * 256 + c8);
        u16x8 vB = *(const u16x8*)(rows + (size_t)sB * 256 + c8);
        #pragma unroll
        for (int j = 0; j < 8; ++j)
            acc[j] += wA * b2f(vA[j]) + wB * b2f(vB[j]);
    }
    for (; p + 1 < end; p += 2) {
        int sA = srcs[p + half];
        sA = ((unsigned)sA < (unsigned)N) ? sA : 0;
        float wA = alpha[p + half];
        u16x8 vA = *(const u16x8*)(rows + (size_t)sA * 256 + c8);
        #pragma unroll
        for (int j = 0; j < 8; ++j)
            acc[j] += wA * b2f(vA[j]);
    }
    if (p < end) {
        int sA = srcs[p];
        sA = ((unsigned)sA < (unsigned)N) ? sA : 0;
        float wA = half ? 0.f : alpha[p];
        u16x8 vA = *(const u16x8*)(rows + (size_t)sA * 256 + c8);
        #pragma unroll
        for (int j = 0; j < 8; ++j)
            acc[j] += wA * b2f(vA[j]);
    }
    #pragma unroll
    for (int j = 0; j < 8; ++j)
        acc[j] += __shfl_xor(acc[j], 32, 64);
    if (half == 0) {
        size_t ob = (size_t)n * 256 + c8;
        if (add) {
            u16x8 ad8 = *(const u16x8*)(add + ob);
            #pragma unroll
            for (int j = 0; j < 8; ++j) acc[j] += b2f(ad8[j]);
        }
        u16x8 o;
        #pragma unroll
        for (int j = 0; j < 8; ++j) o[j] = f2b(acc[j]);
        *(u16x8*)(out + ob) = o;
    }
}

// ---------------------------------------------------------------------------
// full-width fused MFMA GEMM: BM=64, K=512 (two bf16 A halves of 256 each),
// NC=512 from fragment-major pre-packed WTf. Output split at col 256 into
// (C1, C2) with per-half fp32 bias pairs and relu flags. A read ONCE from HBM.
// 8 waves, each owns a 64x64 tile; all LDS reads base + lane*16 (conflict-
// free); staging is linear int4 copy (bulk prefetch, 2 barriers/kt).
// [Round-8 post-mortem: this LDS-staged form measured fastest; B-direct-L2
//  and barrier-free variants both regressed at ~30% occupancy.]
// ---------------------------------------------------------------------------
__global__ __launch_bounds__(512)
void bigfull(const u16* __restrict__ A1, int lda1,
             const u16* __restrict__ A2, int lda2,
             const u16* __restrict__ WTf,
             const float* b0a, const float* b0b,
             const float* b1a, const float* b1b,
             u16* C1, int ldc1, u16* C2, int ldc2,
             int M, int relu0, int relu1)
{
    __shared__ u16 As[64 * 32];      // frag-major: [rf][lane][8]   (4 KB)
    __shared__ u16 Bs[512 * 32];     // frag-major: [cf][lane][8]  (32 KB)

    const int tid = threadIdx.x;
    const int w = tid >> 6, lane = tid & 63;
    const int m16 = lane & 15, q = lane >> 4;
    const int rowBase = blockIdx.x * 64;

    float4v acc[16] = {};

    for (int k0 = 0; k0 < 512; k0 += 32) {
        const int kt = k0 >> 5;
        __syncthreads();
        if (tid < 256) {   // stage A 64x32 into fragment order
            int rf = tid >> 6, al = tid & 63;
            int grow = rowBase + rf * 16 + (al & 15);
            if (grow >= M) grow = M - 1;          // clamp; value unused
            int kk = k0 + (al >> 4) * 8;
            const u16* src = (kk < 256)
                ? A1 + (size_t)grow * lda1 + kk
                : A2 + (size_t)grow * lda2 + (kk - 256);
            *(int4*)&As[tid * 8] = *(const int4*)src;
        }
        {   // stage B 512x32: pure linear copy of pre-packed fragments
            const u16* wsrc = WTf + (size_t)kt * 16384;
            #pragma unroll
            for (int p = 0; p < 4; ++p) {
                int ch = p * 512 + tid;
                *(int4*)&Bs[ch * 8] = *(const int4*)(wsrc + (size_t)ch * 8);
            }
        }
        __syncthreads();

        short8 a[4], b[4];
        #pragma unroll
        for (int r = 0; r < 4; ++r)
            a[r] = *(const short8*)&As[r * 512 + lane * 8];
        #pragma unroll
        for (int c = 0; c < 4; ++c)
            b[c] = *(const short8*)&Bs[(w * 4 + c) * 512 + lane * 8];
        #pragma unroll
        for (int r = 0; r < 4; ++r)
            #pragma unroll
            for (int c = 0; c < 4; ++c)
                acc[r * 4 + c] = __builtin_amdgcn_mfma_f32_16x16x32_bf16(
                    a[r], b[c], acc[r * 4 + c], 0, 0, 0);
    }

    const int colgrp = w >> 2;
    const float* ba = colgrp ? b1a : b0a;
    const float* bb = colgrp ? b1b : b0b;
    u16* C  = colgrp ? C2 : C1;
    const int ldc  = colgrp ? ldc2 : ldc1;
    const int relu = colgrp ? relu1 : relu0;
    #pragma unroll
    for (int c = 0; c < 4; ++c) {
        int lc = ((w & 3) * 4 + c) * 16 + m16;
        float bv = (ba ? ba[lc] : 0.f) + (bb ? bb[lc] : 0.f);
        #pragma unroll
        for (int r = 0; r < 4; ++r)
            #pragma unroll
            for (int i = 0; i < 4; ++i) {
                int grow = rowBase + r * 16 + q * 4 + i;
                if (grow < M) {
                    float v = acc[r * 4 + c][i] + bv;
                    if (relu) v = fmaxf(v, 0.f);
                    C[(size_t)grow * ldc + lc] = f2b(v);
                }
            }
    }
}

// ---------------------------------------------------------------------------
// fused 3-layer MLP [256->256] relu + classifier + softmax. 512 threads =
// 8 waves sharing a 64-row frag-major LDS panel (32 KB); each wave owns
// 64 rows x 32 cols (8 acc frags -> low VGPR -> high occupancy). B read
// directly per-wave from L2. Final layer stays in the panel; fc 256->5 +
// softmax computed from it (waves 0-3), writing only `out`.
// ---------------------------------------------------------------------------
__global__ __launch_bounds__(512)
void k_mlp3fc(const u16* __restrict__ WTHf,
              const float* Hb1, const float* Hb2, const float* Hb3,
              const float* __restrict__ fcw, const float* __restrict__ fcb,
              const u16* __restrict__ Hin, float* __restrict__ out, int M)
{
    __shared__ u16 P[64 * 256];     // frag-major activation panel (32 KB)

    const int tid = threadIdx.x;
    const int w = tid >> 6, lane = tid & 63;
    const int m16 = lane & 15, q = lane >> 4;
    const int rowBase = blockIdx.x * 64;

    // load panel (global row-major -> fragment-major), 4 chunks/thread
    #pragma unroll
    for (int p = 0; p < 4; ++p) {
        int ch = p * 512 + tid;          // 0..2047 16B-chunks
        int f = ch >> 6, l = ch & 63;    // frag f = kt*4+rf, lane-slot l
        int kt = f >> 2, rf = f & 3;
        int grow = rowBase + rf * 16 + (l & 15);
        if (grow >= M) grow = M - 1;
        int col = kt * 32 + (l >> 4) * 8;
        *(int4*)&P[ch * 8] = *(const int4*)(Hin + (size_t)grow * 256 + col);
    }
    __syncthreads();

    const float* biases[3] = {Hb1, Hb2, Hb3};
    for (int L = 0; L < 3; ++L) {
        const u16* WTf = WTHf + (size_t)L * 65536;
        float4v acc[8] = {};
        #pragma unroll 2
        for (int kt = 0; kt < 8; ++kt) {
            short8 a[4], b[2];
            #pragma unroll
            for (int c = 0; c < 2; ++c) {
                int4 bv = *(const int4*)(WTf + (size_t)(kt * 16 + w * 2 + c) * 512
                                         + lane * 8);
                b[c] = *(short8*)&bv;
            }
            #pragma unroll
            for (int r = 0; r < 4; ++r)
                a[r] = *(const short8*)&P[(kt * 4 + r) * 512 + lane * 8];
            #pragma unroll
            for (int r = 0; r < 4; ++r)
                #pragma unroll
                for (int c = 0; c < 2; ++c)
                    acc[r * 2 + c] = __builtin_amdgcn_mfma_f32_16x16x32_bf16(
                        a[r], b[c], acc[r * 2 + c], 0, 0, 0);
        }
        const float* bias = biases[L];
        __syncthreads();    // all panel reads done before overwrite
        // writeback into fragment-major panel (out col -> next-layer k)
        #pragma unroll
        for (int c = 0; c < 2; ++c) {
            int col = w * 32 + c * 16 + m16;
            float bv = bias[col];
            int kt2 = col >> 5;               // == w
            int l2h = 16 * ((col & 31) >> 3);
            int j2 = col & 7;
            #pragma unroll
            for (int r = 0; r < 4; ++r)
                #pragma unroll
                for (int i = 0; i < 4; ++i) {
                    int l2 = (q * 4 + i) + l2h;
                    P[(size_t)(kt2 * 4 + r) * 512 + l2 * 8 + j2] =
                        f2b(fmaxf(acc[r * 2 + c][i] + bv, 0.f));
                }
        }
        __syncthreads();
    }

    // classifier + softmax from the panel (waves 0-3, rf = w).
    if (w < 4) {
        float p5[5] = {0.f, 0.f, 0.f, 0.f, 0.f};
        #pragma unroll
        for (int kt = 0; kt < 8; ++kt) {
            u16x8 v = *(const u16x8*)&P[(kt * 4 + w) * 512 + lane * 8];
            int colb = kt * 32 + q * 8;
            #pragma unroll
            for (int j = 0; j < 8; ++j) {
                float hv = b2f(v[j]);
                const float* wr = fcw + (size_t)(colb + j) * 5;
                #pragma unroll
                for (int c = 0; c < 5; ++c) p5[c] += hv * wr[c];
            }
        }
        #pragma unroll
        for (int c = 0; c < 5; ++c) {
            p5[c] += __shfl_xor(p5[c], 16, 64);
            p5[c] += __shfl_xor(p5[c], 32, 64);
        }
        int grow = rowBase + w * 16 + m16;
        if (q == 0 && grow < M) {
            float mx = -1e30f;
            #pragma unroll
            for (int c = 0; c < 5; ++c) { p5[c] += fcb[c]; mx = fmaxf(mx, p5[c]); }
            float s = 0.f, e[5];
            #pragma unroll
            for (int c = 0; c < 5; ++c) { e[c] = __expf(p5[c] - mx); s += e[c]; }
            float inv = 1.f / s;
            #pragma unroll
            for (int c = 0; c < 5; ++c) out[(size_t)grow * 5 + c] = e[c] * inv;
        }
    }
}

// ---------------------------------------------------------------------------
extern "C" void kernel_launch(void* const* d_in, const int* in_sizes, int n_in,
                              void* d_out, int out_size, void* d_ws, size_t ws_size,
                              hipStream_t stream)
{
    const float* x    = (const float*)d_in[0];
    const int*   ei   = (const int*)  d_in[1];
    const float* W1   = (const float*)d_in[2];
    const float* as1  = (const float*)d_in[3];
    const float* ad1  = (const float*)d_in[4];
    const float* bc1  = (const float*)d_in[5];
    const float* A1w  = (const float*)d_in[6];
    const float* b1   = (const float*)d_in[7];
    const float* W2   = (const float*)d_in[8];
    const float* as2  = (const float*)d_in[9];
    const float* ad2  = (const float*)d_in[10];
    const float* bc2  = (const float*)d_in[11];
    const float* A2w  = (const float*)d_in[12];
    const float* b2   = (const float*)d_in[13];
    const float* Hw1  = (const float*)d_in[14];
    const float* Hb1  = (const float*)d_in[15];
    const float* Hw2  = (const float*)d_in[16];
    const float* Hb2  = (const float*)d_in[17];
    const float* Hw3  = (const float*)d_in[18];
    const float* Hb3  = (const float*)d_in[19];
    const float* fcw  = (const float*)d_in[20];
    const float* fcb  = (const float*)d_in[21];
    float* out = (float*)d_out;

    const int D = 256;
    const int N = in_sizes[0] / D;
    const int E = in_sizes[1] / 2;

    char* w = (char*)d_ws;
    auto alloc = [&](size_t bytes) {
        char* p = w;
        w += (bytes + 255) & ~(size_t)255;
        return p;
    };
    int*   flag   = (int*)  alloc(256);
    int*   flag64 = (int*)  alloc(256);
    float* a_s    = (float*)alloc((size_t)N * 4);
    float* a_d    = (float*)alloc((size_t)N * 4);
    float* vs1    = (float*)alloc(1024);                 // W1 @ att_src1  [256]
    float* vd1    = (float*)alloc(1024);                 // W1 @ att_dst1  [256]
    int*   deg    = (int*)  alloc((size_t)N * 4);
    int*   cursor = (int*)  alloc((size_t)N * 4);
    int*   offA   = (int*)  alloc((size_t)(N + 1) * 4);
    int*   part   = (int*)  alloc((size_t)((N + 1023) / 1024 + 1) * 4);
    int*   srcs   = (int*)  alloc((size_t)E * 4);
    float* alpha  = (float*)alloc((size_t)E * 4);        // normalized edge weights
    u16*   WT1    = (u16*)  alloc(512 * 512 * 2);        // frag-major [A1w;W1]
    u16*   WT2    = (u16*)  alloc(512 * 512 * 2);        // frag-major [W2|A2w]
    u16*   WTH    = (u16*)  alloc(3 * 256 * 256 * 2);    // frag-major MLP weights
    u16*   BUF1   = (u16*)  alloc((size_t)N * 512 * 2);  // xb|aggx -> h2|res2
    u16*   BUF2   = (u16*)  alloc((size_t)N * 512 * 2);  // hl1 -> out2

    // src32/dst32 alias BUF1 (dead before xb is written)
    int* src32 = (int*)BUF1;
    int* dst32 = src32 + E;

    size_t need = (size_t)(w - (char*)d_ws);             // ~112 MB
    if (ws_size < need) {
        float code = 1000.0f + (float)(ws_size >> 20);
        k_diag<<<(out_size + 255) / 256, 256, 0, stream>>>(out, out_size, code);
        return;
    }

    const int EB  = (E + 255) / 256;
    const int NB4 = (N + 3) / 4;
    const int OB  = (out_size + 255) / 256;
    const int NE  = (N > E ? N : E);
    const int RB64 = (N + 63) / 64;
    const int NBLK = (N + 1023) / 1024;
    const size_t NH2 = (size_t)N * 256;
    u16* XB   = BUF1;            // bf16 cast of x      [N,256]
    u16* AGGX = BUF1 + NH2;      // alpha-aggregated x  [N,256]

    hipMemsetAsync(flag, 0, 4, stream);
    hipMemsetAsync(deg, 0, (size_t)N * 4, stream);

    // ---- edge extraction (+degree count) + CSR by destination ----
    k_detect <<<1, 256, 0, stream>>>(ei, E, flag64);
    k_extract<<<EB, 256, 0, stream>>>(ei, E, flag64, src32, dst32, deg, N);
    k_scan_a <<<NBLK, 256, 0, stream>>>(deg, offA, part, N);
    k_scan_b <<<1, 1024, 0, stream>>>(part, NBLK);
    k_scan_c <<<(N + 255) / 256, 256, 0, stream>>>(offA, cursor, part, N, E);
    k_scatter<<<EB, 256, 0, stream>>>(src32, dst32, cursor, srcs, E, N);
    scan_csr <<<(NE + 255) / 256, 256, 0, stream>>>(offA, srcs, N, E, flag, 1);

    // ---- weight pre-pack (fragment-major bf16, single launch) ----
    k_packAll<<<dim3(32, 16, 5), 64, 0, stream>>>(A1w, W1, W2, A2w,
                                                  Hw1, Hw2, Hw3, WT1, WT2, WTH);

    // ---- attention vectors, then fused cast+dot over x ----
    k_rowdot2f<<<64, 256, 0, stream>>>(W1, 512, 512, as1, ad1, vs1, vd1, 256);
    k_castdot<<<(N + 7) / 8, 256, 0, stream>>>(x, vs1, vd1, XB, a_s, a_d, N);
    k_alpha<<<NB4, 256, 0, stream>>>(offA, srcs, a_s, a_d, alpha, N);

    // ---- aggx = sum_e alpha_e * xb[src_e]  (GAT linearity: agg before W1) ----
    k_aggw<<<NB4, 256, 0, stream>>>(XB, offA, srcs, alpha, nullptr, AGGX, N);

    // ---- layer 1 fused: hl1 = relu([XB|AGGX] @ [A1w;W1] + b1 + bc1) ----
    bigfull<<<RB64, 512, 0, stream>>>(XB, 256, AGGX, 256, WT1,
                                      b1, bc1, b1 + 256, bc1 + 256,
                                      BUF2, 512, BUF2 + 256, 512, N, 1, 1);

    // ---- layer 2 fused: [h2 | res2] = hl1 @ [W2 | A2w] (+b2+bc2 on res2) ----
    bigfull<<<RB64, 512, 0, stream>>>(BUF2, 512, BUF2 + 256, 512, WT2,
                                      nullptr, nullptr, b2, bc2,
                                      BUF1, 256, BUF1 + NH2, 256, N, 0, 0);

    k_rowdot2<<<NB4, 256, 0, stream>>>(BUF1, 256, 256, as2, ad2, a_s, a_d, N);
    k_alpha<<<NB4, 256, 0, stream>>>(offA, srcs, a_s, a_d, alpha, N);
    k_aggw<<<NB4, 256, 0, stream>>>(BUF1, offA, srcs, alpha, BUF1 + NH2, BUF2, N);

    // ---- fused 3-layer MLP + classifier + softmax (reads BUF2, writes out) ----
    k_mlp3fc<<<RB64, 512, 0, stream>>>(WTH, Hb1, Hb2, Hb3, fcw, fcb,
                                       BUF2, out, N);

    k_final_diag<<<OB, 256, 0, stream>>>(flag, out, out_size);
}

// Round 10
// 541.725 us; speedup vs baseline: 1.0936x; 1.0028x over previous
//
#include <hip/hip_runtime.h>

typedef unsigned short u16;
typedef short short8 __attribute__((ext_vector_type(8)));
typedef u16 u16x4 __attribute__((ext_vector_type(4)));
typedef u16 u16x8 __attribute__((ext_vector_type(8)));
typedef float float4v __attribute__((ext_vector_type(4)));

#define NEG_SLOPE 0.2f

#define GLOAD_LDS16(g, l) __builtin_amdgcn_global_load_lds(                    \
    (const __attribute__((address_space(1))) void*)(g),                        \
    (__attribute__((address_space(3))) void*)(l), 16, 0, 0)

static __device__ __forceinline__ float b2f(u16 u) {
    union { unsigned int i; float f; } x; x.i = ((unsigned int)u) << 16; return x.f;
}
static __device__ __forceinline__ u16 f2b(float f) {
    unsigned int u = __float_as_uint(f);
    unsigned int r = (u + 0x7fffu + ((u >> 16) & 1u)) >> 16;
    return (u16)r;
}

// ---------------------------------------------------------------------------
// diagnostics: code 32 = CSR inconsistent; 1000+ = ws too small
// ---------------------------------------------------------------------------
__global__ void k_diag(float* out, int n, float val)
{
    int i = blockIdx.x * 256 + threadIdx.x;
    if (i < n) out[i] = val;
}

__global__ void scan_csr(const int* off, const int* srcs, int N, int E,
                         int* flag, int bit)
{
    int i = blockIdx.x * 256 + threadIdx.x;
    if (i < N) {
        int a = off[i], b = off[i + 1];
        if (a < 0 || b < a || b > E) atomicOr(flag, bit);
    }
    if (i == 0 && off[N] != E) atomicOr(flag, bit);
    if (i < E) {
        if ((unsigned)srcs[i] >= (unsigned)N) atomicOr(flag, bit);
    }
}

__global__ void k_final_diag(const int* flag, float* out, int n)
{
    int f = *flag;
    if (f == 0) return;
    int b = __ffs(f) - 1;
    float val = 32.0f * (b + 1);
    int i = blockIdx.x * 256 + threadIdx.x;
    if (i < n) out[i] = val;
}

// ---------------------------------------------------------------------------
// edge_index dtype probe + canonical int32 extraction (+ degree count fused)
// ---------------------------------------------------------------------------
__global__ void k_detect(const int* ei, int E, int* flag64)
{
    __shared__ int zc;
    if (threadIdx.x == 0) zc = 0;
    __syncthreads();
    int idx = 1 + 2 * (int)threadIdx.x;
    int z = (idx < 2 * E && ei[idx] == 0) ? 1 : 0;
    atomicAdd(&zc, z);
    __syncthreads();
    if (threadIdx.x == 0) *flag64 = (zc >= 200) ? 1 : 0;
}

__global__ void k_extract(const int* ei, int E, const int* flag64,
                          int* src, int* dst, int* deg, int N)
{
    int e = blockIdx.x * 256 + threadIdx.x;
    if (e >= E) return;
    int s, d;
    if (*flag64) {
        s = ei[2 * e];
        d = ei[2 * E + 2 * e];
    } else {
        s = ei[e];
        d = ei[E + e];
    }
    src[e] = s; dst[e] = d;
    if ((unsigned)d < (unsigned)N) atomicAdd(&deg[d], 1);
}

// ---------------------------------------------------------------------------
// device-wide exclusive scan, 3-phase (1024 elems per block in phase A)
// ---------------------------------------------------------------------------
__global__ __launch_bounds__(256)
void k_scan_a(const int* __restrict__ deg, int* __restrict__ off,
              int* __restrict__ partial, int N)
{
    __shared__ int sd[256];
    int tid = threadIdx.x;
    int base = blockIdx.x * 1024;
    int i0 = base + tid * 4;
    int v0 = 0, v1 = 0, v2 = 0, v3 = 0;
    if (i0 < N)     v0 = deg[i0];
    if (i0 + 1 < N) v1 = deg[i0 + 1];
    if (i0 + 2 < N) v2 = deg[i0 + 2];
    if (i0 + 3 < N) v3 = deg[i0 + 3];
    int t = v0 + v1 + v2 + v3;
    sd[tid] = t;
    __syncthreads();
    #pragma unroll
    for (int s = 1; s < 256; s <<= 1) {
        int u = (tid >= s) ? sd[tid - s] : 0;
        __syncthreads();
        sd[tid] += u;
        __syncthreads();
    }
    int excl = sd[tid] - t;                 // exclusive within block
    if (i0 < N)     off[i0]     = excl;
    if (i0 + 1 < N) off[i0 + 1] = excl + v0;
    if (i0 + 2 < N) off[i0 + 2] = excl + v0 + v1;
    if (i0 + 3 < N) off[i0 + 3] = excl + v0 + v1 + v2;
    if (tid == 255) partial[blockIdx.x] = sd[255];
}

__global__ __launch_bounds__(1024)
void k_scan_b(int* partial, int nblk)
{
    __shared__ int sd[1024];
    __shared__ int running;
    int tid = threadIdx.x;
    if (tid == 0) running = 0;
    __syncthreads();
    for (int base = 0; base < nblk; base += 1024) {
        int i = base + tid;
        int v = (i < nblk) ? partial[i] : 0;
        sd[tid] = v;
        __syncthreads();
        for (int s = 1; s < 1024; s <<= 1) {
            int u = (tid >= s) ? sd[tid - s] : 0;
            __syncthreads();
            sd[tid] += u;
            __syncthreads();
        }
        if (i < nblk) partial[i] = sd[tid] - v + running;   // exclusive
        int total = sd[1023];
        __syncthreads();
        if (tid == 0) running += total;
        __syncthreads();
    }
}

__global__ __launch_bounds__(256)
void k_scan_c(int* __restrict__ off, int* __restrict__ cursor,
              const int* __restrict__ partial, int N, int E)
{
    int i = blockIdx.x * 256 + threadIdx.x;
    if (i < N) {
        int v = off[i] + partial[i >> 10];
        off[i] = v;
        cursor[i] = v;
    }
    if (i == 0) off[N] = E;
}

__global__ void k_scatter(const int* src, const int* dst, int* cursor,
                          int* srcs, int E, int N)
{
    int e = blockIdx.x * 256 + threadIdx.x;
    if (e < E) {
        int d = dst[e];
        if ((unsigned)d < (unsigned)N) {
            int p = atomicAdd(&cursor[d], 1);
            if ((unsigned)p < (unsigned)E) srcs[p] = src[e];
        }
    }
}

// ---------------------------------------------------------------------------
// fused fp32->bf16 cast + row dots vs (vs,vd): 8 rows/block, 32 lanes/row.
// ---------------------------------------------------------------------------
__global__ __launch_bounds__(256)
void k_castdot(const float* __restrict__ x, const float* __restrict__ vs,
               const float* __restrict__ vd, u16* __restrict__ xb,
               float* __restrict__ a_s, float* __restrict__ a_d, int N)
{
    int tid = threadIdx.x;
    int rowb = tid >> 5;                // 0..7
    int col8 = (tid & 31) * 8;
    int n = blockIdx.x * 8 + rowb;
    if (n >= N) return;
    const float* xr = x + (size_t)n * 256 + col8;
    float4 v0 = *(const float4*)xr;
    float4 v1 = *(const float4*)(xr + 4);
    int4 w;
    w.x = (int)f2b(v0.x) | ((int)f2b(v0.y) << 16);
    w.y = (int)f2b(v0.z) | ((int)f2b(v0.w) << 16);
    w.z = (int)f2b(v1.x) | ((int)f2b(v1.y) << 16);
    w.w = (int)f2b(v1.z) | ((int)f2b(v1.w) << 16);
    *(int4*)(xb + (size_t)n * 256 + col8) = w;

    float4 s0 = *(const float4*)(vs + col8);
    float4 s1 = *(const float4*)(vs + col8 + 4);
    float4 d0 = *(const float4*)(vd + col8);
    float4 d1 = *(const float4*)(vd + col8 + 4);
    float ss = v0.x*s0.x + v0.y*s0.y + v0.z*s0.z + v0.w*s0.w
             + v1.x*s1.x + v1.y*s1.y + v1.z*s1.z + v1.w*s1.w;
    float sd = v0.x*d0.x + v0.y*d0.y + v0.z*d0.z + v0.w*d0.w
             + v1.x*d1.x + v1.y*d1.y + v1.z*d1.z + v1.w*d1.w;
    #pragma unroll
    for (int m = 16; m; m >>= 1) {
        ss += __shfl_xor(ss, m, 64);
        sd += __shfl_xor(sd, m, 64);
    }
    if ((tid & 31) == 0) { a_s[n] = ss; a_d[n] = sd; }
}

// ---------------------------------------------------------------------------
// fragment-major weight pack, all weights in one launch (blockIdx.z selects)
// out[(kt*NC16 + cf)*512 + l*8 + j] = bf16( W[kt*32+(l>>4)*8+j][cf*16+(l&15)] )
// ---------------------------------------------------------------------------
__global__ __launch_bounds__(64)
void k_packAll(const float* A1w, const float* W1, const float* W2, const float* A2w,
               const float* Hw1, const float* Hw2, const float* Hw3,
               u16* WT1, u16* WT2, u16* WTH)
{
    int z = blockIdx.z;
    const float *in1, *in2; int ksplit, csplit, in_ld, NC16; u16* out;
    if (z == 0)      { in1 = A1w; in2 = W1;  ksplit = 256; csplit = 0;   in_ld = 512; out = WT1; NC16 = 32; }
    else if (z == 1) { in1 = W2;  in2 = A2w; ksplit = 0;   csplit = 256; in_ld = 256; out = WT2; NC16 = 32; }
    else {
        if (blockIdx.x >= 16 || blockIdx.y >= 8) return;
        in1 = (z == 2) ? Hw1 : (z == 3) ? Hw2 : Hw3;
        in2 = nullptr; ksplit = 0; csplit = 0; in_ld = 256; NC16 = 16;
        out = WTH + (size_t)(z - 2) * 65536;
    }
    int l = threadIdx.x;
    int cf = blockIdx.x, kt = blockIdx.y;
    int col = cf * 16 + (l & 15);
    int kbase = kt * 32 + (l >> 4) * 8;
    const float* src = in1;
    int cc = col, koff = 0;
    if (ksplit > 0 && kbase >= ksplit) { src = in2; koff = ksplit; }
    if (csplit > 0 && col >= csplit)   { src = in2; cc = col - csplit; }
    u16* o = out + ((size_t)(kt * NC16 + cf) * 512) + l * 8;
    #pragma unroll
    for (int j = 0; j < 8; ++j)
        o[j] = f2b(src[(size_t)(kbase - koff + j) * in_ld + cc]);
}

// ---------------------------------------------------------------------------
// fp32 row-dot against two fp32 vectors — one wave per row, float4 lanes
// ---------------------------------------------------------------------------
__global__ __launch_bounds__(256)
void k_rowdot2f(const float* __restrict__ A, int ld, int H,
                const float* __restrict__ vs, const float* __restrict__ vd,
                float* a_s, float* a_d, int N)
{
    int wave = threadIdx.x >> 6, lane = threadIdx.x & 63;
    int n = blockIdx.x * 4 + wave;
    if (n >= N) return;
    const float* ar = A + (size_t)n * ld;
    float ss = 0.f, sd = 0.f;
    for (int i = lane * 4; i < H; i += 256) {
        float4 v  = *(const float4*)(ar + i);
        float4 s4 = *(const float4*)(vs + i);
        float4 d4 = *(const float4*)(vd + i);
        ss += v.x * s4.x + v.y * s4.y + v.z * s4.z + v.w * s4.w;
        sd += v.x * d4.x + v.y * d4.y + v.z * d4.z + v.w * d4.w;
    }
    #pragma unroll
    for (int m = 32; m; m >>= 1) {
        ss += __shfl_xor(ss, m, 64);
        sd += __shfl_xor(sd, m, 64);
    }
    if (lane == 0) { a_s[n] = ss; a_d[n] = sd; }
}

// ---------------------------------------------------------------------------
// bf16 row-dot (for layer-2 h2) — one wave per node
// ---------------------------------------------------------------------------
__global__ __launch_bounds__(256)
void k_rowdot2(const u16* h, int ld, int H, const float* vs, const float* vd,
               float* a_s, float* a_d, int N)
{
    int wave = threadIdx.x >> 6, lane = threadIdx.x & 63;
    int n = blockIdx.x * 4 + wave;
    if (n >= N) return;
    const u16* hr = h + (size_t)n * ld;
    float ss = 0.f, sd = 0.f;
    for (int i = lane; i < H; i += 64) {
        float v = b2f(hr[i]);
        ss += v * vs[i];
        sd += v * vd[i];
    }
    #pragma unroll
    for (int m = 32; m; m >>= 1) {
        ss += __shfl_xor(ss, m, 64);
        sd += __shfl_xor(sd, m, 64);
    }
    if (lane == 0) { a_s[n] = ss; a_d[n] = sd; }
}

// ---------------------------------------------------------------------------
// per-dst softmax: exact online max/sum (1 pass) + alpha write (1 pass)
// ---------------------------------------------------------------------------
__global__ __launch_bounds__(256)
void k_alpha(const int* __restrict__ off, const int* __restrict__ srcs,
             const float* __restrict__ a_s, const float* __restrict__ a_d,
             float* __restrict__ alpha, int N)
{
    int wave = threadIdx.x >> 6, lane = threadIdx.x & 63;
    int n = blockIdx.x * 4 + wave;
    if (n >= N) return;
    int base = off[n], end = off[n + 1];
    float adn = a_d[n];
    float m = -1e30f, s = 0.f;
    for (int p = base + lane; p < end; p += 64) {
        int sx = srcs[p];
        sx = ((unsigned)sx < (unsigned)N) ? sx : 0;
        float z = a_s[sx] + adn;
        z = fmaxf(z, NEG_SLOPE * z);          // leaky_relu (slope<1)
        float mn = fmaxf(m, z);
        s = s * __expf(m - mn) + __expf(z - mn);
        m = mn;
    }
    #pragma unroll
    for (int msk = 32; msk; msk >>= 1) {
        float mo = __shfl_xor(m, msk, 64);
        float so = __shfl_xor(s, msk, 64);
        float mn = fmaxf(m, mo);
        s = s * __expf(m - mn) + so * __expf(mo - mn);
        m = mn;
    }
    float inv = 1.f / (s + 1e-16f);
    for (int p = base + lane; p < end; p += 64) {
        int sx = srcs[p];
        sx = ((unsigned)sx < (unsigned)N) ? sx : 0;
        float z = a_s[sx] + adn;
        z = fmaxf(z, NEG_SLOPE * z);
        alpha[p] = __expf(z - m) * inv;
    }
}

// ---------------------------------------------------------------------------
// weighted gather-aggregate, half-wave split: lanes 0-31 edge p, 32-63 edge
// p+1; 16B row loads; 4 edges in flight; one shfl(32) reduce per node.
// ---------------------------------------------------------------------------
__global__ __launch_bounds__(256)
void k_aggw(const u16* __restrict__ rows, const int* __restrict__ off,
            const int* __restrict__ srcs, const float* __restrict__ alpha,
            const u16* __restrict__ add, u16* __restrict__ out, int N)
{
    int wave = threadIdx.x >> 6, lane = threadIdx.x & 63;
    int n = blockIdx.x * 4 + wave;
    if (n >= N) return;
    int base = off[n], end = off[n + 1];
    int half = lane >> 5;
    int c8 = (lane & 31) * 8;
    float acc[8] = {};
    int p = base;
    for (; p + 3 < end; p += 4) {
        int sA = srcs[p + half];
        int sB = srcs[p + 2 + half];
        sA = ((unsigned)sA < (unsigned)N) ? sA : 0;
        sB = ((unsigned)sB < (unsigned)N) ? sB : 0;
        float wA = alpha[p + half];
        float wB = alpha[p + 2 + half];
        u16x8 vA = *(const u16x8*)(rows + (size_t)sA * 256 + c8);
        u16x8 vB = *(const u16x8*)(rows + (size_t)sB * 256 + c8);
        #pragma unroll
        for (int j = 0; j < 8; ++j)
            acc[j] += wA * b2f(vA[j]) + wB * b2f(vB[j]);
    }
    for (; p + 1 < end; p += 2) {
        int sA = srcs[p + half];
        sA = ((unsigned)sA < (unsigned)N) ? sA : 0;
        float wA = alpha[p + half];
        u16x8 vA = *(const u16x8*)(rows + (size_t)sA * 256 + c8);
        #pragma unroll
        for (int j = 0; j < 8; ++j)
            acc[j] += wA * b2f(vA[j]);
    }
    if (p < end) {
        int sA = srcs[p];
        sA = ((unsigned)sA < (unsigned)N) ? sA : 0;
        float wA = half ? 0.f : alpha[p];
        u16x8 vA = *(const u16x8*)(rows + (size_t)sA * 256 + c8);
        #pragma unroll
        for (int j = 0; j < 8; ++j)
            acc[j] += wA * b2f(vA[j]);
    }
    #pragma unroll
    for (int j = 0; j < 8; ++j)
        acc[j] += __shfl_xor(acc[j], 32, 64);
    if (half == 0) {
        size_t ob = (size_t)n * 256 + c8;
        if (add) {
            u16x8 ad8 = *(const u16x8*)(add + ob);
            #pragma unroll
            for (int j = 0; j < 8; ++j) acc[j] += b2f(ad8[j]);
        }
        u16x8 o;
        #pragma unroll
        for (int j = 0; j < 8; ++j) o[j] = f2b(acc[j]);
        *(u16x8*)(out + ob) = o;
    }
}

// ---------------------------------------------------------------------------
// full-width fused MFMA GEMM: BM=64, K=512 (two bf16 A halves of 256 each),
// NC=512 from fragment-major pre-packed WTf. Output split at col 256 into
// (C1, C2) with per-half fp32 bias pairs and relu flags. A read ONCE from HBM.
// 8 waves, each owns a 64x64 tile; all LDS reads base + lane*16 (conflict-
// free). Staging now via async global_load_lds width=16 (wave-uniform LDS
// base + lane*16, per-lane global src) — no VGPR round-trip, no ds_write.
// ---------------------------------------------------------------------------
__global__ __launch_bounds__(512)
void bigfull(const u16* __restrict__ A1, int lda1,
             const u16* __restrict__ A2, int lda2,
             const u16* __restrict__ WTf,
             const float* b0a, const float* b0b,
             const float* b1a, const float* b1b,
             u16* C1, int ldc1, u16* C2, int ldc2,
             int M, int relu0, int relu1)
{
    __shared__ u16 As[64 * 32];      // frag-major: [rf][lane][8]   (4 KB)
    __shared__ u16 Bs[512 * 32];     // frag-major: [cf][lane][8]  (32 KB)

    const int tid = threadIdx.x;
    const int w = tid >> 6, lane = tid & 63;
    const int m16 = lane & 15, q = lane >> 4;
    const int rowBase = blockIdx.x * 64;

    // waves 0-3 stage row-fragment rf = w: per-lane source row (clamped)
    int garow = rowBase + (w & 3) * 16 + m16;
    if (garow >= M) garow = M - 1;          // clamp; value unused when OOB

    float4v acc[16] = {};

    for (int k0 = 0; k0 < 512; k0 += 32) {
        const int kt = k0 >> 5;
        __syncthreads();
        if (w < 4) {   // stage A 64x32 into fragment order (async, 16B/lane)
            int kk = k0 + q * 8;
            const u16* src = (kk < 256)
                ? A1 + (size_t)garow * lda1 + kk
                : A2 + (size_t)garow * lda2 + (kk - 256);
            GLOAD_LDS16(src, &As[w * 512]);
        }
        {   // stage B 512x32: linear async copy of pre-packed fragments
            const u16* wsrc = WTf + (size_t)kt * 16384;
            #pragma unroll
            for (int p = 0; p < 4; ++p) {
                int chb = p * 512 + w * 64;          // wave-uniform chunk base
                GLOAD_LDS16(wsrc + ((size_t)chb + lane) * 8, &Bs[chb * 8]);
            }
        }
        __syncthreads();

        short8 a[4], b[4];
        #pragma unroll
        for (int r = 0; r < 4; ++r)
            a[r] = *(const short8*)&As[r * 512 + lane * 8];
        #pragma unroll
        for (int c = 0; c < 4; ++c)
            b[c] = *(const short8*)&Bs[(w * 4 + c) * 512 + lane * 8];
        #pragma unroll
        for (int r = 0; r < 4; ++r)
            #pragma unroll
            for (int c = 0; c < 4; ++c)
                acc[r * 4 + c] = __builtin_amdgcn_mfma_f32_16x16x32_bf16(
                    a[r], b[c], acc[r * 4 + c], 0, 0, 0);
    }

    const int colgrp = w >> 2;
    const float* ba = colgrp ? b1a : b0a;
    const float* bb = colgrp ? b1b : b0b;
    u16* C  = colgrp ? C2 : C1;
    const int ldc  = colgrp ? ldc2 : ldc1;
    const int relu = colgrp ? relu1 : relu0;
    #pragma unroll
    for (int c = 0; c < 4; ++c) {
        int lc = ((w & 3) * 4 + c) * 16 + m16;
        float bv = (ba ? ba[lc] : 0.f) + (bb ? bb[lc] : 0.f);
        #pragma unroll
        for (int r = 0; r < 4; ++r)
            #pragma unroll
            for (int i = 0; i < 4; ++i) {
                int grow = rowBase + r * 16 + q * 4 + i;
                if (grow < M) {
                    float v = acc[r * 4 + c][i] + bv;
                    if (relu) v = fmaxf(v, 0.f);
                    C[(size_t)grow * ldc + lc] = f2b(v);
                }
            }
    }
}

// ---------------------------------------------------------------------------
// fused 3-layer MLP [256->256] relu + classifier + softmax. 512 threads =
// 8 waves sharing a 64-row frag-major LDS panel (32 KB); each wave owns
// 64 rows x 32 cols (8 acc frags -> low VGPR -> high occupancy). B read
// directly per-wave from L2. Final layer stays in the panel; fc 256->5 +
// softmax computed from it (waves 0-3), writing only `out`.
// ---------------------------------------------------------------------------
__global__ __launch_bounds__(512)
void k_mlp3fc(const u16* __restrict__ WTHf,
              const float* Hb1, const float* Hb2, const float* Hb3,
              const float* __restrict__ fcw, const float* __restrict__ fcb,
              const u16* __restrict__ Hin, float* __restrict__ out, int M)
{
    __shared__ u16 P[64 * 256];     // frag-major activation panel (32 KB)

    const int tid = threadIdx.x;
    const int w = tid >> 6, lane = tid & 63;
    const int m16 = lane & 15, q = lane >> 4;
    const int rowBase = blockIdx.x * 64;

    // load panel (global row-major -> fragment-major), 4 chunks/thread
    #pragma unroll
    for (int p = 0; p < 4; ++p) {
        int ch = p * 512 + tid;          // 0..2047 16B-chunks
        int f = ch >> 6, l = ch & 63;    // frag f = kt*4+rf, lane-slot l
        int kt = f >> 2, rf = f & 3;
        int grow = rowBase + rf * 16 + (l & 15);
        if (grow >= M) grow = M - 1;
        int col = kt * 32 + (l >> 4) * 8;
        *(int4*)&P[ch * 8] = *(const int4*)(Hin + (size_t)grow * 256 + col);
    }
    __syncthreads();

    const float* biases[3] = {Hb1, Hb2, Hb3};
    for (int L = 0; L < 3; ++L) {
        const u16* WTf = WTHf + (size_t)L * 65536;
        float4v acc[8] = {};
        #pragma unroll 2
        for (int kt = 0; kt < 8; ++kt) {
            short8 a[4], b[2];
            #pragma unroll
            for (int c = 0; c < 2; ++c) {
                int4 bv = *(const int4*)(WTf + (size_t)(kt * 16 + w * 2 + c) * 512
                                         + lane * 8);
                b[c] = *(short8*)&bv;
            }
            #pragma unroll
            for (int r = 0; r < 4; ++r)
                a[r] = *(const short8*)&P[(kt * 4 + r) * 512 + lane * 8];
            #pragma unroll
            for (int r = 0; r < 4; ++r)
                #pragma unroll
                for (int c = 0; c < 2; ++c)
                    acc[r * 2 + c] = __builtin_amdgcn_mfma_f32_16x16x32_bf16(
                        a[r], b[c], acc[r * 2 + c], 0, 0, 0);
        }
        const float* bias = biases[L];
        __syncthreads();    // all panel reads done before overwrite
        // writeback into fragment-major panel (out col -> next-layer k)
        #pragma unroll
        for (int c = 0; c < 2; ++c) {
            int col = w * 32 + c * 16 + m16;
            float bv = bias[col];
            int kt2 = col >> 5;               // == w
            int l2h = 16 * ((col & 31) >> 3);
            int j2 = col & 7;
            #pragma unroll
            for (int r = 0; r < 4; ++r)
                #pragma unroll
                for (int i = 0; i < 4; ++i) {
                    int l2 = (q * 4 + i) + l2h;
                    P[(size_t)(kt2 * 4 + r) * 512 + l2 * 8 + j2] =
                        f2b(fmaxf(acc[r * 2 + c][i] + bv, 0.f));
                }
        }
        __syncthreads();
    }

    // classifier + softmax from the panel (waves 0-3, rf = w).
    if (w < 4) {
        float p5[5] = {0.f, 0.f, 0.f, 0.f, 0.f};
        #pragma unroll
        for (int kt = 0; kt < 8; ++kt) {
            u16x8 v = *(const u16x8*)&P[(kt * 4 + w) * 512 + lane * 8];
            int colb = kt * 32 + q * 8;
            #pragma unroll
            for (int j = 0; j < 8; ++j) {
                float hv = b2f(v[j]);
                const float* wr = fcw + (size_t)(colb + j) * 5;
                #pragma unroll
                for (int c = 0; c < 5; ++c) p5[c] += hv * wr[c];
            }
        }
        #pragma unroll
        for (int c = 0; c < 5; ++c) {
            p5[c] += __shfl_xor(p5[c], 16, 64);
            p5[c] += __shfl_xor(p5[c], 32, 64);
        }
        int grow = rowBase + w * 16 + m16;
        if (q == 0 && grow < M) {
            float mx = -1e30f;
            #pragma unroll
            for (int c = 0; c < 5; ++c) { p5[c] += fcb[c]; mx = fmaxf(mx, p5[c]); }
            float s = 0.f, e[5];
            #pragma unroll
            for (int c = 0; c < 5; ++c) { e[c] = __expf(p5[c] - mx); s += e[c]; }
            float inv = 1.f / s;
            #pragma unroll
            for (int c = 0; c < 5; ++c) out[(size_t)grow * 5 + c] = e[c] * inv;
        }
    }
}

// ---------------------------------------------------------------------------
extern "C" void kernel_launch(void* const* d_in, const int* in_sizes, int n_in,
                              void* d_out, int out_size, void* d_ws, size_t ws_size,
                              hipStream_t stream)
{
    const float* x    = (const float*)d_in[0];
    const int*   ei   = (const int*)  d_in[1];
    const float* W1   = (const float*)d_in[2];
    const float* as1  = (const float*)d_in[3];
    const float* ad1  = (const float*)d_in[4];
    const float* bc1  = (const float*)d_in[5];
    const float* A1w  = (const float*)d_in[6];
    const float* b1   = (const float*)d_in[7];
    const float* W2   = (const float*)d_in[8];
    const float* as2  = (const float*)d_in[9];
    const float* ad2  = (const float*)d_in[10];
    const float* bc2  = (const float*)d_in[11];
    const float* A2w  = (const float*)d_in[12];
    const float* b2   = (const float*)d_in[13];
    const float* Hw1  = (const float*)d_in[14];
    const float* Hb1  = (const float*)d_in[15];
    const float* Hw2  = (const float*)d_in[16];
    const float* Hb2  = (const float*)d_in[17];
    const float* Hw3  = (const float*)d_in[18];
    const float* Hb3  = (const float*)d_in[19];
    const float* fcw  = (const float*)d_in[20];
    const float* fcb  = (const float*)d_in[21];
    float* out = (float*)d_out;

    const int D = 256;
    const int N = in_sizes[0] / D;
    const int E = in_sizes[1] / 2;

    char* w = (char*)d_ws;
    auto alloc = [&](size_t bytes) {
        char* p = w;
        w += (bytes + 255) & ~(size_t)255;
        return p;
    };
    int*   flag   = (int*)  alloc(256);
    int*   flag64 = (int*)  alloc(256);
    float* a_s    = (float*)alloc((size_t)N * 4);
    float* a_d    = (float*)alloc((size_t)N * 4);
    float* vs1    = (float*)alloc(1024);                 // W1 @ att_src1  [256]
    float* vd1    = (float*)alloc(1024);                 // W1 @ att_dst1  [256]
    int*   deg    = (int*)  alloc((size_t)N * 4);
    int*   cursor = (int*)  alloc((size_t)N * 4);
    int*   offA   = (int*)  alloc((size_t)(N + 1) * 4);
    int*   part   = (int*)  alloc((size_t)((N + 1023) / 1024 + 1) * 4);
    int*   srcs   = (int*)  alloc((size_t)E * 4);
    float* alpha  = (float*)alloc((size_t)E * 4);        // normalized edge weights
    u16*   WT1    = (u16*)  alloc(512 * 512 * 2);        // frag-major [A1w;W1]
    u16*   WT2    = (u16*)  alloc(512 * 512 * 2);        // frag-major [W2|A2w]
    u16*   WTH    = (u16*)  alloc(3 * 256 * 256 * 2);    // frag-major MLP weights
    u16*   BUF1   = (u16*)  alloc((size_t)N * 512 * 2);  // xb|aggx -> h2|res2
    u16*   BUF2   = (u16*)  alloc((size_t)N * 512 * 2);  // hl1 -> out2

    // src32/dst32 alias BUF1 (dead before xb is written)
    int* src32 = (int*)BUF1;
    int* dst32 = src32 + E;

    size_t need = (size_t)(w - (char*)d_ws);             // ~112 MB
    if (ws_size < need) {
        float code = 1000.0f + (float)(ws_size >> 20);
        k_diag<<<(out_size + 255) / 256, 256, 0, stream>>>(out, out_size, code);
        return;
    }

    const int EB  = (E + 255) / 256;
    const int NB4 = (N + 3) / 4;
    const int OB  = (out_size + 255) / 256;
    const int NE  = (N > E ? N : E);
    const int RB64 = (N + 63) / 64;
    const int NBLK = (N + 1023) / 1024;
    const size_t NH2 = (size_t)N * 256;
    u16* XB   = BUF1;            // bf16 cast of x      [N,256]
    u16* AGGX = BUF1 + NH2;      // alpha-aggregated x  [N,256]

    hipMemsetAsync(flag, 0, 4, stream);
    hipMemsetAsync(deg, 0, (size_t)N * 4, stream);

    // ---- edge extraction (+degree count) + CSR by destination ----
    k_detect <<<1, 256, 0, stream>>>(ei, E, flag64);
    k_extract<<<EB, 256, 0, stream>>>(ei, E, flag64, src32, dst32, deg, N);
    k_scan_a <<<NBLK, 256, 0, stream>>>(deg, offA, part, N);
    k_scan_b <<<1, 1024, 0, stream>>>(part, NBLK);
    k_scan_c <<<(N + 255) / 256, 256, 0, stream>>>(offA, cursor, part, N, E);
    k_scatter<<<EB, 256, 0, stream>>>(src32, dst32, cursor, srcs, E, N);
    scan_csr <<<(NE + 255) / 256, 256, 0, stream>>>(offA, srcs, N, E, flag, 1);

    // ---- weight pre-pack (fragment-major bf16, single launch) ----
    k_packAll<<<dim3(32, 16, 5), 64, 0, stream>>>(A1w, W1, W2, A2w,
                                                  Hw1, Hw2, Hw3, WT1, WT2, WTH);

    // ---- attention vectors, then fused cast+dot over x ----
    k_rowdot2f<<<64, 256, 0, stream>>>(W1, 512, 512, as1, ad1, vs1, vd1, 256);
    k_castdot<<<(N + 7) / 8, 256, 0, stream>>>(x, vs1, vd1, XB, a_s, a_d, N);
    k_alpha<<<NB4, 256, 0, stream>>>(offA, srcs, a_s, a_d, alpha, N);

    // ---- aggx = sum_e alpha_e * xb[src_e]  (GAT linearity: agg before W1) ----
    k_aggw<<<NB4, 256, 0, stream>>>(XB, offA, srcs, alpha, nullptr, AGGX, N);

    // ---- layer 1 fused: hl1 = relu([XB|AGGX] @ [A1w;W1] + b1 + bc1) ----
    bigfull<<<RB64, 512, 0, stream>>>(XB, 256, AGGX, 256, WT1,
                                      b1, bc1, b1 + 256, bc1 + 256,
                                      BUF2, 512, BUF2 + 256, 512, N, 1, 1);

    // ---- layer 2 fused: [h2 | res2] = hl1 @ [W2 | A2w] (+b2+bc2 on res2) ----
    bigfull<<<RB64, 512, 0, stream>>>(BUF2, 512, BUF2 + 256, 512, WT2,
                                      nullptr, nullptr, b2, bc2,
                                      BUF1, 256, BUF1 + NH2, 256, N, 0, 0);

    k_rowdot2<<<NB4, 256, 0, stream>>>(BUF1, 256, 256, as2, ad2, a_s, a_d, N);
    k_alpha<<<NB4, 256, 0, stream>>>(offA, srcs, a_s, a_d, alpha, N);
    k_aggw<<<NB4, 256, 0, stream>>>(BUF1, offA, srcs, alpha, BUF1 + NH2, BUF2, N);

    // ---- fused 3-layer MLP + classifier + softmax (reads BUF2, writes out) ----
    k_mlp3fc<<<RB64, 512, 0, stream>>>(WTH, Hb1, Hb2, Hb3, fcw, fcb,
                                       BUF2, out, N);

    k_final_diag<<<OB, 256, 0, stream>>>(flag, out, out_size);
}

// Round 11
// 532.940 us; speedup vs baseline: 1.1117x; 1.0165x over previous
//
#include <hip/hip_runtime.h>

typedef unsigned short u16;
typedef short short8 __attribute__((ext_vector_type(8)));
typedef u16 u16x8 __attribute__((ext_vector_type(8)));
typedef float float4v __attribute__((ext_vector_type(4)));

#define NEG_SLOPE 0.2f

#define GLOAD_LDS16(g, l) __builtin_amdgcn_global_load_lds(                    \
    (const __attribute__((address_space(1))) void*)(g),                        \
    (__attribute__((address_space(3))) void*)(l), 16, 0, 0)

static __device__ __forceinline__ float b2f(u16 u) {
    union { unsigned int i; float f; } x; x.i = ((unsigned int)u) << 16; return x.f;
}
static __device__ __forceinline__ u16 f2b(float f) {
    unsigned int u = __float_as_uint(f);
    unsigned int r = (u + 0x7fffu + ((u >> 16) & 1u)) >> 16;
    return (u16)r;
}

// ---------------------------------------------------------------------------
// diagnostics: code 32 = CSR inconsistent; 1000+ = ws too small
// ---------------------------------------------------------------------------
__global__ void k_diag(float* out, int n, float val)
{
    int i = blockIdx.x * 256 + threadIdx.x;
    if (i < n) out[i] = val;
}

__global__ void scan_csr(const int* off, const int* srcs, int N, int E,
                         int* flag, int bit)
{
    int i = blockIdx.x * 256 + threadIdx.x;
    if (i < N) {
        int a = off[i], b = off[i + 1];
        if (a < 0 || b < a || b > E) atomicOr(flag, bit);
    }
    if (i == 0 && off[N] != E) atomicOr(flag, bit);
    if (i < E) {
        if ((unsigned)srcs[i] >= (unsigned)N) atomicOr(flag, bit);
    }
}

__global__ void k_final_diag(const int* flag, float* out, int n)
{
    int f = *flag;
    if (f == 0) return;
    int b = __ffs(f) - 1;
    float val = 32.0f * (b + 1);
    int i = blockIdx.x * 256 + threadIdx.x;
    if (i < n) out[i] = val;
}

// ---------------------------------------------------------------------------
// edge_index dtype probe + canonical int32 extraction (+ degree count fused)
// ---------------------------------------------------------------------------
__global__ void k_detect(const int* ei, int E, int* flag64)
{
    __shared__ int zc;
    if (threadIdx.x == 0) zc = 0;
    __syncthreads();
    int idx = 1 + 2 * (int)threadIdx.x;
    int z = (idx < 2 * E && ei[idx] == 0) ? 1 : 0;
    atomicAdd(&zc, z);
    __syncthreads();
    if (threadIdx.x == 0) *flag64 = (zc >= 200) ? 1 : 0;
}

__global__ void k_extract(const int* ei, int E, const int* flag64,
                          int* src, int* dst, int* deg, int N)
{
    int e = blockIdx.x * 256 + threadIdx.x;
    if (e >= E) return;
    int s, d;
    if (*flag64) {
        s = ei[2 * e];
        d = ei[2 * E + 2 * e];
    } else {
        s = ei[e];
        d = ei[E + e];
    }
    src[e] = s; dst[e] = d;
    if ((unsigned)d < (unsigned)N) atomicAdd(&deg[d], 1);
}

// ---------------------------------------------------------------------------
// device-wide exclusive scan, 3-phase (1024 elems per block in phase A)
// ---------------------------------------------------------------------------
__global__ __launch_bounds__(256)
void k_scan_a(const int* __restrict__ deg, int* __restrict__ off,
              int* __restrict__ partial, int N)
{
    __shared__ int sd[256];
    int tid = threadIdx.x;
    int base = blockIdx.x * 1024;
    int i0 = base + tid * 4;
    int v0 = 0, v1 = 0, v2 = 0, v3 = 0;
    if (i0 < N)     v0 = deg[i0];
    if (i0 + 1 < N) v1 = deg[i0 + 1];
    if (i0 + 2 < N) v2 = deg[i0 + 2];
    if (i0 + 3 < N) v3 = deg[i0 + 3];
    int t = v0 + v1 + v2 + v3;
    sd[tid] = t;
    __syncthreads();
    #pragma unroll
    for (int s = 1; s < 256; s <<= 1) {
        int u = (tid >= s) ? sd[tid - s] : 0;
        __syncthreads();
        sd[tid] += u;
        __syncthreads();
    }
    int excl = sd[tid] - t;                 // exclusive within block
    if (i0 < N)     off[i0]     = excl;
    if (i0 + 1 < N) off[i0 + 1] = excl + v0;
    if (i0 + 2 < N) off[i0 + 2] = excl + v0 + v1;
    if (i0 + 3 < N) off[i0 + 3] = excl + v0 + v1 + v2;
    if (tid == 255) partial[blockIdx.x] = sd[255];
}

__global__ __launch_bounds__(1024)
void k_scan_b(int* partial, int nblk)
{
    __shared__ int sd[1024];
    __shared__ int running;
    int tid = threadIdx.x;
    if (tid == 0) running = 0;
    __syncthreads();
    for (int base = 0; base < nblk; base += 1024) {
        int i = base + tid;
        int v = (i < nblk) ? partial[i] : 0;
        sd[tid] = v;
        __syncthreads();
        for (int s = 1; s < 1024; s <<= 1) {
            int u = (tid >= s) ? sd[tid - s] : 0;
            __syncthreads();
            sd[tid] += u;
            __syncthreads();
        }
        if (i < nblk) partial[i] = sd[tid] - v + running;   // exclusive
        int total = sd[1023];
        __syncthreads();
        if (tid == 0) running += total;
        __syncthreads();
    }
}

__global__ __launch_bounds__(256)
void k_scan_c(int* __restrict__ off, int* __restrict__ cursor,
              const int* __restrict__ partial, int N, int E)
{
    int i = blockIdx.x * 256 + threadIdx.x;
    if (i < N) {
        int v = off[i] + partial[i >> 10];
        off[i] = v;
        cursor[i] = v;
    }
    if (i == 0) off[N] = E;
}

__global__ void k_scatter(const int* src, const int* dst, int* cursor,
                          int* srcs, int E, int N)
{
    int e = blockIdx.x * 256 + threadIdx.x;
    if (e < E) {
        int d = dst[e];
        if ((unsigned)d < (unsigned)N) {
            int p = atomicAdd(&cursor[d], 1);
            if ((unsigned)p < (unsigned)E) srcs[p] = src[e];
        }
    }
}

// ---------------------------------------------------------------------------
// fused fp32->bf16 cast + row dots vs (vs,vd): 8 rows/block, 32 lanes/row.
// ---------------------------------------------------------------------------
__global__ __launch_bounds__(256)
void k_castdot(const float* __restrict__ x, const float* __restrict__ vs,
               const float* __restrict__ vd, u16* __restrict__ xb,
               float* __restrict__ a_s, float* __restrict__ a_d, int N)
{
    int tid = threadIdx.x;
    int rowb = tid >> 5;                // 0..7
    int col8 = (tid & 31) * 8;
    int n = blockIdx.x * 8 + rowb;
    if (n >= N) return;
    const float* xr = x + (size_t)n * 256 + col8;
    float4 v0 = *(const float4*)xr;
    float4 v1 = *(const float4*)(xr + 4);
    int4 w;
    w.x = (int)f2b(v0.x) | ((int)f2b(v0.y) << 16);
    w.y = (int)f2b(v0.z) | ((int)f2b(v0.w) << 16);
    w.z = (int)f2b(v1.x) | ((int)f2b(v1.y) << 16);
    w.w = (int)f2b(v1.z) | ((int)f2b(v1.w) << 16);
    *(int4*)(xb + (size_t)n * 256 + col8) = w;

    float4 s0 = *(const float4*)(vs + col8);
    float4 s1 = *(const float4*)(vs + col8 + 4);
    float4 d0 = *(const float4*)(vd + col8);
    float4 d1 = *(const float4*)(vd + col8 + 4);
    float ss = v0.x*s0.x + v0.y*s0.y + v0.z*s0.z + v0.w*s0.w
             + v1.x*s1.x + v1.y*s1.y + v1.z*s1.z + v1.w*s1.w;
    float sd = v0.x*d0.x + v0.y*d0.y + v0.z*d0.z + v0.w*d0.w
             + v1.x*d1.x + v1.y*d1.y + v1.z*d1.z + v1.w*d1.w;
    #pragma unroll
    for (int m = 16; m; m >>= 1) {
        ss += __shfl_xor(ss, m, 64);
        sd += __shfl_xor(sd, m, 64);
    }
    if ((tid & 31) == 0) { a_s[n] = ss; a_d[n] = sd; }
}

// ---------------------------------------------------------------------------
// fragment-major weight pack, all weights in one launch (blockIdx.z selects)
// out[(kt*NC16 + cf)*512 + l*8 + j] = bf16( W[kt*32+(l>>4)*8+j][cf*16+(l&15)] )
// ---------------------------------------------------------------------------
__global__ __launch_bounds__(64)
void k_packAll(const float* A1w, const float* W1, const float* W2, const float* A2w,
               const float* Hw1, const float* Hw2, const float* Hw3,
               u16* WT1, u16* WT2, u16* WTH)
{
    int z = blockIdx.z;
    const float *in1, *in2; int ksplit, csplit, in_ld, NC16; u16* out;
    if (z == 0)      { in1 = A1w; in2 = W1;  ksplit = 256; csplit = 0;   in_ld = 512; out = WT1; NC16 = 32; }
    else if (z == 1) { in1 = W2;  in2 = A2w; ksplit = 0;   csplit = 256; in_ld = 256; out = WT2; NC16 = 32; }
    else {
        if (blockIdx.x >= 16 || blockIdx.y >= 8) return;
        in1 = (z == 2) ? Hw1 : (z == 3) ? Hw2 : Hw3;
        in2 = nullptr; ksplit = 0; csplit = 0; in_ld = 256; NC16 = 16;
        out = WTH + (size_t)(z - 2) * 65536;
    }
    int l = threadIdx.x;
    int cf = blockIdx.x, kt = blockIdx.y;
    int col = cf * 16 + (l & 15);
    int kbase = kt * 32 + (l >> 4) * 8;
    const float* src = in1;
    int cc = col, koff = 0;
    if (ksplit > 0 && kbase >= ksplit) { src = in2; koff = ksplit; }
    if (csplit > 0 && col >= csplit)   { src = in2; cc = col - csplit; }
    u16* o = out + ((size_t)(kt * NC16 + cf) * 512) + l * 8;
    #pragma unroll
    for (int j = 0; j < 8; ++j)
        o[j] = f2b(src[(size_t)(kbase - koff + j) * in_ld + cc]);
}

// ---------------------------------------------------------------------------
// fp32 row-dot against two fp32 vectors — one wave per row, float4 lanes
// ---------------------------------------------------------------------------
__global__ __launch_bounds__(256)
void k_rowdot2f(const float* __restrict__ A, int ld, int H,
                const float* __restrict__ vs, const float* __restrict__ vd,
                float* a_s, float* a_d, int N)
{
    int wave = threadIdx.x >> 6, lane = threadIdx.x & 63;
    int n = blockIdx.x * 4 + wave;
    if (n >= N) return;
    const float* ar = A + (size_t)n * ld;
    float ss = 0.f, sd = 0.f;
    for (int i = lane * 4; i < H; i += 256) {
        float4 v  = *(const float4*)(ar + i);
        float4 s4 = *(const float4*)(vs + i);
        float4 d4 = *(const float4*)(vd + i);
        ss += v.x * s4.x + v.y * s4.y + v.z * s4.z + v.w * s4.w;
        sd += v.x * d4.x + v.y * d4.y + v.z * d4.z + v.w * d4.w;
    }
    #pragma unroll
    for (int m = 32; m; m >>= 1) {
        ss += __shfl_xor(ss, m, 64);
        sd += __shfl_xor(sd, m, 64);
    }
    if (lane == 0) { a_s[n] = ss; a_d[n] = sd; }
}

// ---------------------------------------------------------------------------
// per-dst softmax stats, ONE pass: exact online (m, sum) -> mu[n], inv[n].
// alpha is computed inline by k_aggw from (a_s, a_d, mu, inv).
// ---------------------------------------------------------------------------
__global__ __launch_bounds__(256)
void k_alpha1p(const int* __restrict__ off, const int* __restrict__ srcs,
               const float* __restrict__ a_s, const float* __restrict__ a_d,
               float* __restrict__ mu, float* __restrict__ inv, int N)
{
    int wave = threadIdx.x >> 6, lane = threadIdx.x & 63;
    int n = blockIdx.x * 4 + wave;
    if (n >= N) return;
    int base = off[n], end = off[n + 1];
    float adn = a_d[n];
    float m = -1e30f, s = 0.f;
    for (int p = base + lane; p < end; p += 64) {
        int sx = srcs[p];
        sx = ((unsigned)sx < (unsigned)N) ? sx : 0;
        float z = a_s[sx] + adn;
        z = fmaxf(z, NEG_SLOPE * z);          // leaky_relu (slope<1)
        float mn = fmaxf(m, z);
        s = s * __expf(m - mn) + __expf(z - mn);
        m = mn;
    }
    #pragma unroll
    for (int msk = 32; msk; msk >>= 1) {
        float mo = __shfl_xor(m, msk, 64);
        float so = __shfl_xor(s, msk, 64);
        float mn = fmaxf(m, mo);
        s = s * __expf(m - mn) + so * __expf(mo - mn);
        m = mn;
    }
    if (lane == 0) { mu[n] = m; inv[n] = 1.f / (s + 1e-16f); }
}

// ---------------------------------------------------------------------------
// weighted gather-aggregate with INLINE alpha: half-wave split (lanes 0-31
// edge p, 32-63 edge p+1), 16B row loads, alpha = exp(leaky(a_s[s]+adn)-mu)
// * inv computed per edge (identical formula to the old k_alpha pass-2).
// ---------------------------------------------------------------------------
__global__ __launch_bounds__(256)
void k_aggw(const u16* __restrict__ rows, const int* __restrict__ off,
            const int* __restrict__ srcs, const float* __restrict__ a_s,
            const float* __restrict__ a_d, const float* __restrict__ mu,
            const float* __restrict__ inv,
            const u16* __restrict__ add, u16* __restrict__ out, int N)
{
    int wave = threadIdx.x >> 6, lane = threadIdx.x & 63;
    int n = blockIdx.x * 4 + wave;
    if (n >= N) return;
    int base = off[n], end = off[n + 1];
    float adn = a_d[n], mn = mu[n], iv = inv[n];
    int half = lane >> 5;
    int c8 = (lane & 31) * 8;
    float acc[8] = {};
    int p = base;
    for (; p + 3 < end; p += 4) {
        int sA = srcs[p + half];
        int sB = srcs[p + 2 + half];
        sA = ((unsigned)sA < (unsigned)N) ? sA : 0;
        sB = ((unsigned)sB < (unsigned)N) ? sB : 0;
        float zA = a_s[sA] + adn; zA = fmaxf(zA, NEG_SLOPE * zA);
        float zB = a_s[sB] + adn; zB = fmaxf(zB, NEG_SLOPE * zB);
        float wA = __expf(zA - mn) * iv;
        float wB = __expf(zB - mn) * iv;
        u16x8 vA = *(const u16x8*)(rows + (size_t)sA * 256 + c8);
        u16x8 vB = *(const u16x8*)(rows + (size_t)sB * 256 + c8);
        #pragma unroll
        for (int j = 0; j < 8; ++j)
            acc[j] += wA * b2f(vA[j]) + wB * b2f(vB[j]);
    }
    for (; p + 1 < end; p += 2) {
        int sA = srcs[p + half];
        sA = ((unsigned)sA < (unsigned)N) ? sA : 0;
        float zA = a_s[sA] + adn; zA = fmaxf(zA, NEG_SLOPE * zA);
        float wA = __expf(zA - mn) * iv;
        u16x8 vA = *(const u16x8*)(rows + (size_t)sA * 256 + c8);
        #pragma unroll
        for (int j = 0; j < 8; ++j)
            acc[j] += wA * b2f(vA[j]);
    }
    if (p < end) {
        int sA = srcs[p];
        sA = ((unsigned)sA < (unsigned)N) ? sA : 0;
        float zA = a_s[sA] + adn; zA = fmaxf(zA, NEG_SLOPE * zA);
        float wA = half ? 0.f : (__expf(zA - mn) * iv);
        u16x8 vA = *(const u16x8*)(rows + (size_t)sA * 256 + c8);
        #pragma unroll
        for (int j = 0; j < 8; ++j)
            acc[j] += wA * b2f(vA[j]);
    }
    #pragma unroll
    for (int j = 0; j < 8; ++j)
        acc[j] += __shfl_xor(acc[j], 32, 64);
    if (half == 0) {
        size_t ob = (size_t)n * 256 + c8;
        if (add) {
            u16x8 ad8 = *(const u16x8*)(add + ob);
            #pragma unroll
            for (int j = 0; j < 8; ++j) acc[j] += b2f(ad8[j]);
        }
        u16x8 o;
        #pragma unroll
        for (int j = 0; j < 8; ++j) o[j] = f2b(acc[j]);
        *(u16x8*)(out + ob) = o;
    }
}

// ---------------------------------------------------------------------------
// full-width fused MFMA GEMM: BM=64, K=512 (two bf16 A halves of 256 each),
// NC=512 from fragment-major pre-packed WTf. Output split at col 256 into
// (C1, C2) with per-half fp32 bias pairs and relu flags. A read ONCE from HBM.
// 8 waves, each owns a 64x64 tile; LDS-staged bulk prefetch (measured-best
// structure), staging via async global_load_lds width=16.
// Optional fused row-dots on the C1 half (bf16-rounded acc · dotS/dotD,
// atomicAdd into oaS/oaD) — replaces the separate k_rowdot2 pass over h2.
// ---------------------------------------------------------------------------
__global__ __launch_bounds__(512)
void bigfull(const u16* __restrict__ A1, int lda1,
             const u16* __restrict__ A2, int lda2,
             const u16* __restrict__ WTf,
             const float* b0a, const float* b0b,
             const float* b1a, const float* b1b,
             u16* C1, int ldc1, u16* C2, int ldc2,
             const float* __restrict__ dotS, const float* __restrict__ dotD,
             float* oaS, float* oaD,
             int M, int relu0, int relu1)
{
    __shared__ u16 As[64 * 32];      // frag-major: [rf][lane][8]   (4 KB)
    __shared__ u16 Bs[512 * 32];     // frag-major: [cf][lane][8]  (32 KB)

    const int tid = threadIdx.x;
    const int w = tid >> 6, lane = tid & 63;
    const int m16 = lane & 15, q = lane >> 4;
    const int rowBase = blockIdx.x * 64;

    // waves 0-3 stage row-fragment rf = w: per-lane source row (clamped)
    int garow = rowBase + (w & 3) * 16 + m16;
    if (garow >= M) garow = M - 1;          // clamp; value unused when OOB

    float4v acc[16] = {};

    for (int k0 = 0; k0 < 512; k0 += 32) {
        const int kt = k0 >> 5;
        __syncthreads();
        if (w < 4) {   // stage A 64x32 into fragment order (async, 16B/lane)
            int kk = k0 + q * 8;
            const u16* src = (kk < 256)
                ? A1 + (size_t)garow * lda1 + kk
                : A2 + (size_t)garow * lda2 + (kk - 256);
            GLOAD_LDS16(src, &As[w * 512]);
        }
        {   // stage B 512x32: linear async copy of pre-packed fragments
            const u16* wsrc = WTf + (size_t)kt * 16384;
            #pragma unroll
            for (int p = 0; p < 4; ++p) {
                int chb = p * 512 + w * 64;          // wave-uniform chunk base
                GLOAD_LDS16(wsrc + ((size_t)chb + lane) * 8, &Bs[chb * 8]);
            }
        }
        __syncthreads();

        short8 a[4], b[4];
        #pragma unroll
        for (int r = 0; r < 4; ++r)
            a[r] = *(const short8*)&As[r * 512 + lane * 8];
        #pragma unroll
        for (int c = 0; c < 4; ++c)
            b[c] = *(const short8*)&Bs[(w * 4 + c) * 512 + lane * 8];
        #pragma unroll
        for (int r = 0; r < 4; ++r)
            #pragma unroll
            for (int c = 0; c < 4; ++c)
                acc[r * 4 + c] = __builtin_amdgcn_mfma_f32_16x16x32_bf16(
                    a[r], b[c], acc[r * 4 + c], 0, 0, 0);
    }

    const int colgrp = w >> 2;
    const float* ba = colgrp ? b1a : b0a;
    const float* bb = colgrp ? b1b : b0b;
    u16* C  = colgrp ? C2 : C1;
    const int ldc  = colgrp ? ldc2 : ldc1;
    const int relu = colgrp ? relu1 : relu0;
    #pragma unroll
    for (int c = 0; c < 4; ++c) {
        int lc = ((w & 3) * 4 + c) * 16 + m16;
        float bv = (ba ? ba[lc] : 0.f) + (bb ? bb[lc] : 0.f);
        #pragma unroll
        for (int r = 0; r < 4; ++r)
            #pragma unroll
            for (int i = 0; i < 4; ++i) {
                int grow = rowBase + r * 16 + q * 4 + i;
                if (grow < M) {
                    float v = acc[r * 4 + c][i] + bv;
                    if (relu) v = fmaxf(v, 0.f);
                    C[(size_t)grow * ldc + lc] = f2b(v);
                }
            }
    }

    // fused attention row-dots on the C1 half (no bias / no relu path)
    if (dotS && colgrp == 0) {
        #pragma unroll
        for (int r = 0; r < 4; ++r)
            #pragma unroll
            for (int i = 0; i < 4; ++i) {
                float ss = 0.f, sd = 0.f;
                #pragma unroll
                for (int c = 0; c < 4; ++c) {
                    int lc = ((w & 3) * 4 + c) * 16 + m16;
                    float v = b2f(f2b(acc[r * 4 + c][i]));  // match stored bf16
                    ss += v * dotS[lc];
                    sd += v * dotD[lc];
                }
                #pragma unroll
                for (int msk = 1; msk < 16; msk <<= 1) {
                    ss += __shfl_xor(ss, msk, 64);
                    sd += __shfl_xor(sd, msk, 64);
                }
                int grow = rowBase + r * 16 + q * 4 + i;
                if (m16 == 0 && grow < M) {
                    atomicAdd(&oaS[grow], ss);
                    atomicAdd(&oaD[grow], sd);
                }
            }
    }
}

// ---------------------------------------------------------------------------
// fused 3-layer MLP [256->256] relu + classifier + softmax. 512 threads =
// 8 waves sharing a 64-row frag-major LDS panel (32 KB); each wave owns
// 64 rows x 32 cols (8 acc frags -> low VGPR -> high occupancy). B read
// directly per-wave from L2. Final layer stays in the panel; fc 256->5 +
// softmax computed from it (waves 0-3), writing only `out`.
// ---------------------------------------------------------------------------
__global__ __launch_bounds__(512)
void k_mlp3fc(const u16* __restrict__ WTHf,
              const float* Hb1, const float* Hb2, const float* Hb3,
              const float* __restrict__ fcw, const float* __restrict__ fcb,
              const u16* __restrict__ Hin, float* __restrict__ out, int M)
{
    __shared__ u16 P[64 * 256];     // frag-major activation panel (32 KB)

    const int tid = threadIdx.x;
    const int w = tid >> 6, lane = tid & 63;
    const int m16 = lane & 15, q = lane >> 4;
    const int rowBase = blockIdx.x * 64;

    // load panel (global row-major -> fragment-major), 4 chunks/thread
    #pragma unroll
    for (int p = 0; p < 4; ++p) {
        int ch = p * 512 + tid;          // 0..2047 16B-chunks
        int f = ch >> 6, l = ch & 63;    // frag f = kt*4+rf, lane-slot l
        int kt = f >> 2, rf = f & 3;
        int grow = rowBase + rf * 16 + (l & 15);
        if (grow >= M) grow = M - 1;
        int col = kt * 32 + (l >> 4) * 8;
        *(int4*)&P[ch * 8] = *(const int4*)(Hin + (size_t)grow * 256 + col);
    }
    __syncthreads();

    const float* biases[3] = {Hb1, Hb2, Hb3};
    for (int L = 0; L < 3; ++L) {
        const u16* WTf = WTHf + (size_t)L * 65536;
        float4v acc[8] = {};
        #pragma unroll 2
        for (int kt = 0; kt < 8; ++kt) {
            short8 a[4], b[2];
            #pragma unroll
            for (int c = 0; c < 2; ++c) {
                int4 bv = *(const int4*)(WTf + (size_t)(kt * 16 + w * 2 + c) * 512
                                         + lane * 8);
                b[c] = *(short8*)&bv;
            }
            #pragma unroll
            for (int r = 0; r < 4; ++r)
                a[r] = *(const short8*)&P[(kt * 4 + r) * 512 + lane * 8];
            #pragma unroll
            for (int r = 0; r < 4; ++r)
                #pragma unroll
                for (int c = 0; c < 2; ++c)
                    acc[r * 2 + c] = __builtin_amdgcn_mfma_f32_16x16x32_bf16(
                        a[r], b[c], acc[r * 2 + c], 0, 0, 0);
        }
        const float* bias = biases[L];
        __syncthreads();    // all panel reads done before overwrite
        // writeback into fragment-major panel (out col -> next-layer k)
        #pragma unroll
        for (int c = 0; c < 2; ++c) {
            int col = w * 32 + c * 16 + m16;
            float bv = bias[col];
            int kt2 = col >> 5;               // == w
            int l2h = 16 * ((col & 31) >> 3);
            int j2 = col & 7;
            #pragma unroll
            for (int r = 0; r < 4; ++r)
                #pragma unroll
                for (int i = 0; i < 4; ++i) {
                    int l2 = (q * 4 + i) + l2h;
                    P[(size_t)(kt2 * 4 + r) * 512 + l2 * 8 + j2] =
                        f2b(fmaxf(acc[r * 2 + c][i] + bv, 0.f));
                }
        }
        __syncthreads();
    }

    // classifier + softmax from the panel (waves 0-3, rf = w).
    if (w < 4) {
        float p5[5] = {0.f, 0.f, 0.f, 0.f, 0.f};
        #pragma unroll
        for (int kt = 0; kt < 8; ++kt) {
            u16x8 v = *(const u16x8*)&P[(kt * 4 + w) * 512 + lane * 8];
            int colb = kt * 32 + q * 8;
            #pragma unroll
            for (int j = 0; j < 8; ++j) {
                float hv = b2f(v[j]);
                const float* wr = fcw + (size_t)(colb + j) * 5;
                #pragma unroll
                for (int c = 0; c < 5; ++c) p5[c] += hv * wr[c];
            }
        }
        #pragma unroll
        for (int c = 0; c < 5; ++c) {
            p5[c] += __shfl_xor(p5[c], 16, 64);
            p5[c] += __shfl_xor(p5[c], 32, 64);
        }
        int grow = rowBase + w * 16 + m16;
        if (q == 0 && grow < M) {
            float mx = -1e30f;
            #pragma unroll
            for (int c = 0; c < 5; ++c) { p5[c] += fcb[c]; mx = fmaxf(mx, p5[c]); }
            float s = 0.f, e[5];
            #pragma unroll
            for (int c = 0; c < 5; ++c) { e[c] = __expf(p5[c] - mx); s += e[c]; }
            float inv = 1.f / s;
            #pragma unroll
            for (int c = 0; c < 5; ++c) out[(size_t)grow * 5 + c] = e[c] * inv;
        }
    }
}

// ---------------------------------------------------------------------------
extern "C" void kernel_launch(void* const* d_in, const int* in_sizes, int n_in,
                              void* d_out, int out_size, void* d_ws, size_t ws_size,
                              hipStream_t stream)
{
    const float* x    = (const float*)d_in[0];
    const int*   ei   = (const int*)  d_in[1];
    const float* W1   = (const float*)d_in[2];
    const float* as1  = (const float*)d_in[3];
    const float* ad1  = (const float*)d_in[4];
    const float* bc1  = (const float*)d_in[5];
    const float* A1w  = (const float*)d_in[6];
    const float* b1   = (const float*)d_in[7];
    const float* W2   = (const float*)d_in[8];
    const float* as2  = (const float*)d_in[9];
    const float* ad2  = (const float*)d_in[10];
    const float* bc2  = (const float*)d_in[11];
    const float* A2w  = (const float*)d_in[12];
    const float* b2   = (const float*)d_in[13];
    const float* Hw1  = (const float*)d_in[14];
    const float* Hb1  = (const float*)d_in[15];
    const float* Hw2  = (const float*)d_in[16];
    const float* Hb2  = (const float*)d_in[17];
    const float* Hw3  = (const float*)d_in[18];
    const float* Hb3  = (const float*)d_in[19];
    const float* fcw  = (const float*)d_in[20];
    const float* fcb  = (const float*)d_in[21];
    float* out = (float*)d_out;

    const int D = 256;
    const int N = in_sizes[0] / D;
    const int E = in_sizes[1] / 2;

    char* w = (char*)d_ws;
    auto alloc = [&](size_t bytes) {
        char* p = w;
        w += (bytes + 255) & ~(size_t)255;
        return p;
    };
    int*   flag   = (int*)  alloc(256);
    int*   flag64 = (int*)  alloc(256);
    float* a_s    = (float*)alloc((size_t)N * 4);
    float* a_d    = (float*)alloc((size_t)N * 4);
    float* mu     = (float*)alloc((size_t)N * 4);
    float* inv    = (float*)alloc((size_t)N * 4);
    float* vs1    = (float*)alloc(1024);                 // W1 @ att_src1  [256]
    float* vd1    = (float*)alloc(1024);                 // W1 @ att_dst1  [256]
    int*   deg    = (int*)  alloc((size_t)N * 4);
    int*   cursor = (int*)  alloc((size_t)N * 4);
    int*   offA   = (int*)  alloc((size_t)(N + 1) * 4);
    int*   part   = (int*)  alloc((size_t)((N + 1023) / 1024 + 1) * 4);
    int*   srcs   = (int*)  alloc((size_t)E * 4);
    u16*   WT1    = (u16*)  alloc(512 * 512 * 2);        // frag-major [A1w;W1]
    u16*   WT2    = (u16*)  alloc(512 * 512 * 2);        // frag-major [W2|A2w]
    u16*   WTH    = (u16*)  alloc(3 * 256 * 256 * 2);    // frag-major MLP weights
    u16*   BUF1   = (u16*)  alloc((size_t)N * 512 * 2);  // xb|aggx -> h2|res2
    u16*   BUF2   = (u16*)  alloc((size_t)N * 512 * 2);  // hl1 -> out2

    // src32/dst32 alias BUF1 (dead before xb is written)
    int* src32 = (int*)BUF1;
    int* dst32 = src32 + E;

    size_t need = (size_t)(w - (char*)d_ws);             // ~110 MB
    if (ws_size < need) {
        float code = 1000.0f + (float)(ws_size >> 20);
        k_diag<<<(out_size + 255) / 256, 256, 0, stream>>>(out, out_size, code);
        return;
    }

    const int EB  = (E + 255) / 256;
    const int NB4 = (N + 3) / 4;
    const int OB  = (out_size + 255) / 256;
    const int NE  = (N > E ? N : E);
    const int RB64 = (N + 63) / 64;
    const int NBLK = (N + 1023) / 1024;
    const size_t NH2 = (size_t)N * 256;
    u16* XB   = BUF1;            // bf16 cast of x      [N,256]
    u16* AGGX = BUF1 + NH2;      // alpha-aggregated x  [N,256]

    hipMemsetAsync(flag, 0, 4, stream);
    hipMemsetAsync(deg, 0, (size_t)N * 4, stream);

    // ---- edge extraction (+degree count) + CSR by destination ----
    k_detect <<<1, 256, 0, stream>>>(ei, E, flag64);
    k_extract<<<EB, 256, 0, stream>>>(ei, E, flag64, src32, dst32, deg, N);
    k_scan_a <<<NBLK, 256, 0, stream>>>(deg, offA, part, N);
    k_scan_b <<<1, 1024, 0, stream>>>(part, NBLK);
    k_scan_c <<<(N + 255) / 256, 256, 0, stream>>>(offA, cursor, part, N, E);
    k_scatter<<<EB, 256, 0, stream>>>(src32, dst32, cursor, srcs, E, N);
    scan_csr <<<(NE + 255) / 256, 256, 0, stream>>>(offA, srcs, N, E, flag, 1);

    // ---- weight pre-pack (fragment-major bf16, single launch) ----
    k_packAll<<<dim3(32, 16, 5), 64, 0, stream>>>(A1w, W1, W2, A2w,
                                                  Hw1, Hw2, Hw3, WT1, WT2, WTH);

    // ---- attention vectors, then fused cast+dot over x ----
    k_rowdot2f<<<64, 256, 0, stream>>>(W1, 512, 512, as1, ad1, vs1, vd1, 256);
    k_castdot<<<(N + 7) / 8, 256, 0, stream>>>(x, vs1, vd1, XB, a_s, a_d, N);
    k_alpha1p<<<NB4, 256, 0, stream>>>(offA, srcs, a_s, a_d, mu, inv, N);

    // ---- aggx = sum_e alpha_e * xb[src_e]  (alpha inline from mu/inv) ----
    k_aggw<<<NB4, 256, 0, stream>>>(XB, offA, srcs, a_s, a_d, mu, inv,
                                    nullptr, AGGX, N);

    // a_s/a_d fully consumed by aggw-1; zero for bigfull-2's atomic dots
    hipMemsetAsync(a_s, 0, (size_t)N * 4, stream);
    hipMemsetAsync(a_d, 0, (size_t)N * 4, stream);

    // ---- layer 1 fused: hl1 = relu([XB|AGGX] @ [A1w;W1] + b1 + bc1) ----
    bigfull<<<RB64, 512, 0, stream>>>(XB, 256, AGGX, 256, WT1,
                                      b1, bc1, b1 + 256, bc1 + 256,
                                      BUF2, 512, BUF2 + 256, 512,
                                      nullptr, nullptr, nullptr, nullptr,
                                      N, 1, 1);

    // ---- layer 2 fused: [h2 | res2] = hl1 @ [W2 | A2w] (+b2+bc2 on res2),
    //      with a_s2/a_d2 = h2·att2 accumulated in the epilogue ----
    bigfull<<<RB64, 512, 0, stream>>>(BUF2, 512, BUF2 + 256, 512, WT2,
                                      nullptr, nullptr, b2, bc2,
                                      BUF1, 256, BUF1 + NH2, 256,
                                      as2, ad2, a_s, a_d,
                                      N, 0, 0);

    k_alpha1p<<<NB4, 256, 0, stream>>>(offA, srcs, a_s, a_d, mu, inv, N);
    k_aggw<<<NB4, 256, 0, stream>>>(BUF1, offA, srcs, a_s, a_d, mu, inv,
                                    BUF1 + NH2, BUF2, N);

    // ---- fused 3-layer MLP + classifier + softmax (reads BUF2, writes out) ----
    k_mlp3fc<<<RB64, 512, 0, stream>>>(WTH, Hb1, Hb2, Hb3, fcw, fcb,
                                       BUF2, out, N);

    k_final_diag<<<OB, 256, 0, stream>>>(flag, out, out_size);
}

// Round 12
// 511.435 us; speedup vs baseline: 1.1584x; 1.0420x over previous
//
#include <hip/hip_runtime.h>

typedef unsigned short u16;
typedef short short8 __attribute__((ext_vector_type(8)));
typedef u16 u16x8 __attribute__((ext_vector_type(8)));
typedef float float4v __attribute__((ext_vector_type(4)));

#define NEG_SLOPE 0.2f

#define GLOAD_LDS16(g, l) __builtin_amdgcn_global_load_lds(                    \
    (const __attribute__((address_space(1))) void*)(g),                        \
    (__attribute__((address_space(3))) void*)(l), 16, 0, 0)

static __device__ __forceinline__ float b2f(u16 u) {
    union { unsigned int i; float f; } x; x.i = ((unsigned int)u) << 16; return x.f;
}
static __device__ __forceinline__ u16 f2b(float f) {
    unsigned int u = __float_as_uint(f);
    unsigned int r = (u + 0x7fffu + ((u >> 16) & 1u)) >> 16;
    return (u16)r;
}

// ---------------------------------------------------------------------------
// diagnostics: code 32 = CSR inconsistent; 1000+ = ws too small
// ---------------------------------------------------------------------------
__global__ void k_diag(float* out, int n, float val)
{
    int i = blockIdx.x * 256 + threadIdx.x;
    if (i < n) out[i] = val;
}

__global__ void scan_csr(const int* off, const int* srcs, int N, int E,
                         int* flag, int bit)
{
    int i = blockIdx.x * 256 + threadIdx.x;
    if (i < N) {
        int a = off[i], b = off[i + 1];
        if (a < 0 || b < a || b > E) atomicOr(flag, bit);
    }
    if (i == 0 && off[N] != E) atomicOr(flag, bit);
    if (i < E) {
        if ((unsigned)srcs[i] >= (unsigned)N) atomicOr(flag, bit);
    }
}

__global__ void k_final_diag(const int* flag, float* out, int n)
{
    int f = *flag;
    if (f == 0) return;
    int b = __ffs(f) - 1;
    float val = 32.0f * (b + 1);
    int i = blockIdx.x * 256 + threadIdx.x;
    if (i < n) out[i] = val;
}

// ---------------------------------------------------------------------------
// edge_index dtype probe + canonical int32 extraction (+ degree count fused)
// ---------------------------------------------------------------------------
__global__ void k_detect(const int* ei, int E, int* flag64)
{
    __shared__ int zc;
    if (threadIdx.x == 0) zc = 0;
    __syncthreads();
    int idx = 1 + 2 * (int)threadIdx.x;
    int z = (idx < 2 * E && ei[idx] == 0) ? 1 : 0;
    atomicAdd(&zc, z);
    __syncthreads();
    if (threadIdx.x == 0) *flag64 = (zc >= 200) ? 1 : 0;
}

__global__ void k_extract(const int* ei, int E, const int* flag64,
                          int* src, int* dst, int* deg, int N)
{
    int e = blockIdx.x * 256 + threadIdx.x;
    if (e >= E) return;
    int s, d;
    if (*flag64) {
        s = ei[2 * e];
        d = ei[2 * E + 2 * e];
    } else {
        s = ei[e];
        d = ei[E + e];
    }
    src[e] = s; dst[e] = d;
    if ((unsigned)d < (unsigned)N) atomicAdd(&deg[d], 1);
}

// ---------------------------------------------------------------------------
// device-wide exclusive scan, 3-phase (1024 elems per block in phase A)
// ---------------------------------------------------------------------------
__global__ __launch_bounds__(256)
void k_scan_a(const int* __restrict__ deg, int* __restrict__ off,
              int* __restrict__ partial, int N)
{
    __shared__ int sd[256];
    int tid = threadIdx.x;
    int base = blockIdx.x * 1024;
    int i0 = base + tid * 4;
    int v0 = 0, v1 = 0, v2 = 0, v3 = 0;
    if (i0 < N)     v0 = deg[i0];
    if (i0 + 1 < N) v1 = deg[i0 + 1];
    if (i0 + 2 < N) v2 = deg[i0 + 2];
    if (i0 + 3 < N) v3 = deg[i0 + 3];
    int t = v0 + v1 + v2 + v3;
    sd[tid] = t;
    __syncthreads();
    #pragma unroll
    for (int s = 1; s < 256; s <<= 1) {
        int u = (tid >= s) ? sd[tid - s] : 0;
        __syncthreads();
        sd[tid] += u;
        __syncthreads();
    }
    int excl = sd[tid] - t;                 // exclusive within block
    if (i0 < N)     off[i0]     = excl;
    if (i0 + 1 < N) off[i0 + 1] = excl + v0;
    if (i0 + 2 < N) off[i0 + 2] = excl + v0 + v1;
    if (i0 + 3 < N) off[i0 + 3] = excl + v0 + v1 + v2;
    if (tid == 255) partial[blockIdx.x] = sd[255];
}

__global__ __launch_bounds__(1024)
void k_scan_b(int* partial, int nblk)
{
    __shared__ int sd[1024];
    __shared__ int running;
    int tid = threadIdx.x;
    if (tid == 0) running = 0;
    __syncthreads();
    for (int base = 0; base < nblk; base += 1024) {
        int i = base + tid;
        int v = (i < nblk) ? partial[i] : 0;
        sd[tid] = v;
        __syncthreads();
        for (int s = 1; s < 1024; s <<= 1) {
            int u = (tid >= s) ? sd[tid - s] : 0;
            __syncthreads();
            sd[tid] += u;
            __syncthreads();
        }
        if (i < nblk) partial[i] = sd[tid] - v + running;   // exclusive
        int total = sd[1023];
        __syncthreads();
        if (tid == 0) running += total;
        __syncthreads();
    }
}

__global__ __launch_bounds__(256)
void k_scan_c(int* __restrict__ off, int* __restrict__ cursor,
              const int* __restrict__ partial, int N, int E)
{
    int i = blockIdx.x * 256 + threadIdx.x;
    if (i < N) {
        int v = off[i] + partial[i >> 10];
        off[i] = v;
        cursor[i] = v;
    }
    if (i == 0) off[N] = E;
}

__global__ void k_scatter(const int* src, const int* dst, int* cursor,
                          int* srcs, int E, int N)
{
    int e = blockIdx.x * 256 + threadIdx.x;
    if (e < E) {
        int d = dst[e];
        if ((unsigned)d < (unsigned)N) {
            int p = atomicAdd(&cursor[d], 1);
            if ((unsigned)p < (unsigned)E) srcs[p] = src[e];
        }
    }
}

// ---------------------------------------------------------------------------
// fused fp32->bf16 cast + row dots vs (vs,vd): 8 rows/block, 32 lanes/row.
// ---------------------------------------------------------------------------
__global__ __launch_bounds__(256)
void k_castdot(const float* __restrict__ x, const float* __restrict__ vs,
               const float* __restrict__ vd, u16* __restrict__ xb,
               float* __restrict__ a_s, float* __restrict__ a_d, int N)
{
    int tid = threadIdx.x;
    int rowb = tid >> 5;                // 0..7
    int col8 = (tid & 31) * 8;
    int n = blockIdx.x * 8 + rowb;
    if (n >= N) return;
    const float* xr = x + (size_t)n * 256 + col8;
    float4 v0 = *(const float4*)xr;
    float4 v1 = *(const float4*)(xr + 4);
    int4 w;
    w.x = (int)f2b(v0.x) | ((int)f2b(v0.y) << 16);
    w.y = (int)f2b(v0.z) | ((int)f2b(v0.w) << 16);
    w.z = (int)f2b(v1.x) | ((int)f2b(v1.y) << 16);
    w.w = (int)f2b(v1.z) | ((int)f2b(v1.w) << 16);
    *(int4*)(xb + (size_t)n * 256 + col8) = w;

    float4 s0 = *(const float4*)(vs + col8);
    float4 s1 = *(const float4*)(vs + col8 + 4);
    float4 d0 = *(const float4*)(vd + col8);
    float4 d1 = *(const float4*)(vd + col8 + 4);
    float ss = v0.x*s0.x + v0.y*s0.y + v0.z*s0.z + v0.w*s0.w
             + v1.x*s1.x + v1.y*s1.y + v1.z*s1.z + v1.w*s1.w;
    float sd = v0.x*d0.x + v0.y*d0.y + v0.z*d0.z + v0.w*d0.w
             + v1.x*d1.x + v1.y*d1.y + v1.z*d1.z + v1.w*d1.w;
    #pragma unroll
    for (int m = 16; m; m >>= 1) {
        ss += __shfl_xor(ss, m, 64);
        sd += __shfl_xor(sd, m, 64);
    }
    if ((tid & 31) == 0) { a_s[n] = ss; a_d[n] = sd; }
}

// ---------------------------------------------------------------------------
// fragment-major weight pack, all weights in one launch (blockIdx.z selects)
// out[(kt*NC16 + cf)*512 + l*8 + j] = bf16( W[kt*32+(l>>4)*8+j][cf*16+(l&15)] )
// ---------------------------------------------------------------------------
__global__ __launch_bounds__(64)
void k_packAll(const float* A1w, const float* W1, const float* W2, const float* A2w,
               const float* Hw1, const float* Hw2, const float* Hw3,
               u16* WT1, u16* WT2, u16* WTH)
{
    int z = blockIdx.z;
    const float *in1, *in2; int ksplit, csplit, in_ld, NC16; u16* out;
    if (z == 0)      { in1 = A1w; in2 = W1;  ksplit = 256; csplit = 0;   in_ld = 512; out = WT1; NC16 = 32; }
    else if (z == 1) { in1 = W2;  in2 = A2w; ksplit = 0;   csplit = 256; in_ld = 256; out = WT2; NC16 = 32; }
    else {
        if (blockIdx.x >= 16 || blockIdx.y >= 8) return;
        in1 = (z == 2) ? Hw1 : (z == 3) ? Hw2 : Hw3;
        in2 = nullptr; ksplit = 0; csplit = 0; in_ld = 256; NC16 = 16;
        out = WTH + (size_t)(z - 2) * 65536;
    }
    int l = threadIdx.x;
    int cf = blockIdx.x, kt = blockIdx.y;
    int col = cf * 16 + (l & 15);
    int kbase = kt * 32 + (l >> 4) * 8;
    const float* src = in1;
    int cc = col, koff = 0;
    if (ksplit > 0 && kbase >= ksplit) { src = in2; koff = ksplit; }
    if (csplit > 0 && col >= csplit)   { src = in2; cc = col - csplit; }
    u16* o = out + ((size_t)(kt * NC16 + cf) * 512) + l * 8;
    #pragma unroll
    for (int j = 0; j < 8; ++j)
        o[j] = f2b(src[(size_t)(kbase - koff + j) * in_ld + cc]);
}

// ---------------------------------------------------------------------------
// fp32 row-dot against two fp32 vectors — one wave per row, float4 lanes
// ---------------------------------------------------------------------------
__global__ __launch_bounds__(256)
void k_rowdot2f(const float* __restrict__ A, int ld, int H,
                const float* __restrict__ vs, const float* __restrict__ vd,
                float* a_s, float* a_d, int N)
{
    int wave = threadIdx.x >> 6, lane = threadIdx.x & 63;
    int n = blockIdx.x * 4 + wave;
    if (n >= N) return;
    const float* ar = A + (size_t)n * ld;
    float ss = 0.f, sd = 0.f;
    for (int i = lane * 4; i < H; i += 256) {
        float4 v  = *(const float4*)(ar + i);
        float4 s4 = *(const float4*)(vs + i);
        float4 d4 = *(const float4*)(vd + i);
        ss += v.x * s4.x + v.y * s4.y + v.z * s4.z + v.w * s4.w;
        sd += v.x * d4.x + v.y * d4.y + v.z * d4.z + v.w * d4.w;
    }
    #pragma unroll
    for (int m = 32; m; m >>= 1) {
        ss += __shfl_xor(ss, m, 64);
        sd += __shfl_xor(sd, m, 64);
    }
    if (lane == 0) { a_s[n] = ss; a_d[n] = sd; }
}

// ---------------------------------------------------------------------------
// FLASH-STYLE fused softmax + gather-aggregate (single edge pass).
// Softmax normalization sum(e^(z-m) row)/sum(e^(z-m)) is invariant to the
// reference m; m only guards overflow. Each half-wave keeps running
// (m, s, acc[8]) with defer-threshold rescale (z > m+8 -> rescale, rare);
// halves merged exp-weighted at the end. Replaces k_alpha1p + k_aggw.
// ---------------------------------------------------------------------------
__global__ __launch_bounds__(256)
void k_aggfl(const u16* __restrict__ rows, const int* __restrict__ off,
             const int* __restrict__ srcs, const float* __restrict__ a_s,
             const float* __restrict__ a_d,
             const u16* __restrict__ add, u16* __restrict__ out, int N)
{
    int wave = threadIdx.x >> 6, lane = threadIdx.x & 63;
    int n = blockIdx.x * 4 + wave;
    if (n >= N) return;
    int base = off[n], end = off[n + 1];
    float adn = a_d[n];
    int half = lane >> 5;
    int c8 = (lane & 31) * 8;
    float m = -1e30f, s = 0.f;
    float acc[8] = {};
    int p = base;
    for (; p + 3 < end; p += 4) {
        int sA = srcs[p + half];
        int sB = srcs[p + 2 + half];
        sA = ((unsigned)sA < (unsigned)N) ? sA : 0;
        sB = ((unsigned)sB < (unsigned)N) ? sB : 0;
        float zA = a_s[sA] + adn; zA = fmaxf(zA, NEG_SLOPE * zA);
        float zB = a_s[sB] + adn; zB = fmaxf(zB, NEG_SLOPE * zB);
        float z2 = fmaxf(zA, zB);
        if (z2 > m + 8.f) {
            float r = __expf(m - z2);
            s *= r;
            #pragma unroll
            for (int j = 0; j < 8; ++j) acc[j] *= r;
            m = z2;
        }
        float wA = __expf(zA - m), wB = __expf(zB - m);
        s += wA + wB;
        u16x8 vA = *(const u16x8*)(rows + (size_t)sA * 256 + c8);
        u16x8 vB = *(const u16x8*)(rows + (size_t)sB * 256 + c8);
        #pragma unroll
        for (int j = 0; j < 8; ++j)
            acc[j] += wA * b2f(vA[j]) + wB * b2f(vB[j]);
    }
    for (; p + 1 < end; p += 2) {
        int sA = srcs[p + half];
        sA = ((unsigned)sA < (unsigned)N) ? sA : 0;
        float zA = a_s[sA] + adn; zA = fmaxf(zA, NEG_SLOPE * zA);
        if (zA > m + 8.f) {
            float r = __expf(m - zA);
            s *= r;
            #pragma unroll
            for (int j = 0; j < 8; ++j) acc[j] *= r;
            m = zA;
        }
        float wA = __expf(zA - m);
        s += wA;
        u16x8 vA = *(const u16x8*)(rows + (size_t)sA * 256 + c8);
        #pragma unroll
        for (int j = 0; j < 8; ++j)
            acc[j] += wA * b2f(vA[j]);
    }
    if (p < end && half == 0) {          // odd tail edge: half 0 only
        int sA = srcs[p];
        sA = ((unsigned)sA < (unsigned)N) ? sA : 0;
        float zA = a_s[sA] + adn; zA = fmaxf(zA, NEG_SLOPE * zA);
        if (zA > m + 8.f) {
            float r = __expf(m - zA);
            s *= r;
            #pragma unroll
            for (int j = 0; j < 8; ++j) acc[j] *= r;
            m = zA;
        }
        float wA = __expf(zA - m);
        s += wA;
        u16x8 vA = *(const u16x8*)(rows + (size_t)sA * 256 + c8);
        #pragma unroll
        for (int j = 0; j < 8; ++j)
            acc[j] += wA * b2f(vA[j]);
    }
    // merge the two half-wave states (exp-weighted; symmetric in both halves)
    float mo = __shfl_xor(m, 32, 64);
    float so = __shfl_xor(s, 32, 64);
    float mn = fmaxf(m, mo);
    float rA = __expf(m - mn), rB = __expf(mo - mn);
    float st = s * rA + so * rB;
    float invs = 1.f / (st + 1e-16f);
    #pragma unroll
    for (int j = 0; j < 8; ++j) {
        float ao = __shfl_xor(acc[j], 32, 64);
        acc[j] = acc[j] * rA + ao * rB;
    }
    if (half == 0) {
        size_t ob = (size_t)n * 256 + c8;
        if (add) {
            u16x8 ad8 = *(const u16x8*)(add + ob);
            #pragma unroll
            for (int j = 0; j < 8; ++j) acc[j] = acc[j] * invs + b2f(ad8[j]);
        } else {
            #pragma unroll
            for (int j = 0; j < 8; ++j) acc[j] *= invs;
        }
        u16x8 o;
        #pragma unroll
        for (int j = 0; j < 8; ++j) o[j] = f2b(acc[j]);
        *(u16x8*)(out + ob) = o;
    }
}

// ---------------------------------------------------------------------------
// full-width fused MFMA GEMM: BM=64, K=512 (two bf16 A halves of 256 each),
// NC=512 from fragment-major pre-packed WTf. Output split at col 256 into
// (C1, C2) with per-half fp32 bias pairs and relu flags. A read ONCE from HBM.
// 8 waves, each owns a 64x64 tile; LDS-staged bulk prefetch (measured-best
// structure), staging via async global_load_lds width=16.
// Optional fused row-dots on the C1 half (bf16-rounded acc · dotS/dotD,
// atomicAdd into oaS/oaD) — replaces the separate rowdot pass over h2.
// ---------------------------------------------------------------------------
__global__ __launch_bounds__(512)
void bigfull(const u16* __restrict__ A1, int lda1,
             const u16* __restrict__ A2, int lda2,
             const u16* __restrict__ WTf,
             const float* b0a, const float* b0b,
             const float* b1a, const float* b1b,
             u16* C1, int ldc1, u16* C2, int ldc2,
             const float* __restrict__ dotS, const float* __restrict__ dotD,
             float* oaS, float* oaD,
             int M, int relu0, int relu1)
{
    __shared__ u16 As[64 * 32];      // frag-major: [rf][lane][8]   (4 KB)
    __shared__ u16 Bs[512 * 32];     // frag-major: [cf][lane][8]  (32 KB)

    const int tid = threadIdx.x;
    const int w = tid >> 6, lane = tid & 63;
    const int m16 = lane & 15, q = lane >> 4;
    const int rowBase = blockIdx.x * 64;

    // waves 0-3 stage row-fragment rf = w: per-lane source row (clamped)
    int garow = rowBase + (w & 3) * 16 + m16;
    if (garow >= M) garow = M - 1;          // clamp; value unused when OOB

    float4v acc[16] = {};

    for (int k0 = 0; k0 < 512; k0 += 32) {
        const int kt = k0 >> 5;
        __syncthreads();
        if (w < 4) {   // stage A 64x32 into fragment order (async, 16B/lane)
            int kk = k0 + q * 8;
            const u16* src = (kk < 256)
                ? A1 + (size_t)garow * lda1 + kk
                : A2 + (size_t)garow * lda2 + (kk - 256);
            GLOAD_LDS16(src, &As[w * 512]);
        }
        {   // stage B 512x32: linear async copy of pre-packed fragments
            const u16* wsrc = WTf + (size_t)kt * 16384;
            #pragma unroll
            for (int p = 0; p < 4; ++p) {
                int chb = p * 512 + w * 64;          // wave-uniform chunk base
                GLOAD_LDS16(wsrc + ((size_t)chb + lane) * 8, &Bs[chb * 8]);
            }
        }
        __syncthreads();

        short8 a[4], b[4];
        #pragma unroll
        for (int r = 0; r < 4; ++r)
            a[r] = *(const short8*)&As[r * 512 + lane * 8];
        #pragma unroll
        for (int c = 0; c < 4; ++c)
            b[c] = *(const short8*)&Bs[(w * 4 + c) * 512 + lane * 8];
        #pragma unroll
        for (int r = 0; r < 4; ++r)
            #pragma unroll
            for (int c = 0; c < 4; ++c)
                acc[r * 4 + c] = __builtin_amdgcn_mfma_f32_16x16x32_bf16(
                    a[r], b[c], acc[r * 4 + c], 0, 0, 0);
    }

    const int colgrp = w >> 2;
    const float* ba = colgrp ? b1a : b0a;
    const float* bb = colgrp ? b1b : b0b;
    u16* C  = colgrp ? C2 : C1;
    const int ldc  = colgrp ? ldc2 : ldc1;
    const int relu = colgrp ? relu1 : relu0;
    #pragma unroll
    for (int c = 0; c < 4; ++c) {
        int lc = ((w & 3) * 4 + c) * 16 + m16;
        float bv = (ba ? ba[lc] : 0.f) + (bb ? bb[lc] : 0.f);
        #pragma unroll
        for (int r = 0; r < 4; ++r)
            #pragma unroll
            for (int i = 0; i < 4; ++i) {
                int grow = rowBase + r * 16 + q * 4 + i;
                if (grow < M) {
                    float v = acc[r * 4 + c][i] + bv;
                    if (relu) v = fmaxf(v, 0.f);
                    C[(size_t)grow * ldc + lc] = f2b(v);
                }
            }
    }

    // fused attention row-dots on the C1 half (no bias / no relu path)
    if (dotS && colgrp == 0) {
        #pragma unroll
        for (int r = 0; r < 4; ++r)
            #pragma unroll
            for (int i = 0; i < 4; ++i) {
                float ss = 0.f, sd = 0.f;
                #pragma unroll
                for (int c = 0; c < 4; ++c) {
                    int lc = ((w & 3) * 4 + c) * 16 + m16;
                    float v = b2f(f2b(acc[r * 4 + c][i]));  // match stored bf16
                    ss += v * dotS[lc];
                    sd += v * dotD[lc];
                }
                #pragma unroll
                for (int msk = 1; msk < 16; msk <<= 1) {
                    ss += __shfl_xor(ss, msk, 64);
                    sd += __shfl_xor(sd, msk, 64);
                }
                int grow = rowBase + r * 16 + q * 4 + i;
                if (m16 == 0 && grow < M) {
                    atomicAdd(&oaS[grow], ss);
                    atomicAdd(&oaD[grow], sd);
                }
            }
    }
}

// ---------------------------------------------------------------------------
// fused 3-layer MLP [256->256] relu + classifier + softmax. 512 threads =
// 8 waves sharing a 64-row frag-major LDS panel (32 KB); each wave owns
// 64 rows x 32 cols (8 acc frags -> low VGPR -> high occupancy). B read
// directly per-wave from L2. Final layer stays in the panel; fc 256->5 +
// softmax computed from it (waves 0-3), writing only `out`.
// ---------------------------------------------------------------------------
__global__ __launch_bounds__(512)
void k_mlp3fc(const u16* __restrict__ WTHf,
              const float* Hb1, const float* Hb2, const float* Hb3,
              const float* __restrict__ fcw, const float* __restrict__ fcb,
              const u16* __restrict__ Hin, float* __restrict__ out, int M)
{
    __shared__ u16 P[64 * 256];     // frag-major activation panel (32 KB)

    const int tid = threadIdx.x;
    const int w = tid >> 6, lane = tid & 63;
    const int m16 = lane & 15, q = lane >> 4;
    const int rowBase = blockIdx.x * 64;

    // load panel (global row-major -> fragment-major), 4 chunks/thread
    #pragma unroll
    for (int p = 0; p < 4; ++p) {
        int ch = p * 512 + tid;          // 0..2047 16B-chunks
        int f = ch >> 6, l = ch & 63;    // frag f = kt*4+rf, lane-slot l
        int kt = f >> 2, rf = f & 3;
        int grow = rowBase + rf * 16 + (l & 15);
        if (grow >= M) grow = M - 1;
        int col = kt * 32 + (l >> 4) * 8;
        *(int4*)&P[ch * 8] = *(const int4*)(Hin + (size_t)grow * 256 + col);
    }
    __syncthreads();

    const float* biases[3] = {Hb1, Hb2, Hb3};
    for (int L = 0; L < 3; ++L) {
        const u16* WTf = WTHf + (size_t)L * 65536;
        float4v acc[8] = {};
        #pragma unroll 2
        for (int kt = 0; kt < 8; ++kt) {
            short8 a[4], b[2];
            #pragma unroll
            for (int c = 0; c < 2; ++c) {
                int4 bv = *(const int4*)(WTf + (size_t)(kt * 16 + w * 2 + c) * 512
                                         + lane * 8);
                b[c] = *(short8*)&bv;
            }
            #pragma unroll
            for (int r = 0; r < 4; ++r)
                a[r] = *(const short8*)&P[(kt * 4 + r) * 512 + lane * 8];
            #pragma unroll
            for (int r = 0; r < 4; ++r)
                #pragma unroll
                for (int c = 0; c < 2; ++c)
                    acc[r * 2 + c] = __builtin_amdgcn_mfma_f32_16x16x32_bf16(
                        a[r], b[c], acc[r * 2 + c], 0, 0, 0);
        }
        const float* bias = biases[L];
        __syncthreads();    // all panel reads done before overwrite
        // writeback into fragment-major panel (out col -> next-layer k)
        #pragma unroll
        for (int c = 0; c < 2; ++c) {
            int col = w * 32 + c * 16 + m16;
            float bv = bias[col];
            int kt2 = col >> 5;               // == w
            int l2h = 16 * ((col & 31) >> 3);
            int j2 = col & 7;
            #pragma unroll
            for (int r = 0; r < 4; ++r)
                #pragma unroll
                for (int i = 0; i < 4; ++i) {
                    int l2 = (q * 4 + i) + l2h;
                    P[(size_t)(kt2 * 4 + r) * 512 + l2 * 8 + j2] =
                        f2b(fmaxf(acc[r * 2 + c][i] + bv, 0.f));
                }
        }
        __syncthreads();
    }

    // classifier + softmax from the panel (waves 0-3, rf = w).
    if (w < 4) {
        float p5[5] = {0.f, 0.f, 0.f, 0.f, 0.f};
        #pragma unroll
        for (int kt = 0; kt < 8; ++kt) {
            u16x8 v = *(const u16x8*)&P[(kt * 4 + w) * 512 + lane * 8];
            int colb = kt * 32 + q * 8;
            #pragma unroll
            for (int j = 0; j < 8; ++j) {
                float hv = b2f(v[j]);
                const float* wr = fcw + (size_t)(colb + j) * 5;
                #pragma unroll
                for (int c = 0; c < 5; ++c) p5[c] += hv * wr[c];
            }
        }
        #pragma unroll
        for (int c = 0; c < 5; ++c) {
            p5[c] += __shfl_xor(p5[c], 16, 64);
            p5[c] += __shfl_xor(p5[c], 32, 64);
        }
        int grow = rowBase + w * 16 + m16;
        if (q == 0 && grow < M) {
            float mx = -1e30f;
            #pragma unroll
            for (int c = 0; c < 5; ++c) { p5[c] += fcb[c]; mx = fmaxf(mx, p5[c]); }
            float s = 0.f, e[5];
            #pragma unroll
            for (int c = 0; c < 5; ++c) { e[c] = __expf(p5[c] - mx); s += e[c]; }
            float inv = 1.f / s;
            #pragma unroll
            for (int c = 0; c < 5; ++c) out[(size_t)grow * 5 + c] = e[c] * inv;
        }
    }
}

// ---------------------------------------------------------------------------
extern "C" void kernel_launch(void* const* d_in, const int* in_sizes, int n_in,
                              void* d_out, int out_size, void* d_ws, size_t ws_size,
                              hipStream_t stream)
{
    const float* x    = (const float*)d_in[0];
    const int*   ei   = (const int*)  d_in[1];
    const float* W1   = (const float*)d_in[2];
    const float* as1  = (const float*)d_in[3];
    const float* ad1  = (const float*)d_in[4];
    const float* bc1  = (const float*)d_in[5];
    const float* A1w  = (const float*)d_in[6];
    const float* b1   = (const float*)d_in[7];
    const float* W2   = (const float*)d_in[8];
    const float* as2  = (const float*)d_in[9];
    const float* ad2  = (const float*)d_in[10];
    const float* bc2  = (const float*)d_in[11];
    const float* A2w  = (const float*)d_in[12];
    const float* b2   = (const float*)d_in[13];
    const float* Hw1  = (const float*)d_in[14];
    const float* Hb1  = (const float*)d_in[15];
    const float* Hw2  = (const float*)d_in[16];
    const float* Hb2  = (const float*)d_in[17];
    const float* Hw3  = (const float*)d_in[18];
    const float* Hb3  = (const float*)d_in[19];
    const float* fcw  = (const float*)d_in[20];
    const float* fcb  = (const float*)d_in[21];
    float* out = (float*)d_out;

    const int D = 256;
    const int N = in_sizes[0] / D;
    const int E = in_sizes[1] / 2;

    char* w = (char*)d_ws;
    auto alloc = [&](size_t bytes) {
        char* p = w;
        w += (bytes + 255) & ~(size_t)255;
        return p;
    };
    int*   flag   = (int*)  alloc(256);
    int*   flag64 = (int*)  alloc(256);
    float* a_s    = (float*)alloc((size_t)N * 4);
    float* a_d    = (float*)alloc((size_t)N * 4);
    float* vs1    = (float*)alloc(1024);                 // W1 @ att_src1  [256]
    float* vd1    = (float*)alloc(1024);                 // W1 @ att_dst1  [256]
    int*   deg    = (int*)  alloc((size_t)N * 4);
    int*   cursor = (int*)  alloc((size_t)N * 4);
    int*   offA   = (int*)  alloc((size_t)(N + 1) * 4);
    int*   part   = (int*)  alloc((size_t)((N + 1023) / 1024 + 1) * 4);
    int*   srcs   = (int*)  alloc((size_t)E * 4);
    u16*   WT1    = (u16*)  alloc(512 * 512 * 2);        // frag-major [A1w;W1]
    u16*   WT2    = (u16*)  alloc(512 * 512 * 2);        // frag-major [W2|A2w]
    u16*   WTH    = (u16*)  alloc(3 * 256 * 256 * 2);    // frag-major MLP weights
    u16*   BUF1   = (u16*)  alloc((size_t)N * 512 * 2);  // xb|aggx -> h2|res2
    u16*   BUF2   = (u16*)  alloc((size_t)N * 512 * 2);  // hl1 -> out2

    // src32/dst32 alias BUF1 (dead before xb is written)
    int* src32 = (int*)BUF1;
    int* dst32 = src32 + E;

    size_t need = (size_t)(w - (char*)d_ws);             // ~110 MB
    if (ws_size < need) {
        float code = 1000.0f + (float)(ws_size >> 20);
        k_diag<<<(out_size + 255) / 256, 256, 0, stream>>>(out, out_size, code);
        return;
    }

    const int EB  = (E + 255) / 256;
    const int NB4 = (N + 3) / 4;
    const int OB  = (out_size + 255) / 256;
    const int NE  = (N > E ? N : E);
    const int RB64 = (N + 63) / 64;
    const int NBLK = (N + 1023) / 1024;
    const size_t NH2 = (size_t)N * 256;
    u16* XB   = BUF1;            // bf16 cast of x      [N,256]
    u16* AGGX = BUF1 + NH2;      // alpha-aggregated x  [N,256]

    hipMemsetAsync(flag, 0, 4, stream);
    hipMemsetAsync(deg, 0, (size_t)N * 4, stream);

    // ---- edge extraction (+degree count) + CSR by destination ----
    k_detect <<<1, 256, 0, stream>>>(ei, E, flag64);
    k_extract<<<EB, 256, 0, stream>>>(ei, E, flag64, src32, dst32, deg, N);
    k_scan_a <<<NBLK, 256, 0, stream>>>(deg, offA, part, N);
    k_scan_b <<<1, 1024, 0, stream>>>(part, NBLK);
    k_scan_c <<<(N + 255) / 256, 256, 0, stream>>>(offA, cursor, part, N, E);
    k_scatter<<<EB, 256, 0, stream>>>(src32, dst32, cursor, srcs, E, N);
    scan_csr <<<(NE + 255) / 256, 256, 0, stream>>>(offA, srcs, N, E, flag, 1);

    // ---- weight pre-pack (fragment-major bf16, single launch) ----
    k_packAll<<<dim3(32, 16, 5), 64, 0, stream>>>(A1w, W1, W2, A2w,
                                                  Hw1, Hw2, Hw3, WT1, WT2, WTH);

    // ---- attention vectors, then fused cast+dot over x ----
    k_rowdot2f<<<64, 256, 0, stream>>>(W1, 512, 512, as1, ad1, vs1, vd1, 256);
    k_castdot<<<(N + 7) / 8, 256, 0, stream>>>(x, vs1, vd1, XB, a_s, a_d, N);

    // ---- aggx = flash-style softmax-aggregate of xb (single edge pass) ----
    k_aggfl<<<NB4, 256, 0, stream>>>(XB, offA, srcs, a_s, a_d,
                                     nullptr, AGGX, N);

    // a_s/a_d fully consumed by aggfl-1; zero for bigfull-2's atomic dots
    hipMemsetAsync(a_s, 0, (size_t)N * 4, stream);
    hipMemsetAsync(a_d, 0, (size_t)N * 4, stream);

    // ---- layer 1 fused: hl1 = relu([XB|AGGX] @ [A1w;W1] + b1 + bc1) ----
    bigfull<<<RB64, 512, 0, stream>>>(XB, 256, AGGX, 256, WT1,
                                      b1, bc1, b1 + 256, bc1 + 256,
                                      BUF2, 512, BUF2 + 256, 512,
                                      nullptr, nullptr, nullptr, nullptr,
                                      N, 1, 1);

    // ---- layer 2 fused: [h2 | res2] = hl1 @ [W2 | A2w] (+b2+bc2 on res2),
    //      with a_s2/a_d2 = h2·att2 accumulated in the epilogue ----
    bigfull<<<RB64, 512, 0, stream>>>(BUF2, 512, BUF2 + 256, 512, WT2,
                                      nullptr, nullptr, b2, bc2,
                                      BUF1, 256, BUF1 + NH2, 256,
                                      as2, ad2, a_s, a_d,
                                      N, 0, 0);

    // ---- layer-2 flash aggregate + residual add ----
    k_aggfl<<<NB4, 256, 0, stream>>>(BUF1, offA, srcs, a_s, a_d,
                                     BUF1 + NH2, BUF2, N);

    // ---- fused 3-layer MLP + classifier + softmax (reads BUF2, writes out) ----
    k_mlp3fc<<<RB64, 512, 0, stream>>>(WTH, Hb1, Hb2, Hb3, fcw, fcb,
                                       BUF2, out, N);

    k_final_diag<<<OB, 256, 0, stream>>>(flag, out, out_size);
}

// Round 13
// 501.183 us; speedup vs baseline: 1.1821x; 1.0205x over previous
//
#include <hip/hip_runtime.h>

typedef unsigned short u16;
typedef short short8 __attribute__((ext_vector_type(8)));
typedef u16 u16x8 __attribute__((ext_vector_type(8)));
typedef float float4v __attribute__((ext_vector_type(4)));

#define NEG_SLOPE 0.2f

#define GLOAD_LDS16(g, l) __builtin_amdgcn_global_load_lds(                    \
    (const __attribute__((address_space(1))) void*)(g),                        \
    (__attribute__((address_space(3))) void*)(l), 16, 0, 0)

static __device__ __forceinline__ float b2f(u16 u) {
    union { unsigned int i; float f; } x; x.i = ((unsigned int)u) << 16; return x.f;
}
static __device__ __forceinline__ u16 f2b(float f) {
    unsigned int u = __float_as_uint(f);
    unsigned int r = (u + 0x7fffu + ((u >> 16) & 1u)) >> 16;
    return (u16)r;
}

// ---------------------------------------------------------------------------
// diagnostics: code 32 = CSR inconsistent; 1000+ = ws too small
// ---------------------------------------------------------------------------
__global__ void k_diag(float* out, int n, float val)
{
    int i = blockIdx.x * 256 + threadIdx.x;
    if (i < n) out[i] = val;
}

__global__ void scan_csr(const int* off, const int* srcs, int N, int E,
                         int* flag, int bit)
{
    int i = blockIdx.x * 256 + threadIdx.x;
    if (i < N) {
        int a = off[i], b = off[i + 1];
        if (a < 0 || b < a || b > E) atomicOr(flag, bit);
    }
    if (i == 0 && off[N] != E) atomicOr(flag, bit);
    if (i < E) {
        if ((unsigned)srcs[i] >= (unsigned)N) atomicOr(flag, bit);
    }
}

__global__ void k_final_diag(const int* flag, float* out, int n)
{
    int f = *flag;
    if (f == 0) return;
    int b = __ffs(f) - 1;
    float val = 32.0f * (b + 1);
    int i = blockIdx.x * 256 + threadIdx.x;
    if (i < n) out[i] = val;
}

// ---------------------------------------------------------------------------
// edge_index dtype probe + canonical int32 extraction (+ degree count fused)
// ---------------------------------------------------------------------------
__global__ void k_detect(const int* ei, int E, int* flag64)
{
    __shared__ int zc;
    if (threadIdx.x == 0) zc = 0;
    __syncthreads();
    int idx = 1 + 2 * (int)threadIdx.x;
    int z = (idx < 2 * E && ei[idx] == 0) ? 1 : 0;
    atomicAdd(&zc, z);
    __syncthreads();
    if (threadIdx.x == 0) *flag64 = (zc >= 200) ? 1 : 0;
}

__global__ void k_extract(const int* ei, int E, const int* flag64,
                          int* src, int* dst, int* deg, int N)
{
    int e = blockIdx.x * 256 + threadIdx.x;
    if (e >= E) return;
    int s, d;
    if (*flag64) {
        s = ei[2 * e];
        d = ei[2 * E + 2 * e];
    } else {
        s = ei[e];
        d = ei[E + e];
    }
    src[e] = s; dst[e] = d;
    if ((unsigned)d < (unsigned)N) atomicAdd(&deg[d], 1);
}

// ---------------------------------------------------------------------------
// device-wide exclusive scan, 3-phase (1024 elems per block in phase A)
// ---------------------------------------------------------------------------
__global__ __launch_bounds__(256)
void k_scan_a(const int* __restrict__ deg, int* __restrict__ off,
              int* __restrict__ partial, int N)
{
    __shared__ int sd[256];
    int tid = threadIdx.x;
    int base = blockIdx.x * 1024;
    int i0 = base + tid * 4;
    int v0 = 0, v1 = 0, v2 = 0, v3 = 0;
    if (i0 < N)     v0 = deg[i0];
    if (i0 + 1 < N) v1 = deg[i0 + 1];
    if (i0 + 2 < N) v2 = deg[i0 + 2];
    if (i0 + 3 < N) v3 = deg[i0 + 3];
    int t = v0 + v1 + v2 + v3;
    sd[tid] = t;
    __syncthreads();
    #pragma unroll
    for (int s = 1; s < 256; s <<= 1) {
        int u = (tid >= s) ? sd[tid - s] : 0;
        __syncthreads();
        sd[tid] += u;
        __syncthreads();
    }
    int excl = sd[tid] - t;                 // exclusive within block
    if (i0 < N)     off[i0]     = excl;
    if (i0 + 1 < N) off[i0 + 1] = excl + v0;
    if (i0 + 2 < N) off[i0 + 2] = excl + v0 + v1;
    if (i0 + 3 < N) off[i0 + 3] = excl + v0 + v1 + v2;
    if (tid == 255) partial[blockIdx.x] = sd[255];
}

__global__ __launch_bounds__(1024)
void k_scan_b(int* partial, int nblk)
{
    __shared__ int sd[1024];
    __shared__ int running;
    int tid = threadIdx.x;
    if (tid == 0) running = 0;
    __syncthreads();
    for (int base = 0; base < nblk; base += 1024) {
        int i = base + tid;
        int v = (i < nblk) ? partial[i] : 0;
        sd[tid] = v;
        __syncthreads();
        for (int s = 1; s < 1024; s <<= 1) {
            int u = (tid >= s) ? sd[tid - s] : 0;
            __syncthreads();
            sd[tid] += u;
            __syncthreads();
        }
        if (i < nblk) partial[i] = sd[tid] - v + running;   // exclusive
        int total = sd[1023];
        __syncthreads();
        if (tid == 0) running += total;
        __syncthreads();
    }
}

__global__ __launch_bounds__(256)
void k_scan_c(int* __restrict__ off, int* __restrict__ cursor,
              const int* __restrict__ partial, int N, int E)
{
    int i = blockIdx.x * 256 + threadIdx.x;
    if (i < N) {
        int v = off[i] + partial[i >> 10];
        off[i] = v;
        cursor[i] = v;
    }
    if (i == 0) off[N] = E;
}

__global__ void k_scatter(const int* src, const int* dst, int* cursor,
                          int* srcs, int E, int N)
{
    int e = blockIdx.x * 256 + threadIdx.x;
    if (e < E) {
        int d = dst[e];
        if ((unsigned)d < (unsigned)N) {
            int p = atomicAdd(&cursor[d], 1);
            if ((unsigned)p < (unsigned)E) srcs[p] = src[e];
        }
    }
}

// ---------------------------------------------------------------------------
// fused fp32->bf16 cast + row dots vs (vs,vd): 8 rows/block, 32 lanes/row.
// ---------------------------------------------------------------------------
__global__ __launch_bounds__(256)
void k_castdot(const float* __restrict__ x, const float* __restrict__ vs,
               const float* __restrict__ vd, u16* __restrict__ xb,
               float* __restrict__ a_s, float* __restrict__ a_d, int N)
{
    int tid = threadIdx.x;
    int rowb = tid >> 5;                // 0..7
    int col8 = (tid & 31) * 8;
    int n = blockIdx.x * 8 + rowb;
    if (n >= N) return;
    const float* xr = x + (size_t)n * 256 + col8;
    float4 v0 = *(const float4*)xr;
    float4 v1 = *(const float4*)(xr + 4);
    int4 w;
    w.x = (int)f2b(v0.x) | ((int)f2b(v0.y) << 16);
    w.y = (int)f2b(v0.z) | ((int)f2b(v0.w) << 16);
    w.z = (int)f2b(v1.x) | ((int)f2b(v1.y) << 16);
    w.w = (int)f2b(v1.z) | ((int)f2b(v1.w) << 16);
    *(int4*)(xb + (size_t)n * 256 + col8) = w;

    float4 s0 = *(const float4*)(vs + col8);
    float4 s1 = *(const float4*)(vs + col8 + 4);
    float4 d0 = *(const float4*)(vd + col8);
    float4 d1 = *(const float4*)(vd + col8 + 4);
    float ss = v0.x*s0.x + v0.y*s0.y + v0.z*s0.z + v0.w*s0.w
             + v1.x*s1.x + v1.y*s1.y + v1.z*s1.z + v1.w*s1.w;
    float sd = v0.x*d0.x + v0.y*d0.y + v0.z*d0.z + v0.w*d0.w
             + v1.x*d1.x + v1.y*d1.y + v1.z*d1.z + v1.w*d1.w;
    #pragma unroll
    for (int m = 16; m; m >>= 1) {
        ss += __shfl_xor(ss, m, 64);
        sd += __shfl_xor(sd, m, 64);
    }
    if ((tid & 31) == 0) { a_s[n] = ss; a_d[n] = sd; }
}

// ---------------------------------------------------------------------------
// fragment-major weight pack, all weights in one launch (blockIdx.z selects)
// out[(kt*NC16 + cf)*512 + l*8 + j] = bf16( W[kt*32+(l>>4)*8+j][cf*16+(l&15)] )
// ---------------------------------------------------------------------------
__global__ __launch_bounds__(64)
void k_packAll(const float* A1w, const float* W1, const float* W2, const float* A2w,
               const float* Hw1, const float* Hw2, const float* Hw3,
               u16* WT1, u16* WT2, u16* WTH)
{
    int z = blockIdx.z;
    const float *in1, *in2; int ksplit, csplit, in_ld, NC16; u16* out;
    if (z == 0)      { in1 = A1w; in2 = W1;  ksplit = 256; csplit = 0;   in_ld = 512; out = WT1; NC16 = 32; }
    else if (z == 1) { in1 = W2;  in2 = A2w; ksplit = 0;   csplit = 256; in_ld = 256; out = WT2; NC16 = 32; }
    else {
        if (blockIdx.x >= 16 || blockIdx.y >= 8) return;
        in1 = (z == 2) ? Hw1 : (z == 3) ? Hw2 : Hw3;
        in2 = nullptr; ksplit = 0; csplit = 0; in_ld = 256; NC16 = 16;
        out = WTH + (size_t)(z - 2) * 65536;
    }
    int l = threadIdx.x;
    int cf = blockIdx.x, kt = blockIdx.y;
    int col = cf * 16 + (l & 15);
    int kbase = kt * 32 + (l >> 4) * 8;
    const float* src = in1;
    int cc = col, koff = 0;
    if (ksplit > 0 && kbase >= ksplit) { src = in2; koff = ksplit; }
    if (csplit > 0 && col >= csplit)   { src = in2; cc = col - csplit; }
    u16* o = out + ((size_t)(kt * NC16 + cf) * 512) + l * 8;
    #pragma unroll
    for (int j = 0; j < 8; ++j)
        o[j] = f2b(src[(size_t)(kbase - koff + j) * in_ld + cc]);
}

// ---------------------------------------------------------------------------
// fp32 row-dot against two fp32 vectors — one wave per row, float4 lanes
// ---------------------------------------------------------------------------
__global__ __launch_bounds__(256)
void k_rowdot2f(const float* __restrict__ A, int ld, int H,
                const float* __restrict__ vs, const float* __restrict__ vd,
                float* a_s, float* a_d, int N)
{
    int wave = threadIdx.x >> 6, lane = threadIdx.x & 63;
    int n = blockIdx.x * 4 + wave;
    if (n >= N) return;
    const float* ar = A + (size_t)n * ld;
    float ss = 0.f, sd = 0.f;
    for (int i = lane * 4; i < H; i += 256) {
        float4 v  = *(const float4*)(ar + i);
        float4 s4 = *(const float4*)(vs + i);
        float4 d4 = *(const float4*)(vd + i);
        ss += v.x * s4.x + v.y * s4.y + v.z * s4.z + v.w * s4.w;
        sd += v.x * d4.x + v.y * d4.y + v.z * d4.z + v.w * d4.w;
    }
    #pragma unroll
    for (int m = 32; m; m >>= 1) {
        ss += __shfl_xor(ss, m, 64);
        sd += __shfl_xor(sd, m, 64);
    }
    if (lane == 0) { a_s[n] = ss; a_d[n] = sd; }
}

// ---------------------------------------------------------------------------
// FLASH-STYLE fused softmax + gather-aggregate (single edge pass), 8 edges
// per iteration (4 per half-wave) so 4 row-gathers are in flight per lane.
// Defer-threshold rescale (group max vs m+8, rare). Halves merged
// exp-weighted at the end.
// ---------------------------------------------------------------------------
__global__ __launch_bounds__(256)
void k_aggfl(const u16* __restrict__ rows, const int* __restrict__ off,
             const int* __restrict__ srcs, const float* __restrict__ a_s,
             const float* __restrict__ a_d,
             const u16* __restrict__ add, u16* __restrict__ out, int N)
{
    int wave = threadIdx.x >> 6, lane = threadIdx.x & 63;
    int n = blockIdx.x * 4 + wave;
    if (n >= N) return;
    int base = off[n], end = off[n + 1];
    float adn = a_d[n];
    int half = lane >> 5;
    int c8 = (lane & 31) * 8;
    float m = -1e30f, s = 0.f;
    float acc[8] = {};
    int p = base;
    // 8-edge groups: half h takes p + 2k + h, k = 0..3
    for (; p + 7 < end; p += 8) {
        int s0 = srcs[p + half];
        int s1 = srcs[p + 2 + half];
        int s2 = srcs[p + 4 + half];
        int s3 = srcs[p + 6 + half];
        s0 = ((unsigned)s0 < (unsigned)N) ? s0 : 0;
        s1 = ((unsigned)s1 < (unsigned)N) ? s1 : 0;
        s2 = ((unsigned)s2 < (unsigned)N) ? s2 : 0;
        s3 = ((unsigned)s3 < (unsigned)N) ? s3 : 0;
        float z0 = a_s[s0] + adn; z0 = fmaxf(z0, NEG_SLOPE * z0);
        float z1 = a_s[s1] + adn; z1 = fmaxf(z1, NEG_SLOPE * z1);
        float z2 = a_s[s2] + adn; z2 = fmaxf(z2, NEG_SLOPE * z2);
        float z3 = a_s[s3] + adn; z3 = fmaxf(z3, NEG_SLOPE * z3);
        float zm = fmaxf(fmaxf(z0, z1), fmaxf(z2, z3));
        if (zm > m + 8.f) {
            float r = __expf(m - zm);
            s *= r;
            #pragma unroll
            for (int j = 0; j < 8; ++j) acc[j] *= r;
            m = zm;
        }
        float w0 = __expf(z0 - m), w1 = __expf(z1 - m);
        float w2 = __expf(z2 - m), w3 = __expf(z3 - m);
        s += (w0 + w1) + (w2 + w3);
        u16x8 v0 = *(const u16x8*)(rows + (size_t)s0 * 256 + c8);
        u16x8 v1 = *(const u16x8*)(rows + (size_t)s1 * 256 + c8);
        u16x8 v2 = *(const u16x8*)(rows + (size_t)s2 * 256 + c8);
        u16x8 v3 = *(const u16x8*)(rows + (size_t)s3 * 256 + c8);
        #pragma unroll
        for (int j = 0; j < 8; ++j)
            acc[j] += (w0 * b2f(v0[j]) + w1 * b2f(v1[j]))
                    + (w2 * b2f(v2[j]) + w3 * b2f(v3[j]));
    }
    for (; p + 3 < end; p += 4) {
        int s0 = srcs[p + half];
        int s1 = srcs[p + 2 + half];
        s0 = ((unsigned)s0 < (unsigned)N) ? s0 : 0;
        s1 = ((unsigned)s1 < (unsigned)N) ? s1 : 0;
        float z0 = a_s[s0] + adn; z0 = fmaxf(z0, NEG_SLOPE * z0);
        float z1 = a_s[s1] + adn; z1 = fmaxf(z1, NEG_SLOPE * z1);
        float zm = fmaxf(z0, z1);
        if (zm > m + 8.f) {
            float r = __expf(m - zm);
            s *= r;
            #pragma unroll
            for (int j = 0; j < 8; ++j) acc[j] *= r;
            m = zm;
        }
        float w0 = __expf(z0 - m), w1 = __expf(z1 - m);
        s += w0 + w1;
        u16x8 v0 = *(const u16x8*)(rows + (size_t)s0 * 256 + c8);
        u16x8 v1 = *(const u16x8*)(rows + (size_t)s1 * 256 + c8);
        #pragma unroll
        for (int j = 0; j < 8; ++j)
            acc[j] += w0 * b2f(v0[j]) + w1 * b2f(v1[j]);
    }
    for (; p + 1 < end; p += 2) {
        int s0 = srcs[p + half];
        s0 = ((unsigned)s0 < (unsigned)N) ? s0 : 0;
        float z0 = a_s[s0] + adn; z0 = fmaxf(z0, NEG_SLOPE * z0);
        if (z0 > m + 8.f) {
            float r = __expf(m - z0);
            s *= r;
            #pragma unroll
            for (int j = 0; j < 8; ++j) acc[j] *= r;
            m = z0;
        }
        float w0 = __expf(z0 - m);
        s += w0;
        u16x8 v0 = *(const u16x8*)(rows + (size_t)s0 * 256 + c8);
        #pragma unroll
        for (int j = 0; j < 8; ++j)
            acc[j] += w0 * b2f(v0[j]);
    }
    if (p < end && half == 0) {          // odd tail edge: half 0 only
        int s0 = srcs[p];
        s0 = ((unsigned)s0 < (unsigned)N) ? s0 : 0;
        float z0 = a_s[s0] + adn; z0 = fmaxf(z0, NEG_SLOPE * z0);
        if (z0 > m + 8.f) {
            float r = __expf(m - z0);
            s *= r;
            #pragma unroll
            for (int j = 0; j < 8; ++j) acc[j] *= r;
            m = z0;
        }
        float w0 = __expf(z0 - m);
        s += w0;
        u16x8 v0 = *(const u16x8*)(rows + (size_t)s0 * 256 + c8);
        #pragma unroll
        for (int j = 0; j < 8; ++j)
            acc[j] += w0 * b2f(v0[j]);
    }
    // merge the two half-wave states (exp-weighted; symmetric in both halves)
    float mo = __shfl_xor(m, 32, 64);
    float so = __shfl_xor(s, 32, 64);
    float mn = fmaxf(m, mo);
    float rA = __expf(m - mn), rB = __expf(mo - mn);
    float st = s * rA + so * rB;
    float invs = 1.f / (st + 1e-16f);
    #pragma unroll
    for (int j = 0; j < 8; ++j) {
        float ao = __shfl_xor(acc[j], 32, 64);
        acc[j] = acc[j] * rA + ao * rB;
    }
    if (half == 0) {
        size_t ob = (size_t)n * 256 + c8;
        if (add) {
            u16x8 ad8 = *(const u16x8*)(add + ob);
            #pragma unroll
            for (int j = 0; j < 8; ++j) acc[j] = acc[j] * invs + b2f(ad8[j]);
        } else {
            #pragma unroll
            for (int j = 0; j < 8; ++j) acc[j] *= invs;
        }
        u16x8 o;
        #pragma unroll
        for (int j = 0; j < 8; ++j) o[j] = f2b(acc[j]);
        *(u16x8*)(out + ob) = o;
    }
}

// ---------------------------------------------------------------------------
// full-width fused MFMA GEMM: BM=64, K=512 (two bf16 A halves of 256 each),
// NC=512 from fragment-major pre-packed WTf. Output split at col 256 into
// (C1, C2) with per-half fp32 bias pairs and relu flags. A read ONCE from HBM.
// 8 waves, each owns a 64x64 tile; LDS-staged bulk prefetch (measured-best
// structure), staging via async global_load_lds width=16.
// Optional fused row-dots on the C1 half (bf16-rounded acc · dotS/dotD,
// atomicAdd into oaS/oaD) — replaces the separate rowdot pass over h2.
// ---------------------------------------------------------------------------
__global__ __launch_bounds__(512)
void bigfull(const u16* __restrict__ A1, int lda1,
             const u16* __restrict__ A2, int lda2,
             const u16* __restrict__ WTf,
             const float* b0a, const float* b0b,
             const float* b1a, const float* b1b,
             u16* C1, int ldc1, u16* C2, int ldc2,
             const float* __restrict__ dotS, const float* __restrict__ dotD,
             float* oaS, float* oaD,
             int M, int relu0, int relu1)
{
    __shared__ u16 As[64 * 32];      // frag-major: [rf][lane][8]   (4 KB)
    __shared__ u16 Bs[512 * 32];     // frag-major: [cf][lane][8]  (32 KB)

    const int tid = threadIdx.x;
    const int w = tid >> 6, lane = tid & 63;
    const int m16 = lane & 15, q = lane >> 4;
    const int rowBase = blockIdx.x * 64;

    // waves 0-3 stage row-fragment rf = w: per-lane source row (clamped)
    int garow = rowBase + (w & 3) * 16 + m16;
    if (garow >= M) garow = M - 1;          // clamp; value unused when OOB

    float4v acc[16] = {};

    for (int k0 = 0; k0 < 512; k0 += 32) {
        const int kt = k0 >> 5;
        __syncthreads();
        if (w < 4) {   // stage A 64x32 into fragment order (async, 16B/lane)
            int kk = k0 + q * 8;
            const u16* src = (kk < 256)
                ? A1 + (size_t)garow * lda1 + kk
                : A2 + (size_t)garow * lda2 + (kk - 256);
            GLOAD_LDS16(src, &As[w * 512]);
        }
        {   // stage B 512x32: linear async copy of pre-packed fragments
            const u16* wsrc = WTf + (size_t)kt * 16384;
            #pragma unroll
            for (int p = 0; p < 4; ++p) {
                int chb = p * 512 + w * 64;          // wave-uniform chunk base
                GLOAD_LDS16(wsrc + ((size_t)chb + lane) * 8, &Bs[chb * 8]);
            }
        }
        __syncthreads();

        short8 a[4], b[4];
        #pragma unroll
        for (int r = 0; r < 4; ++r)
            a[r] = *(const short8*)&As[r * 512 + lane * 8];
        #pragma unroll
        for (int c = 0; c < 4; ++c)
            b[c] = *(const short8*)&Bs[(w * 4 + c) * 512 + lane * 8];
        #pragma unroll
        for (int r = 0; r < 4; ++r)
            #pragma unroll
            for (int c = 0; c < 4; ++c)
                acc[r * 4 + c] = __builtin_amdgcn_mfma_f32_16x16x32_bf16(
                    a[r], b[c], acc[r * 4 + c], 0, 0, 0);
    }

    const int colgrp = w >> 2;
    const float* ba = colgrp ? b1a : b0a;
    const float* bb = colgrp ? b1b : b0b;
    u16* C  = colgrp ? C2 : C1;
    const int ldc  = colgrp ? ldc2 : ldc1;
    const int relu = colgrp ? relu1 : relu0;
    #pragma unroll
    for (int c = 0; c < 4; ++c) {
        int lc = ((w & 3) * 4 + c) * 16 + m16;
        float bv = (ba ? ba[lc] : 0.f) + (bb ? bb[lc] : 0.f);
        #pragma unroll
        for (int r = 0; r < 4; ++r)
            #pragma unroll
            for (int i = 0; i < 4; ++i) {
                int grow = rowBase + r * 16 + q * 4 + i;
                if (grow < M) {
                    float v = acc[r * 4 + c][i] + bv;
                    if (relu) v = fmaxf(v, 0.f);
                    C[(size_t)grow * ldc + lc] = f2b(v);
                }
            }
    }

    // fused attention row-dots on the C1 half (no bias / no relu path)
    if (dotS && colgrp == 0) {
        #pragma unroll
        for (int r = 0; r < 4; ++r)
            #pragma unroll
            for (int i = 0; i < 4; ++i) {
                float ss = 0.f, sd = 0.f;
                #pragma unroll
                for (int c = 0; c < 4; ++c) {
                    int lc = ((w & 3) * 4 + c) * 16 + m16;
                    float v = b2f(f2b(acc[r * 4 + c][i]));  // match stored bf16
                    ss += v * dotS[lc];
                    sd += v * dotD[lc];
                }
                #pragma unroll
                for (int msk = 1; msk < 16; msk <<= 1) {
                    ss += __shfl_xor(ss, msk, 64);
                    sd += __shfl_xor(sd, msk, 64);
                }
                int grow = rowBase + r * 16 + q * 4 + i;
                if (m16 == 0 && grow < M) {
                    atomicAdd(&oaS[grow], ss);
                    atomicAdd(&oaD[grow], sd);
                }
            }
    }
}

// ---------------------------------------------------------------------------
// fused 3-layer MLP [256->256] relu + classifier + softmax. 512 threads =
// 8 waves sharing a 64-row frag-major LDS panel (32 KB); each wave owns
// 64 rows x 32 cols (8 acc frags -> low VGPR -> high occupancy). B read
// directly per-wave from L2. Final layer stays in the panel; fc 256->5 +
// softmax computed from it (waves 0-3), writing only `out`.
// ---------------------------------------------------------------------------
__global__ __launch_bounds__(512)
void k_mlp3fc(const u16* __restrict__ WTHf,
              const float* Hb1, const float* Hb2, const float* Hb3,
              const float* __restrict__ fcw, const float* __restrict__ fcb,
              const u16* __restrict__ Hin, float* __restrict__ out, int M)
{
    __shared__ u16 P[64 * 256];     // frag-major activation panel (32 KB)

    const int tid = threadIdx.x;
    const int w = tid >> 6, lane = tid & 63;
    const int m16 = lane & 15, q = lane >> 4;
    const int rowBase = blockIdx.x * 64;

    // load panel (global row-major -> fragment-major), 4 chunks/thread
    #pragma unroll
    for (int p = 0; p < 4; ++p) {
        int ch = p * 512 + tid;          // 0..2047 16B-chunks
        int f = ch >> 6, l = ch & 63;    // frag f = kt*4+rf, lane-slot l
        int kt = f >> 2, rf = f & 3;
        int grow = rowBase + rf * 16 + (l & 15);
        if (grow >= M) grow = M - 1;
        int col = kt * 32 + (l >> 4) * 8;
        *(int4*)&P[ch * 8] = *(const int4*)(Hin + (size_t)grow * 256 + col);
    }
    __syncthreads();

    const float* biases[3] = {Hb1, Hb2, Hb3};
    for (int L = 0; L < 3; ++L) {
        const u16* WTf = WTHf + (size_t)L * 65536;
        float4v acc[8] = {};
        #pragma unroll 2
        for (int kt = 0; kt < 8; ++kt) {
            short8 a[4], b[2];
            #pragma unroll
            for (int c = 0; c < 2; ++c) {
                int4 bv = *(const int4*)(WTf + (size_t)(kt * 16 + w * 2 + c) * 512
                                         + lane * 8);
                b[c] = *(short8*)&bv;
            }
            #pragma unroll
            for (int r = 0; r < 4; ++r)
                a[r] = *(const short8*)&P[(kt * 4 + r) * 512 + lane * 8];
            #pragma unroll
            for (int r = 0; r < 4; ++r)
                #pragma unroll
                for (int c = 0; c < 2; ++c)
                    acc[r * 2 + c] = __builtin_amdgcn_mfma_f32_16x16x32_bf16(
                        a[r], b[c], acc[r * 2 + c], 0, 0, 0);
        }
        const float* bias = biases[L];
        __syncthreads();    // all panel reads done before overwrite
        // writeback into fragment-major panel (out col -> next-layer k)
        #pragma unroll
        for (int c = 0; c < 2; ++c) {
            int col = w * 32 + c * 16 + m16;
            float bv = bias[col];
            int kt2 = col >> 5;               // == w
            int l2h = 16 * ((col & 31) >> 3);
            int j2 = col & 7;
            #pragma unroll
            for (int r = 0; r < 4; ++r)
                #pragma unroll
                for (int i = 0; i < 4; ++i) {
                    int l2 = (q * 4 + i) + l2h;
                    P[(size_t)(kt2 * 4 + r) * 512 + l2 * 8 + j2] =
                        f2b(fmaxf(acc[r * 2 + c][i] + bv, 0.f));
                }
        }
        __syncthreads();
    }

    // classifier + softmax from the panel (waves 0-3, rf = w).
    if (w < 4) {
        float p5[5] = {0.f, 0.f, 0.f, 0.f, 0.f};
        #pragma unroll
        for (int kt = 0; kt < 8; ++kt) {
            u16x8 v = *(const u16x8*)&P[(kt * 4 + w) * 512 + lane * 8];
            int colb = kt * 32 + q * 8;
            #pragma unroll
            for (int j = 0; j < 8; ++j) {
                float hv = b2f(v[j]);
                const float* wr = fcw + (size_t)(colb + j) * 5;
                #pragma unroll
                for (int c = 0; c < 5; ++c) p5[c] += hv * wr[c];
            }
        }
        #pragma unroll
        for (int c = 0; c < 5; ++c) {
            p5[c] += __shfl_xor(p5[c], 16, 64);
            p5[c] += __shfl_xor(p5[c], 32, 64);
        }
        int grow = rowBase + w * 16 + m16;
        if (q == 0 && grow < M) {
            float mx = -1e30f;
            #pragma unroll
            for (int c = 0; c < 5; ++c) { p5[c] += fcb[c]; mx = fmaxf(mx, p5[c]); }
            float s = 0.f, e[5];
            #pragma unroll
            for (int c = 0; c < 5; ++c) { e[c] = __expf(p5[c] - mx); s += e[c]; }
            float inv = 1.f / s;
            #pragma unroll
            for (int c = 0; c < 5; ++c) out[(size_t)grow * 5 + c] = e[c] * inv;
        }
    }
}

// ---------------------------------------------------------------------------
extern "C" void kernel_launch(void* const* d_in, const int* in_sizes, int n_in,
                              void* d_out, int out_size, void* d_ws, size_t ws_size,
                              hipStream_t stream)
{
    const float* x    = (const float*)d_in[0];
    const int*   ei   = (const int*)  d_in[1];
    const float* W1   = (const float*)d_in[2];
    const float* as1  = (const float*)d_in[3];
    const float* ad1  = (const float*)d_in[4];
    const float* bc1  = (const float*)d_in[5];
    const float* A1w  = (const float*)d_in[6];
    const float* b1   = (const float*)d_in[7];
    const float* W2   = (const float*)d_in[8];
    const float* as2  = (const float*)d_in[9];
    const float* ad2  = (const float*)d_in[10];
    const float* bc2  = (const float*)d_in[11];
    const float* A2w  = (const float*)d_in[12];
    const float* b2   = (const float*)d_in[13];
    const float* Hw1  = (const float*)d_in[14];
    const float* Hb1  = (const float*)d_in[15];
    const float* Hw2  = (const float*)d_in[16];
    const float* Hb2  = (const float*)d_in[17];
    const float* Hw3  = (const float*)d_in[18];
    const float* Hb3  = (const float*)d_in[19];
    const float* fcw  = (const float*)d_in[20];
    const float* fcb  = (const float*)d_in[21];
    float* out = (float*)d_out;

    const int D = 256;
    const int N = in_sizes[0] / D;
    const int E = in_sizes[1] / 2;

    char* w = (char*)d_ws;
    auto alloc = [&](size_t bytes) {
        char* p = w;
        w += (bytes + 255) & ~(size_t)255;
        return p;
    };
    int*   flag   = (int*)  alloc(256);
    int*   flag64 = (int*)  alloc(256);
    float* a_s    = (float*)alloc((size_t)N * 4);
    float* a_d    = (float*)alloc((size_t)N * 4);
    float* vs1    = (float*)alloc(1024);                 // W1 @ att_src1  [256]
    float* vd1    = (float*)alloc(1024);                 // W1 @ att_dst1  [256]
    int*   deg    = (int*)  alloc((size_t)N * 4);
    int*   cursor = (int*)  alloc((size_t)N * 4);
    int*   offA   = (int*)  alloc((size_t)(N + 1) * 4);
    int*   part   = (int*)  alloc((size_t)((N + 1023) / 1024 + 1) * 4);
    int*   srcs   = (int*)  alloc((size_t)E * 4);
    u16*   WT1    = (u16*)  alloc(512 * 512 * 2);        // frag-major [A1w;W1]
    u16*   WT2    = (u16*)  alloc(512 * 512 * 2);        // frag-major [W2|A2w]
    u16*   WTH    = (u16*)  alloc(3 * 256 * 256 * 2);    // frag-major MLP weights
    u16*   BUF1   = (u16*)  alloc((size_t)N * 512 * 2);  // xb|aggx -> h2|res2
    u16*   BUF2   = (u16*)  alloc((size_t)N * 512 * 2);  // hl1 -> out2

    // src32/dst32 alias BUF1 (dead before xb is written)
    int* src32 = (int*)BUF1;
    int* dst32 = src32 + E;

    size_t need = (size_t)(w - (char*)d_ws);             // ~110 MB
    if (ws_size < need) {
        float code = 1000.0f + (float)(ws_size >> 20);
        k_diag<<<(out_size + 255) / 256, 256, 0, stream>>>(out, out_size, code);
        return;
    }

    const int EB  = (E + 255) / 256;
    const int NB4 = (N + 3) / 4;
    const int OB  = (out_size + 255) / 256;
    const int NE  = (N > E ? N : E);
    const int RB64 = (N + 63) / 64;
    const int NBLK = (N + 1023) / 1024;
    const size_t NH2 = (size_t)N * 256;
    u16* XB   = BUF1;            // bf16 cast of x      [N,256]
    u16* AGGX = BUF1 + NH2;      // alpha-aggregated x  [N,256]

    hipMemsetAsync(flag, 0, 4, stream);
    hipMemsetAsync(deg, 0, (size_t)N * 4, stream);

    // ---- edge extraction (+degree count) + CSR by destination ----
    k_detect <<<1, 256, 0, stream>>>(ei, E, flag64);
    k_extract<<<EB, 256, 0, stream>>>(ei, E, flag64, src32, dst32, deg, N);
    k_scan_a <<<NBLK, 256, 0, stream>>>(deg, offA, part, N);
    k_scan_b <<<1, 1024, 0, stream>>>(part, NBLK);
    k_scan_c <<<(N + 255) / 256, 256, 0, stream>>>(offA, cursor, part, N, E);
    k_scatter<<<EB, 256, 0, stream>>>(src32, dst32, cursor, srcs, E, N);
    scan_csr <<<(NE + 255) / 256, 256, 0, stream>>>(offA, srcs, N, E, flag, 1);

    // ---- weight pre-pack (fragment-major bf16, single launch) ----
    k_packAll<<<dim3(32, 16, 5), 64, 0, stream>>>(A1w, W1, W2, A2w,
                                                  Hw1, Hw2, Hw3, WT1, WT2, WTH);

    // ---- attention vectors, then fused cast+dot over x ----
    k_rowdot2f<<<64, 256, 0, stream>>>(W1, 512, 512, as1, ad1, vs1, vd1, 256);
    k_castdot<<<(N + 7) / 8, 256, 0, stream>>>(x, vs1, vd1, XB, a_s, a_d, N);

    // ---- aggx = flash-style softmax-aggregate of xb (single edge pass) ----
    k_aggfl<<<NB4, 256, 0, stream>>>(XB, offA, srcs, a_s, a_d,
                                     nullptr, AGGX, N);

    // a_s/a_d fully consumed by aggfl-1; zero both (contiguous) for
    // bigfull-2's atomic dot accumulation
    hipMemsetAsync(a_s, 0, (size_t)((char*)a_d - (char*)a_s) + (size_t)N * 4,
                   stream);

    // ---- layer 1 fused: hl1 = relu([XB|AGGX] @ [A1w;W1] + b1 + bc1) ----
    bigfull<<<RB64, 512, 0, stream>>>(XB, 256, AGGX, 256, WT1,
                                      b1, bc1, b1 + 256, bc1 + 256,
                                      BUF2, 512, BUF2 + 256, 512,
                                      nullptr, nullptr, nullptr, nullptr,
                                      N, 1, 1);

    // ---- layer 2 fused: [h2 | res2] = hl1 @ [W2 | A2w] (+b2+bc2 on res2),
    //      with a_s2/a_d2 = h2·att2 accumulated in the epilogue ----
    bigfull<<<RB64, 512, 0, stream>>>(BUF2, 512, BUF2 + 256, 512, WT2,
                                      nullptr, nullptr, b2, bc2,
                                      BUF1, 256, BUF1 + NH2, 256,
                                      as2, ad2, a_s, a_d,
                                      N, 0, 0);

    // ---- layer-2 flash aggregate + residual add ----
    k_aggfl<<<NB4, 256, 0, stream>>>(BUF1, offA, srcs, a_s, a_d,
                                     BUF1 + NH2, BUF2, N);

    // ---- fused 3-layer MLP + classifier + softmax (reads BUF2, writes out) ----
    k_mlp3fc<<<RB64, 512, 0, stream>>>(WTH, Hb1, Hb2, Hb3, fcw, fcb,
                                       BUF2, out, N);

    k_final_diag<<<OB, 256, 0, stream>>>(flag, out, out_size);
}